// Round 2
// baseline (1384.772 us; speedup 1.0000x reference)
//
#include <hip/hip_runtime.h>

// L2RegressionAttention — chunked WY-transform, ws-size-adaptive layout.
// B=4, S=4096, D=1024, H=16, hd=64, eta = 0.1/4 = 0.025.
//
// Per head: M_t = M_{t-1} + eta * sum_b (v_tb - M_{t-1} k_tb) k_tb^T
//           out_tb = M_t q_tb
// Chunked (C=16 steps, N=64 rows):
//   (I + eta*L) U = eta (V - K M0^T);  Ubar = T eta V, W = T eta K
//   M_next = M0 (I - W^T K) + Ubar^T K = M0 (I - Pdev) + R
//   out = (Q - S W) M0^T + S Ubar = E M0^T + F,  S = blocktril(Q K^T) incl. diag
//
// Memory (adaptive): ws >= 192MB -> P,R,Mc fp32; else >=128MB -> bf16.
//   ws+0    : K bf16 (32MB)  -> Psup/Rsup/Msup fp32 (12MB) after phase1
//   ws+32MB : V bf16 (32MB)  -> F bf16 (overlay, same indices)
//   ws+64MB : Pdev (fp32 64MB | bf16 32MB) -> attn bf16 (32MB) after levelC
//   ws+128/96MB : R (fp32|bf16) -> Mc (overlay, load-before-store)
//   d_out   : Q fp32 -> E fp32 -> final out

typedef unsigned short u16;
typedef __attribute__((ext_vector_type(8))) short short8;
typedef __attribute__((ext_vector_type(4))) float f32x4;

#define B_ 4
#define S_ 4096
#define D_ 1024
#define H_ 16
#define CHUNK 16
#define NCHUNK 256
#define SUPW 16
#define NSUP 16
#define ETA 0.025f

__device__ __forceinline__ u16 f2bf(float f) {
  unsigned u = __builtin_bit_cast(unsigned, f);
  u += 0x7fffu + ((u >> 16) & 1u);
  return (u16)(u >> 16);
}
__device__ __forceinline__ float bf2f(u16 s) {
  unsigned u = ((unsigned)s) << 16;
  return __builtin_bit_cast(float, u);
}
__device__ __forceinline__ float ldv(float v) { return v; }
__device__ __forceinline__ float ldv(u16 v) { return bf2f(v); }
__device__ __forceinline__ void stv(float* p, float v) { *p = v; }
__device__ __forceinline__ void stv(u16* p, float v) { *p = f2bf(v); }

// ---------------- GEMM: C[M][N] = A * B^T, on-the-fly bf16 split ----------------
// ASPLIT=1: A fp32, 3 MFMA passes (AhBh+AhBl+AlBh). ASPLIT=0: A bf16, 2 passes.
// B always fp32, split to hi/lo during staging. 128x128 tile, BK=32, 4 waves.
template<int ASPLIT, typename OutT>
__global__ __launch_bounds__(256) void gemm_k(
    const void* __restrict__ Aptr, const float* __restrict__ Bm,
    OutT* __restrict__ C, int M, int N, int K) {
  __shared__ __align__(16) u16 Ah[128][32];
  __shared__ __align__(16) u16 Al[ASPLIT ? 128 : 1][32];
  __shared__ __align__(16) u16 Bh[128][32];
  __shared__ __align__(16) u16 Bl[128][32];
  const int tid = threadIdx.x;
  const int wave = tid >> 6, lane = tid & 63;
  const int bm = blockIdx.x * 128, bn = blockIdx.y * 128;
  const int wm = (wave >> 1) * 64, wn = (wave & 1) * 64;
  const int fr = lane & 15, kb = lane >> 4;

  f32x4 acc[4][4];
  f32x4 zero = {0.f, 0.f, 0.f, 0.f};
#pragma unroll
  for (int i = 0; i < 4; ++i)
#pragma unroll
    for (int j = 0; j < 4; ++j) acc[i][j] = zero;

  for (int k0 = 0; k0 < K; k0 += 32) {
    __syncthreads();
    // stage B: 128 rows x 32 fp32 -> hi/lo bf16
#pragma unroll
    for (int i = 0; i < 4; ++i) {
      int e = tid + i * 256;            // 0..1023
      int r = e >> 3, sg = (e & 7) * 4; // float4 granularity
      float4 v = *(const float4*)(&Bm[(size_t)(bn + r) * K + k0 + sg]);
      ushort4 h, l;
      h.x = f2bf(v.x); l.x = f2bf(v.x - bf2f(h.x));
      h.y = f2bf(v.y); l.y = f2bf(v.y - bf2f(h.y));
      h.z = f2bf(v.z); l.z = f2bf(v.z - bf2f(h.z));
      h.w = f2bf(v.w); l.w = f2bf(v.w - bf2f(h.w));
      *(ushort4*)(&Bh[r][sg]) = h;
      *(ushort4*)(&Bl[r][sg]) = l;
    }
    if constexpr (ASPLIT) {
      const float* A = (const float*)Aptr;
#pragma unroll
      for (int i = 0; i < 4; ++i) {
        int e = tid + i * 256;
        int r = e >> 3, sg = (e & 7) * 4;
        float4 v = *(const float4*)(&A[(size_t)(bm + r) * K + k0 + sg]);
        ushort4 h, l;
        h.x = f2bf(v.x); l.x = f2bf(v.x - bf2f(h.x));
        h.y = f2bf(v.y); l.y = f2bf(v.y - bf2f(h.y));
        h.z = f2bf(v.z); l.z = f2bf(v.z - bf2f(h.z));
        h.w = f2bf(v.w); l.w = f2bf(v.w - bf2f(h.w));
        *(ushort4*)(&Ah[r][sg]) = h;
        *(ushort4*)(&Al[r][sg]) = l;
      }
    } else {
      const u16* A = (const u16*)Aptr;
#pragma unroll
      for (int i = 0; i < 2; ++i) {
        int e = tid + i * 256;            // 0..511
        int r = e >> 2, sg = (e & 3) * 8; // 8 u16 = 16B
        *(uint4*)(&Ah[r][sg]) = *(const uint4*)(&A[(size_t)(bm + r) * K + k0 + sg]);
      }
    }
    __syncthreads();
    short8 ah[4], al[4], bh[4], bl[4];
#pragma unroll
    for (int mi = 0; mi < 4; ++mi) {
      ah[mi] = *(const short8*)(&Ah[wm + mi * 16 + fr][kb * 8]);
      if constexpr (ASPLIT) al[mi] = *(const short8*)(&Al[wm + mi * 16 + fr][kb * 8]);
    }
#pragma unroll
    for (int ni = 0; ni < 4; ++ni) {
      bh[ni] = *(const short8*)(&Bh[wn + ni * 16 + fr][kb * 8]);
      bl[ni] = *(const short8*)(&Bl[wn + ni * 16 + fr][kb * 8]);
    }
#pragma unroll
    for (int mi = 0; mi < 4; ++mi)
#pragma unroll
      for (int ni = 0; ni < 4; ++ni) {
        acc[mi][ni] = __builtin_amdgcn_mfma_f32_16x16x32_bf16(ah[mi], bh[ni], acc[mi][ni], 0, 0, 0);
        acc[mi][ni] = __builtin_amdgcn_mfma_f32_16x16x32_bf16(ah[mi], bl[ni], acc[mi][ni], 0, 0, 0);
        if constexpr (ASPLIT)
          acc[mi][ni] = __builtin_amdgcn_mfma_f32_16x16x32_bf16(al[mi], bh[ni], acc[mi][ni], 0, 0, 0);
      }
  }
  const int fc = lane & 15, fr4 = (lane >> 4) * 4;
#pragma unroll
  for (int mi = 0; mi < 4; ++mi)
#pragma unroll
    for (int ni = 0; ni < 4; ++ni) {
      int gm = bm + wm + mi * 16 + fr4;
      int gn = bn + wn + ni * 16 + fc;
#pragma unroll
      for (int rg = 0; rg < 4; ++rg)
        stv(&C[(size_t)(gm + rg) * N + gn], acc[mi][ni][rg]);
    }
}

// ---------------- phase 1: per (chunk, head) parallel WY solve ----------------
// In: Q fp32 (d_out), K/V bf16. Out: E fp32 (over Q), F bf16 (over V), Pdev, R (PT).
template<typename PT>
__global__ __launch_bounds__(256) void phase1_kernel(
    float* __restrict__ Qg, const u16* __restrict__ Kg, u16* __restrict__ Vg,
    PT* __restrict__ Pg, PT* __restrict__ Rg) {
  __shared__ float Ks[64][65], Us[64][65], Ws[64][65], Qs[64][65], Ssh[64][65], Gs[64][65];
  const int c = blockIdx.x, h = blockIdx.y, tid = threadIdx.x;

  for (int i = tid; i < 4096; i += 256) {
    int r = i >> 6, d = i & 63, t = r >> 2, b = r & 3;
    size_t g = ((size_t)b * S_ + (size_t)c * CHUNK + t) * D_ + h * 64 + d;
    float kk = bf2f(Kg[g]);
    Ks[r][d] = kk;
    Ws[r][d] = ETA * kk;
    Us[r][d] = ETA * bf2f(Vg[g]);
    Qs[r][d] = Qg[g];
  }
  __syncthreads();

  const int r0 = (tid >> 4) * 4, c0 = (tid & 15) * 4;
  // G = eta * K K^T
  {
    float a[4][4] = {};
    for (int d = 0; d < 64; ++d) {
      float xv[4], yv[4];
#pragma unroll
      for (int i = 0; i < 4; ++i) xv[i] = Ks[r0 + i][d];
#pragma unroll
      for (int j = 0; j < 4; ++j) yv[j] = Ks[c0 + j][d];
#pragma unroll
      for (int i = 0; i < 4; ++i)
#pragma unroll
        for (int j = 0; j < 4; ++j) a[i][j] += xv[i] * yv[j];
    }
#pragma unroll
    for (int i = 0; i < 4; ++i)
#pragma unroll
      for (int j = 0; j < 4; ++j) Gs[r0 + i][c0 + j] = ETA * a[i][j];
  }
  __syncthreads();

  // forward substitution (strictly block-lower)
  {
    const int b = tid >> 6, d = tid & 63;
    for (int t = 1; t < CHUNK; ++t) {
      const int r = t * 4 + b;
      float su = 0.f, sw = 0.f;
      for (int rp = 0; rp < 4 * t; ++rp) {
        float g = Gs[r][rp];
        su += g * Us[rp][d];
        sw += g * Ws[rp][d];
      }
      Us[r][d] -= su;
      Ws[r][d] -= sw;
      __syncthreads();
    }
  }

  // S = Q K^T
  {
    float a[4][4] = {};
    for (int d = 0; d < 64; ++d) {
      float xv[4], yv[4];
#pragma unroll
      for (int i = 0; i < 4; ++i) xv[i] = Qs[r0 + i][d];
#pragma unroll
      for (int j = 0; j < 4; ++j) yv[j] = Ks[c0 + j][d];
#pragma unroll
      for (int i = 0; i < 4; ++i)
#pragma unroll
        for (int j = 0; j < 4; ++j) a[i][j] += xv[i] * yv[j];
    }
#pragma unroll
    for (int i = 0; i < 4; ++i)
#pragma unroll
      for (int j = 0; j < 4; ++j) Ssh[r0 + i][c0 + j] = a[i][j];
  }
  // Pdev = W^T K ; R = Ubar^T K
  {
    float pp[4][4] = {}, rr[4][4] = {};
    for (int r = 0; r < 64; ++r) {
      float wk[4], kk[4], uu[4];
#pragma unroll
      for (int i = 0; i < 4; ++i) { wk[i] = Ws[r][r0 + i]; uu[i] = Us[r][r0 + i]; }
#pragma unroll
      for (int j = 0; j < 4; ++j) kk[j] = Ks[r][c0 + j];
#pragma unroll
      for (int i = 0; i < 4; ++i)
#pragma unroll
        for (int j = 0; j < 4; ++j) { pp[i][j] += wk[i] * kk[j]; rr[i][j] += uu[i] * kk[j]; }
    }
    size_t base = ((size_t)c * H_ + h) * 4096;
#pragma unroll
    for (int i = 0; i < 4; ++i)
#pragma unroll
      for (int j = 0; j < 4; ++j) {
        stv(&Pg[base + (r0 + i) * 64 + c0 + j], pp[i][j]);
        stv(&Rg[base + (r0 + i) * 64 + c0 + j], rr[i][j]);
      }
  }
  __syncthreads();

  // E = Q - S W ; F = S Ubar  (rows rp < 4*(t+1): diag block included)
  {
    const int t = tid >> 4, dq = tid & 15;
    float se[4][4] = {}, sf[4][4] = {};
    const int rmax = 4 * (t + 1);
    for (int rp = 0; rp < rmax; ++rp) {
      float sv[4], uv[4], wv[4];
#pragma unroll
      for (int i = 0; i < 4; ++i) sv[i] = Ssh[4 * t + i][rp];
#pragma unroll
      for (int j = 0; j < 4; ++j) { uv[j] = Us[rp][4 * dq + j]; wv[j] = Ws[rp][4 * dq + j]; }
#pragma unroll
      for (int i = 0; i < 4; ++i)
#pragma unroll
        for (int j = 0; j < 4; ++j) { sf[i][j] += sv[i] * uv[j]; se[i][j] += sv[i] * wv[j]; }
    }
#pragma unroll
    for (int i = 0; i < 4; ++i)
#pragma unroll
      for (int j = 0; j < 4; ++j) {
        int r = 4 * t + i, d = 4 * dq + j, b = r & 3;
        size_t g = ((size_t)b * S_ + (size_t)c * CHUNK + t) * D_ + h * 64 + d;
        Qg[g] = Qs[r][d] - se[i][j];  // E
        Vg[g] = f2bf(sf[i][j]);       // F
      }
  }
}

// ---------------- 64x64 fp32 helpers ----------------
__device__ __forceinline__ void load64(float (*dst)[65], const float* src, int tid) {
  for (int i = tid; i < 4096; i += 256) dst[i >> 6][i & 63] = src[i];
}
__device__ __forceinline__ void store64(float* dst, const float (*src)[65], int tid) {
  for (int i = tid; i < 4096; i += 256) dst[i] = src[i >> 6][i & 63];
}
template<typename PT>
__device__ __forceinline__ void loadPfull(float (*dst)[65], const PT* src, int tid) {
  for (int i = tid; i < 4096; i += 256) {
    int r = i >> 6, cc = i & 63;
    dst[r][cc] = ((r == cc) ? 1.f : 0.f) - ldv(src[i]);
  }
}
template<typename PT>
__device__ __forceinline__ void loadR(float (*dst)[65], const PT* src, int tid) {
  for (int i = tid; i < 4096; i += 256) dst[i >> 6][i & 63] = ldv(src[i]);
}
// Dst = X*Y (+Add); Dst may alias X (write after barrier).
__device__ __forceinline__ void mm64(const float (*X)[65], const float (*Y)[65],
                                     float (*Dst)[65], const float (*Add)[65], int tid) {
  const int r0 = (tid >> 4) * 4, c0 = (tid & 15) * 4;
  float a[4][4] = {};
  for (int d = 0; d < 64; ++d) {
    float xv[4], yv[4];
#pragma unroll
    for (int i = 0; i < 4; ++i) xv[i] = X[r0 + i][d];
#pragma unroll
    for (int j = 0; j < 4; ++j) yv[j] = Y[d][c0 + j];
#pragma unroll
    for (int i = 0; i < 4; ++i)
#pragma unroll
      for (int j = 0; j < 4; ++j) a[i][j] += xv[i] * yv[j];
  }
  __syncthreads();
#pragma unroll
  for (int i = 0; i < 4; ++i)
#pragma unroll
    for (int j = 0; j < 4; ++j) {
      float v = a[i][j];
      if (Add) v += Add[r0 + i][c0 + j];
      Dst[r0 + i][c0 + j] = v;
    }
  __syncthreads();
}

// level A: compose (P,R) within each superchunk -> fp32 Psup/Rsup
template<typename PT>
__global__ __launch_bounds__(256) void seq_levelA(const PT* __restrict__ Pg,
    const PT* __restrict__ Rg, float* __restrict__ Psup, float* __restrict__ Rsup) {
  __shared__ float Pa[64][65], Ra[64][65], Pi[64][65], Ri[64][65];
  const int sup = blockIdx.x, h = blockIdx.y, tid = threadIdx.x;
  const int cbase = sup * SUPW;
  loadPfull(Pa, Pg + ((size_t)cbase * H_ + h) * 4096, tid);
  loadR(Ra, Rg + ((size_t)cbase * H_ + h) * 4096, tid);
  __syncthreads();
  for (int s = 1; s < SUPW; ++s) {
    loadPfull(Pi, Pg + ((size_t)(cbase + s) * H_ + h) * 4096, tid);
    loadR(Ri, Rg + ((size_t)(cbase + s) * H_ + h) * 4096, tid);
    __syncthreads();
    mm64(Pa, Pi, Pa, nullptr, tid);  // Pa = Pa*Pi
    mm64(Ra, Pi, Ra, Ri, tid);       // Ra = Ra*Pi + Ri
  }
  store64(Psup + ((size_t)sup * H_ + h) * 4096, Pa, tid);
  store64(Rsup + ((size_t)sup * H_ + h) * 4096, Ra, tid);
}

// level B: sequential over 16 superchunks (per head)
__global__ __launch_bounds__(256) void seq_levelB(const float* __restrict__ Psup,
    const float* __restrict__ Rsup, float* __restrict__ Msup) {
  __shared__ float Ms[64][65], Pi[64][65], Ri[64][65];
  const int h = blockIdx.x, tid = threadIdx.x;
  for (int i = tid; i < 4096; i += 256) Ms[i >> 6][i & 63] = 0.f;
  __syncthreads();
  for (int s = 0; s < NSUP; ++s) {
    store64(Msup + ((size_t)s * H_ + h) * 4096, Ms, tid);
    load64(Pi, Psup + ((size_t)s * H_ + h) * 4096, tid);
    load64(Ri, Rsup + ((size_t)s * H_ + h) * 4096, tid);
    __syncthreads();
    mm64(Ms, Pi, Ms, Ri, tid);
  }
}

// level C: expand within superchunk; writes Mc OVER Rg (load-before-store)
template<typename PT>
__global__ __launch_bounds__(256) void seq_levelC(const PT* __restrict__ Pg,
    PT* __restrict__ Rg, const float* __restrict__ Msup) {
  __shared__ float Ms[64][65], Pi[64][65], Ri[64][65];
  const int sup = blockIdx.x, h = blockIdx.y, tid = threadIdx.x;
  load64(Ms, Msup + ((size_t)sup * H_ + h) * 4096, tid);
  __syncthreads();
  for (int s = 0; s < SUPW; ++s) {
    const size_t slice = ((size_t)(sup * SUPW + s) * H_ + h) * 4096;
    loadPfull(Pi, Pg + slice, tid);
    loadR(Ri, Rg + slice, tid);
    __syncthreads();
    // Mc[c] = M at chunk start (over R slot; Ri already in LDS)
    for (int i = tid; i < 4096; i += 256) stv(&Rg[slice + i], Ms[i >> 6][i & 63]);
    mm64(Ms, Pi, Ms, Ri, tid);
  }
}

// ---------------- phase 3: attn = E*M0^T + F (bf16 out) ----------------
template<typename PT>
__global__ __launch_bounds__(256) void phase3_kernel(
    const float* __restrict__ Eg, const u16* __restrict__ Fg,
    const PT* __restrict__ Mcg, u16* __restrict__ attn) {
  __shared__ float Es[64][65], Ms[64][65];
  const int c = blockIdx.x, h = blockIdx.y, tid = threadIdx.x;
  for (int i = tid; i < 4096; i += 256) {
    int r = i >> 6, d = i & 63, t = r >> 2, b = r & 3;
    size_t g = ((size_t)b * S_ + (size_t)c * CHUNK + t) * D_ + h * 64 + d;
    Es[r][d] = Eg[g];
    Ms[i >> 6][i & 63] = ldv(Mcg[((size_t)c * H_ + h) * 4096 + i]);
  }
  __syncthreads();
  const int r0 = (tid >> 4) * 4, d0 = (tid & 15) * 4;
  float a[4][4] = {};
  for (int k = 0; k < 64; ++k) {
    float ev[4], mv[4];
#pragma unroll
    for (int i = 0; i < 4; ++i) ev[i] = Es[r0 + i][k];
#pragma unroll
    for (int j = 0; j < 4; ++j) mv[j] = Ms[d0 + j][k];
#pragma unroll
    for (int i = 0; i < 4; ++i)
#pragma unroll
      for (int j = 0; j < 4; ++j) a[i][j] += ev[i] * mv[j];
  }
#pragma unroll
  for (int i = 0; i < 4; ++i)
#pragma unroll
    for (int j = 0; j < 4; ++j) {
      int r = r0 + i, d = d0 + j, t = r >> 2, b = r & 3;
      size_t g = ((size_t)b * S_ + (size_t)c * CHUNK + t) * D_ + h * 64 + d;
      attn[g] = f2bf(a[i][j] + bf2f(Fg[g]));
    }
}

// ---------------- launch ----------------
extern "C" void kernel_launch(void* const* d_in, const int* in_sizes, int n_in,
                              void* d_out, int out_size, void* d_ws, size_t ws_size,
                              hipStream_t stream) {
  (void)in_sizes; (void)n_in; (void)out_size;
  const float* x  = (const float*)d_in[0];
  const float* Wq = (const float*)d_in[1];
  const float* Wk = (const float*)d_in[2];
  const float* Wv = (const float*)d_in[3];
  const float* Wo = (const float*)d_in[4];
  float* out = (float*)d_out;

  char* w = (char*)d_ws;
  const size_t MB = 1024 * 1024;
  u16* Kbf = (u16*)w;                    // 32MB; -> smalls after phase1
  u16* Vbf = (u16*)(w + 32 * MB);        // 32MB; -> F
  void* Preg = (void*)(w + 64 * MB);     // 64MB fp32 | 32MB bf16; -> attn
  const bool big = ws_size >= 192 * MB;
  void* Rreg = big ? (void*)(w + 128 * MB) : (void*)(w + 96 * MB);
  float* Psup = (float*)w;
  float* Rsup = (float*)(w + 4 * MB);
  float* Msup = (float*)(w + 8 * MB);
  u16* attn = (u16*)Preg;

  dim3 gg(128, 8);
  gemm_k<1, float><<<gg, 256, 0, stream>>>(x, Wq, out, 16384, 1024, 1024);
  gemm_k<1, u16><<<gg, 256, 0, stream>>>(x, Wk, Kbf, 16384, 1024, 1024);
  gemm_k<1, u16><<<gg, 256, 0, stream>>>(x, Wv, Vbf, 16384, 1024, 1024);

  if (big) {
    float* P = (float*)Preg; float* R = (float*)Rreg;
    phase1_kernel<float><<<dim3(NCHUNK, H_), 256, 0, stream>>>(out, Kbf, Vbf, P, R);
    seq_levelA<float><<<dim3(NSUP, H_), 256, 0, stream>>>(P, R, Psup, Rsup);
    seq_levelB<<<dim3(H_), 256, 0, stream>>>(Psup, Rsup, Msup);
    seq_levelC<float><<<dim3(NSUP, H_), 256, 0, stream>>>(P, R, Msup);
    phase3_kernel<float><<<dim3(NCHUNK, H_), 256, 0, stream>>>(out, Vbf, R, attn);
  } else {
    u16* P = (u16*)Preg; u16* R = (u16*)Rreg;
    phase1_kernel<u16><<<dim3(NCHUNK, H_), 256, 0, stream>>>(out, Kbf, Vbf, P, R);
    seq_levelA<u16><<<dim3(NSUP, H_), 256, 0, stream>>>(P, R, Psup, Rsup);
    seq_levelB<<<dim3(H_), 256, 0, stream>>>(Psup, Rsup, Msup);
    seq_levelC<u16><<<dim3(NSUP, H_), 256, 0, stream>>>(P, R, Msup);
    phase3_kernel<u16><<<dim3(NCHUNK, H_), 256, 0, stream>>>(out, Vbf, R, attn);
  }
  gemm_k<0, float><<<gg, 256, 0, stream>>>(attn, Wo, out, 16384, 1024, 1024);
}

// Round 3
// 1086.715 us; speedup vs baseline: 1.2743x; 1.2743x over previous
//
#include <hip/hip_runtime.h>

// L2RegressionAttention — chunked WY-transform, MFMA phase1 (Neumann chain).
// B=4, S=4096, D=1024, H=16, hd=64, eta = 0.1/4 = 0.025.
//
// Per head: M_t = M_{t-1} + eta * sum_b (v_tb - M_{t-1} k_tb) k_tb^T
//           out_tb = M_t q_tb
// Chunked (C=16 steps, N=64 rows):
//   (I + eta*L) U = eta (V - K M0^T);  N := -eta*L_strict (nilpotent, N^16=0)
//   (I+eta*L)^-1 = (I+N)(I+N^2)(I+N^4)(I+N^8)   [factors commute]
//   Ubar = inv * eta V, W = inv * eta K
//   M_next = M0 (I - W^T K) + Ubar^T K = M0 (I - Pdev) + R
//   out = (Q - S W) M0^T + S Ubar = E M0^T + F,  S = blocktril(Q K^T) incl. diag

typedef unsigned short u16;
typedef __attribute__((ext_vector_type(8))) short short8;
typedef __attribute__((ext_vector_type(4))) float f32x4;

#define B_ 4
#define S_ 4096
#define D_ 1024
#define H_ 16
#define CHUNK 16
#define NCHUNK 256
#define SUPW 16
#define NSUP 16
#define ETA 0.025f

__device__ __forceinline__ u16 f2bf(float f) {
  unsigned u = __builtin_bit_cast(unsigned, f);
  u += 0x7fffu + ((u >> 16) & 1u);
  return (u16)(u >> 16);
}
__device__ __forceinline__ float bf2f(u16 s) {
  unsigned u = ((unsigned)s) << 16;
  return __builtin_bit_cast(float, u);
}
__device__ __forceinline__ float ldv(float v) { return v; }
__device__ __forceinline__ float ldv(u16 v) { return bf2f(v); }
__device__ __forceinline__ void stv(float* p, float v) { *p = v; }
__device__ __forceinline__ void stv(u16* p, float v) { *p = f2bf(v); }

#define MFMA __builtin_amdgcn_mfma_f32_16x16x32_bf16

// ---------------- GEMM: C[M][N] = A * B^T, on-the-fly bf16 split ----------------
template<int ASPLIT, typename OutT>
__global__ __launch_bounds__(256) void gemm_k(
    const void* __restrict__ Aptr, const float* __restrict__ Bm,
    OutT* __restrict__ C, int M, int N, int K) {
  __shared__ __align__(16) u16 Ah[128][32];
  __shared__ __align__(16) u16 Al[ASPLIT ? 128 : 1][32];
  __shared__ __align__(16) u16 Bh[128][32];
  __shared__ __align__(16) u16 Bl[128][32];
  const int tid = threadIdx.x;
  const int wave = tid >> 6, lane = tid & 63;
  const int bm = blockIdx.x * 128, bn = blockIdx.y * 128;
  const int wm = (wave >> 1) * 64, wn = (wave & 1) * 64;
  const int fr = lane & 15, kb = lane >> 4;

  f32x4 acc[4][4];
#pragma unroll
  for (int i = 0; i < 4; ++i)
#pragma unroll
    for (int j = 0; j < 4; ++j) acc[i][j] = (f32x4){0.f, 0.f, 0.f, 0.f};

  for (int k0 = 0; k0 < K; k0 += 32) {
    __syncthreads();
#pragma unroll
    for (int i = 0; i < 4; ++i) {
      int e = tid + i * 256;
      int r = e >> 3, sg = (e & 7) * 4;
      float4 v = *(const float4*)(&Bm[(size_t)(bn + r) * K + k0 + sg]);
      ushort4 h, l;
      h.x = f2bf(v.x); l.x = f2bf(v.x - bf2f(h.x));
      h.y = f2bf(v.y); l.y = f2bf(v.y - bf2f(h.y));
      h.z = f2bf(v.z); l.z = f2bf(v.z - bf2f(h.z));
      h.w = f2bf(v.w); l.w = f2bf(v.w - bf2f(h.w));
      *(ushort4*)(&Bh[r][sg]) = h;
      *(ushort4*)(&Bl[r][sg]) = l;
    }
    if constexpr (ASPLIT) {
      const float* A = (const float*)Aptr;
#pragma unroll
      for (int i = 0; i < 4; ++i) {
        int e = tid + i * 256;
        int r = e >> 3, sg = (e & 7) * 4;
        float4 v = *(const float4*)(&A[(size_t)(bm + r) * K + k0 + sg]);
        ushort4 h, l;
        h.x = f2bf(v.x); l.x = f2bf(v.x - bf2f(h.x));
        h.y = f2bf(v.y); l.y = f2bf(v.y - bf2f(h.y));
        h.z = f2bf(v.z); l.z = f2bf(v.z - bf2f(h.z));
        h.w = f2bf(v.w); l.w = f2bf(v.w - bf2f(h.w));
        *(ushort4*)(&Ah[r][sg]) = h;
        *(ushort4*)(&Al[r][sg]) = l;
      }
    } else {
      const u16* A = (const u16*)Aptr;
#pragma unroll
      for (int i = 0; i < 2; ++i) {
        int e = tid + i * 256;
        int r = e >> 2, sg = (e & 3) * 8;
        *(uint4*)(&Ah[r][sg]) = *(const uint4*)(&A[(size_t)(bm + r) * K + k0 + sg]);
      }
    }
    __syncthreads();
    short8 ah[4], al[4], bh[4], bl[4];
#pragma unroll
    for (int mi = 0; mi < 4; ++mi) {
      ah[mi] = *(const short8*)(&Ah[wm + mi * 16 + fr][kb * 8]);
      if constexpr (ASPLIT) al[mi] = *(const short8*)(&Al[wm + mi * 16 + fr][kb * 8]);
    }
#pragma unroll
    for (int ni = 0; ni < 4; ++ni) {
      bh[ni] = *(const short8*)(&Bh[wn + ni * 16 + fr][kb * 8]);
      bl[ni] = *(const short8*)(&Bl[wn + ni * 16 + fr][kb * 8]);
    }
#pragma unroll
    for (int mi = 0; mi < 4; ++mi)
#pragma unroll
      for (int ni = 0; ni < 4; ++ni) {
        acc[mi][ni] = MFMA(ah[mi], bh[ni], acc[mi][ni], 0, 0, 0);
        acc[mi][ni] = MFMA(ah[mi], bl[ni], acc[mi][ni], 0, 0, 0);
        if constexpr (ASPLIT)
          acc[mi][ni] = MFMA(al[mi], bh[ni], acc[mi][ni], 0, 0, 0);
      }
  }
  const int fc = lane & 15, fr4 = (lane >> 4) * 4;
#pragma unroll
  for (int mi = 0; mi < 4; ++mi)
#pragma unroll
    for (int ni = 0; ni < 4; ++ni) {
      int gm = bm + wm + mi * 16 + fr4;
      int gn = bn + wn + ni * 16 + fc;
#pragma unroll
      for (int rg = 0; rg < 4; ++rg)
        stv(&C[(size_t)(gm + rg) * N + gn], acc[mi][ni][rg]);
    }
}

// ---------------- phase 1 (MFMA): per (chunk, head) WY solve ----------------
// LDS: Ks,Gh,Gl,Ab bf16 [64][72] + Ut,Wt fp32 [64][68] = 71,680 B -> 2 blk/CU.
// Chain buffers: Gh/Gl = -eta*K*K^T (h/l, symmetric); Ab=N^2; N^4->Gh; N^8->Gl.
// Late reuse: Qh->Ab, Ql->Gh, Smh->Gl, Sml->Ks.
template<typename PT>
__global__ __launch_bounds__(256) void phase1_kernel(
    float* __restrict__ Qg, const u16* __restrict__ Kg, u16* __restrict__ Vg,
    PT* __restrict__ Pg, PT* __restrict__ Rg) {
  __shared__ __align__(16) u16 Ks[64][72];
  __shared__ __align__(16) u16 Gh[64][72];
  __shared__ __align__(16) u16 Gl[64][72];
  __shared__ __align__(16) u16 Ab[64][72];
  __shared__ __align__(16) float Ut[64][68];
  __shared__ __align__(16) float Wt[64][68];

  const int c = blockIdx.x, h = blockIdx.y, tid = threadIdx.x;
  const int w = tid >> 6, lane = tid & 63;
  const int fr = lane & 15, kq = lane >> 4, orow = kq * 4;
  const int xr = 16 * w + fr;  // X-frag row for this wave

  auto gidx = [&](int r, int d) -> size_t {
    return ((size_t)(r & 3) * S_ + (size_t)c * CHUNK + (r >> 2)) * D_ + h * 64 + d;
  };
  auto ldb = [&](const u16 (*M)[72], int row, int s) -> short8 {
    return *(const short8*)(&M[row][32 * s + 8 * kq]);
  };
  // masked read of N = (strict block-triangular part of G): up=false -> lower
  auto ldm = [&](const u16 (*M)[72], int row, int s, bool up) -> short8 {
    short8 r = *(const short8*)(&M[row][32 * s + 8 * kq]);
    int rb = row >> 2, k0 = 32 * s + 8 * kq;
#pragma unroll
    for (int j = 0; j < 8; ++j) {
      int kb2 = (k0 + j) >> 2;
      bool keep = up ? (kb2 > rb) : (rb > kb2);
      if (!keep) r[j] = 0;
    }
    return r;
  };
  // transposed (strided) read: element j = M[k0+j][col]
  auto ldt = [&](const u16 (*M)[72], int col, int s) -> short8 {
    short8 r;
    int k0 = 32 * s + 8 * kq;
#pragma unroll
    for (int j = 0; j < 8; ++j) r[j] = (short)M[k0 + j][col];
    return r;
  };
  auto ldf = [&](const float (*M)[68], int row, int s, short8& hh, short8& ll) {
    const float* p = &M[row][32 * s + 8 * kq];
#pragma unroll
    for (int j = 0; j < 8; ++j) {
      float v = p[j];
      u16 hb = f2bf(v);
      hh[j] = (short)hb;
      ll[j] = (short)f2bf(v - bf2f(hb));
    }
  };
  auto ldfh = [&](const float (*M)[68], int row, int s) -> short8 {
    const float* p = &M[row][32 * s + 8 * kq];
    short8 hh;
#pragma unroll
    for (int j = 0; j < 8; ++j) hh[j] = (short)f2bf(p[j]);
    return hh;
  };

  // ---- ph0: load K, V; state init Wt = eta*K^T, Ut = eta*V^T ----
  for (int i = tid; i < 4096; i += 256) {
    int r = i >> 6, d = i & 63;
    size_t g = gidx(r, d);
    u16 kraw = Kg[g];
    Ks[r][d] = kraw;
    Wt[d][r] = ETA * bf2f(kraw);
    Ut[d][r] = ETA * bf2f(Vg[g]);
  }
  __syncthreads();

  // ---- ph1: G = -eta * K K^T (h/l bf16, exactly symmetric) ----
  {
    f32x4 acc[4];
#pragma unroll
    for (int ni = 0; ni < 4; ++ni) acc[ni] = (f32x4){0.f, 0.f, 0.f, 0.f};
    short8 xf[2];
#pragma unroll
    for (int s = 0; s < 2; ++s) xf[s] = ldb(Ks, xr, s);
#pragma unroll
    for (int ni = 0; ni < 4; ++ni)
#pragma unroll
      for (int s = 0; s < 2; ++s)
        acc[ni] = MFMA(xf[s], ldb(Ks, 16 * ni + fr, s), acc[ni], 0, 0, 0);
#pragma unroll
    for (int ni = 0; ni < 4; ++ni)
#pragma unroll
      for (int rg = 0; rg < 4; ++rg) {
        float v = -ETA * acc[ni][rg];
        u16 hb = f2bf(v);
        int rr = 16 * w + orow + rg, cc = 16 * ni + fr;
        Gh[rr][cc] = hb;
        Gl[rr][cc] = f2bf(v - bf2f(hb));
      }
  }
  __syncthreads();

  // in-place state update: St += St * Yp^T  (Z[d][r] = sum_k St[d][k]*Np[r][k])
  auto app1 = [&](float (*St)[68]) {  // Y = N from masked Gh/Gl, X = h/l (3-pass)
    short8 xh[2], xl[2];
#pragma unroll
    for (int s = 0; s < 2; ++s) ldf(St, xr, s, xh[s], xl[s]);
    f32x4 acc[4];
#pragma unroll
    for (int ni = 0; ni < 4; ++ni) acc[ni] = (f32x4){0.f, 0.f, 0.f, 0.f};
#pragma unroll
    for (int ni = 0; ni < 4; ++ni)
#pragma unroll
      for (int s = 0; s < 2; ++s) {
        short8 yh = ldm(Gh, 16 * ni + fr, s, false);
        short8 yl = ldm(Gl, 16 * ni + fr, s, false);
        acc[ni] = MFMA(xh[s], yh, acc[ni], 0, 0, 0);
        acc[ni] = MFMA(xh[s], yl, acc[ni], 0, 0, 0);
        acc[ni] = MFMA(xl[s], yh, acc[ni], 0, 0, 0);
      }
#pragma unroll
    for (int ni = 0; ni < 4; ++ni)
#pragma unroll
      for (int rg = 0; rg < 4; ++rg)
        St[16 * w + orow + rg][16 * ni + fr] += acc[ni][rg];
  };
  auto appS = [&](float (*St)[68], const u16 (*Np)[72]) {  // single-bf16 power
    short8 xh[2];
#pragma unroll
    for (int s = 0; s < 2; ++s) xh[s] = ldfh(St, xr, s);
    f32x4 acc[4];
#pragma unroll
    for (int ni = 0; ni < 4; ++ni) acc[ni] = (f32x4){0.f, 0.f, 0.f, 0.f};
#pragma unroll
    for (int ni = 0; ni < 4; ++ni)
#pragma unroll
      for (int s = 0; s < 2; ++s)
        acc[ni] = MFMA(xh[s], ldb(Np, 16 * ni + fr, s), acc[ni], 0, 0, 0);
#pragma unroll
    for (int ni = 0; ni < 4; ++ni)
#pragma unroll
      for (int rg = 0; rg < 4; ++rg)
        St[16 * w + orow + rg][16 * ni + fr] += acc[ni][rg];
  };

  // ---- ph2: app1 (U,W) ; sq1: Ab = N^2 (3-pass from masked G h/l) ----
  app1(Ut);
  app1(Wt);
  {
    f32x4 acc[4];
#pragma unroll
    for (int ni = 0; ni < 4; ++ni) acc[ni] = (f32x4){0.f, 0.f, 0.f, 0.f};
    short8 xh[2], xl[2];
#pragma unroll
    for (int s = 0; s < 2; ++s) {
      xh[s] = ldm(Gh, xr, s, false);
      xl[s] = ldm(Gl, xr, s, false);
    }
#pragma unroll
    for (int ni = 0; ni < 4; ++ni)
#pragma unroll
      for (int s = 0; s < 2; ++s) {
        short8 yh = ldm(Gh, 16 * ni + fr, s, true);  // N^T[c][k] = N[k][c] via symmetry
        short8 yl = ldm(Gl, 16 * ni + fr, s, true);
        acc[ni] = MFMA(xh[s], yh, acc[ni], 0, 0, 0);
        acc[ni] = MFMA(xh[s], yl, acc[ni], 0, 0, 0);
        acc[ni] = MFMA(xl[s], yh, acc[ni], 0, 0, 0);
      }
#pragma unroll
    for (int ni = 0; ni < 4; ++ni)
#pragma unroll
      for (int rg = 0; rg < 4; ++rg)
        Ab[16 * w + orow + rg][16 * ni + fr] = f2bf(acc[ni][rg]);
  }
  __syncthreads();

  // ---- ph3: app2 (Y = Ab = N^2) ; sq2: Gh <- N^4 = Ab * Ab ----
  appS(Ut, Ab);
  appS(Wt, Ab);
  {
    f32x4 acc[4];
#pragma unroll
    for (int ni = 0; ni < 4; ++ni) acc[ni] = (f32x4){0.f, 0.f, 0.f, 0.f};
    short8 xf[2];
#pragma unroll
    for (int s = 0; s < 2; ++s) xf[s] = ldb(Ab, xr, s);
#pragma unroll
    for (int ni = 0; ni < 4; ++ni)
#pragma unroll
      for (int s = 0; s < 2; ++s)
        acc[ni] = MFMA(xf[s], ldt(Ab, 16 * ni + fr, s), acc[ni], 0, 0, 0);
#pragma unroll
    for (int ni = 0; ni < 4; ++ni)
#pragma unroll
      for (int rg = 0; rg < 4; ++rg)
        Gh[16 * w + orow + rg][16 * ni + fr] = f2bf(acc[ni][rg]);
  }
  __syncthreads();

  // ---- ph4: app3 (Y = Gh = N^4) ; sq3: Gl <- N^8 = Gh * Gh ----
  appS(Ut, Gh);
  appS(Wt, Gh);
  {
    f32x4 acc[4];
#pragma unroll
    for (int ni = 0; ni < 4; ++ni) acc[ni] = (f32x4){0.f, 0.f, 0.f, 0.f};
    short8 xf[2];
#pragma unroll
    for (int s = 0; s < 2; ++s) xf[s] = ldb(Gh, xr, s);
#pragma unroll
    for (int ni = 0; ni < 4; ++ni)
#pragma unroll
      for (int s = 0; s < 2; ++s)
        acc[ni] = MFMA(xf[s], ldt(Gh, 16 * ni + fr, s), acc[ni], 0, 0, 0);
#pragma unroll
    for (int ni = 0; ni < 4; ++ni)
#pragma unroll
      for (int rg = 0; rg < 4; ++rg)
        Gl[16 * w + orow + rg][16 * ni + fr] = f2bf(acc[ni][rg]);
  }
  __syncthreads();

  // ---- ph5: app4 (Y = Gl = N^8) ; load Q -> Qh(Ab)/Ql(Gh) ----
  appS(Ut, Gl);
  appS(Wt, Gl);
  for (int i = tid; i < 4096; i += 256) {
    int r = i >> 6, d = i & 63;
    float qv = Qg[gidx(r, d)];
    u16 hb = f2bf(qv);
    Ab[r][d] = hb;
    Gh[r][d] = f2bf(qv - bf2f(hb));
  }
  __syncthreads();

  // ---- ph6: P = W^T K, R = Ubar^T K (strided Ks as Y); S = Q K^T -> regs ----
  const size_t base = ((size_t)c * H_ + h) * 4096;
  {
    short8 xh[2], xl[2];
#pragma unroll
    for (int s = 0; s < 2; ++s) ldf(Wt, xr, s, xh[s], xl[s]);
    f32x4 acc[4];
#pragma unroll
    for (int ni = 0; ni < 4; ++ni) acc[ni] = (f32x4){0.f, 0.f, 0.f, 0.f};
#pragma unroll
    for (int ni = 0; ni < 4; ++ni)
#pragma unroll
      for (int s = 0; s < 2; ++s) {
        short8 yf = ldt(Ks, 16 * ni + fr, s);
        acc[ni] = MFMA(xh[s], yf, acc[ni], 0, 0, 0);
        acc[ni] = MFMA(xl[s], yf, acc[ni], 0, 0, 0);
      }
#pragma unroll
    for (int ni = 0; ni < 4; ++ni)
#pragma unroll
      for (int rg = 0; rg < 4; ++rg)
        stv(&Pg[base + (16 * w + orow + rg) * 64 + 16 * ni + fr], acc[ni][rg]);
  }
  {
    short8 xh[2], xl[2];
#pragma unroll
    for (int s = 0; s < 2; ++s) ldf(Ut, xr, s, xh[s], xl[s]);
    f32x4 acc[4];
#pragma unroll
    for (int ni = 0; ni < 4; ++ni) acc[ni] = (f32x4){0.f, 0.f, 0.f, 0.f};
#pragma unroll
    for (int ni = 0; ni < 4; ++ni)
#pragma unroll
      for (int s = 0; s < 2; ++s) {
        short8 yf = ldt(Ks, 16 * ni + fr, s);
        acc[ni] = MFMA(xh[s], yf, acc[ni], 0, 0, 0);
        acc[ni] = MFMA(xl[s], yf, acc[ni], 0, 0, 0);
      }
#pragma unroll
    for (int ni = 0; ni < 4; ++ni)
#pragma unroll
      for (int rg = 0; rg < 4; ++rg)
        stv(&Rg[base + (16 * w + orow + rg) * 64 + 16 * ni + fr], acc[ni][rg]);
  }
  float sreg[4][4];
  {
    short8 xh[2], xl[2];
#pragma unroll
    for (int s = 0; s < 2; ++s) {
      xh[s] = ldb(Ab, xr, s);  // Qh
      xl[s] = ldb(Gh, xr, s);  // Ql
    }
    f32x4 acc[4];
#pragma unroll
    for (int ni = 0; ni < 4; ++ni) acc[ni] = (f32x4){0.f, 0.f, 0.f, 0.f};
#pragma unroll
    for (int ni = 0; ni < 4; ++ni)
#pragma unroll
      for (int s = 0; s < 2; ++s) {
        short8 yf = ldb(Ks, 16 * ni + fr, s);
        acc[ni] = MFMA(xh[s], yf, acc[ni], 0, 0, 0);
        acc[ni] = MFMA(xl[s], yf, acc[ni], 0, 0, 0);
      }
#pragma unroll
    for (int ni = 0; ni < 4; ++ni)
#pragma unroll
      for (int rg = 0; rg < 4; ++rg) {
        int r = 16 * w + orow + rg, cc = 16 * ni + fr;
        sreg[ni][rg] = ((r >> 2) >= (cc >> 2)) ? acc[ni][rg] : 0.f;
      }
  }
  __syncthreads();

  // ---- ph7: Sm h/l -> Gl / Ks ----
#pragma unroll
  for (int ni = 0; ni < 4; ++ni)
#pragma unroll
    for (int rg = 0; rg < 4; ++rg) {
      int r = 16 * w + orow + rg, cc = 16 * ni + fr;
      u16 hb = f2bf(sreg[ni][rg]);
      Gl[r][cc] = hb;
      Ks[r][cc] = f2bf(sreg[ni][rg] - bf2f(hb));
    }
  __syncthreads();

  // ---- ph8: E = Q - Sm*W -> Qg ; F = Sm*Ubar -> Vg ----
  {
    short8 xh[2], xl[2];
#pragma unroll
    for (int s = 0; s < 2; ++s) {
      xh[s] = ldb(Gl, xr, s);
      xl[s] = ldb(Ks, xr, s);
    }
    f32x4 accE[4], accF[4];
#pragma unroll
    for (int ni = 0; ni < 4; ++ni) {
      accE[ni] = (f32x4){0.f, 0.f, 0.f, 0.f};
      accF[ni] = (f32x4){0.f, 0.f, 0.f, 0.f};
    }
#pragma unroll
    for (int ni = 0; ni < 4; ++ni)
#pragma unroll
      for (int s = 0; s < 2; ++s) {
        short8 yh, yl;
        ldf(Wt, 16 * ni + fr, s, yh, yl);
        accE[ni] = MFMA(xh[s], yh, accE[ni], 0, 0, 0);
        accE[ni] = MFMA(xh[s], yl, accE[ni], 0, 0, 0);
        accE[ni] = MFMA(xl[s], yh, accE[ni], 0, 0, 0);
        ldf(Ut, 16 * ni + fr, s, yh, yl);
        accF[ni] = MFMA(xh[s], yh, accF[ni], 0, 0, 0);
        accF[ni] = MFMA(xh[s], yl, accF[ni], 0, 0, 0);
        accF[ni] = MFMA(xl[s], yh, accF[ni], 0, 0, 0);
      }
#pragma unroll
    for (int ni = 0; ni < 4; ++ni)
#pragma unroll
      for (int rg = 0; rg < 4; ++rg) {
        int r = 16 * w + orow + rg, d = 16 * ni + fr;
        size_t g = gidx(r, d);
        float qv = bf2f(Ab[r][d]) + bf2f(Gh[r][d]);
        Qg[g] = qv - accE[ni][rg];
        Vg[g] = f2bf(accF[ni][rg]);
      }
  }
}

// ---------------- 64x64 fp32 helpers (levels) ----------------
__device__ __forceinline__ void load64(float (*dst)[65], const float* src, int tid) {
  for (int i = tid; i < 4096; i += 256) dst[i >> 6][i & 63] = src[i];
}
__device__ __forceinline__ void store64(float* dst, const float (*src)[65], int tid) {
  for (int i = tid; i < 4096; i += 256) dst[i] = src[i >> 6][i & 63];
}
template<typename PT>
__device__ __forceinline__ void loadPfull(float (*dst)[65], const PT* src, int tid) {
  for (int i = tid; i < 4096; i += 256) {
    int r = i >> 6, cc = i & 63;
    dst[r][cc] = ((r == cc) ? 1.f : 0.f) - ldv(src[i]);
  }
}
template<typename PT>
__device__ __forceinline__ void loadR(float (*dst)[65], const PT* src, int tid) {
  for (int i = tid; i < 4096; i += 256) dst[i >> 6][i & 63] = ldv(src[i]);
}
__device__ __forceinline__ void mm64(const float (*X)[65], const float (*Y)[65],
                                     float (*Dst)[65], const float (*Add)[65], int tid) {
  const int r0 = (tid >> 4) * 4, c0 = (tid & 15) * 4;
  float a[4][4] = {};
  for (int d = 0; d < 64; ++d) {
    float xv[4], yv[4];
#pragma unroll
    for (int i = 0; i < 4; ++i) xv[i] = X[r0 + i][d];
#pragma unroll
    for (int j = 0; j < 4; ++j) yv[j] = Y[d][c0 + j];
#pragma unroll
    for (int i = 0; i < 4; ++i)
#pragma unroll
      for (int j = 0; j < 4; ++j) a[i][j] += xv[i] * yv[j];
  }
  __syncthreads();
#pragma unroll
  for (int i = 0; i < 4; ++i)
#pragma unroll
    for (int j = 0; j < 4; ++j) {
      float v = a[i][j];
      if (Add) v += Add[r0 + i][c0 + j];
      Dst[r0 + i][c0 + j] = v;
    }
  __syncthreads();
}

template<typename PT>
__global__ __launch_bounds__(256) void seq_levelA(const PT* __restrict__ Pg,
    const PT* __restrict__ Rg, float* __restrict__ Psup, float* __restrict__ Rsup) {
  __shared__ float Pa[64][65], Ra[64][65], Pi[64][65], Ri[64][65];
  const int sup = blockIdx.x, h = blockIdx.y, tid = threadIdx.x;
  const int cbase = sup * SUPW;
  loadPfull(Pa, Pg + ((size_t)cbase * H_ + h) * 4096, tid);
  loadR(Ra, Rg + ((size_t)cbase * H_ + h) * 4096, tid);
  __syncthreads();
  for (int s = 1; s < SUPW; ++s) {
    loadPfull(Pi, Pg + ((size_t)(cbase + s) * H_ + h) * 4096, tid);
    loadR(Ri, Rg + ((size_t)(cbase + s) * H_ + h) * 4096, tid);
    __syncthreads();
    mm64(Pa, Pi, Pa, nullptr, tid);
    mm64(Ra, Pi, Ra, Ri, tid);
  }
  store64(Psup + ((size_t)sup * H_ + h) * 4096, Pa, tid);
  store64(Rsup + ((size_t)sup * H_ + h) * 4096, Ra, tid);
}

__global__ __launch_bounds__(256) void seq_levelB(const float* __restrict__ Psup,
    const float* __restrict__ Rsup, float* __restrict__ Msup) {
  __shared__ float Ms[64][65], Pi[64][65], Ri[64][65];
  const int h = blockIdx.x, tid = threadIdx.x;
  for (int i = tid; i < 4096; i += 256) Ms[i >> 6][i & 63] = 0.f;
  __syncthreads();
  for (int s = 0; s < NSUP; ++s) {
    store64(Msup + ((size_t)s * H_ + h) * 4096, Ms, tid);
    load64(Pi, Psup + ((size_t)s * H_ + h) * 4096, tid);
    load64(Ri, Rsup + ((size_t)s * H_ + h) * 4096, tid);
    __syncthreads();
    mm64(Ms, Pi, Ms, Ri, tid);
  }
}

template<typename PT>
__global__ __launch_bounds__(256) void seq_levelC(const PT* __restrict__ Pg,
    PT* __restrict__ Rg, const float* __restrict__ Msup) {
  __shared__ float Ms[64][65], Pi[64][65], Ri[64][65];
  const int sup = blockIdx.x, h = blockIdx.y, tid = threadIdx.x;
  load64(Ms, Msup + ((size_t)sup * H_ + h) * 4096, tid);
  __syncthreads();
  for (int s = 0; s < SUPW; ++s) {
    const size_t slice = ((size_t)(sup * SUPW + s) * H_ + h) * 4096;
    loadPfull(Pi, Pg + slice, tid);
    loadR(Ri, Rg + slice, tid);
    __syncthreads();
    for (int i = tid; i < 4096; i += 256) stv(&Rg[slice + i], Ms[i >> 6][i & 63]);
    mm64(Ms, Pi, Ms, Ri, tid);
  }
}

// ---------------- phase 3: attn = E*M0^T + F (bf16 out) ----------------
template<typename PT>
__global__ __launch_bounds__(256) void phase3_kernel(
    const float* __restrict__ Eg, const u16* __restrict__ Fg,
    const PT* __restrict__ Mcg, u16* __restrict__ attn) {
  __shared__ float Es[64][65], Ms[64][65];
  const int c = blockIdx.x, h = blockIdx.y, tid = threadIdx.x;
  for (int i = tid; i < 4096; i += 256) {
    int r = i >> 6, d = i & 63, t = r >> 2, b = r & 3;
    size_t g = ((size_t)b * S_ + (size_t)c * CHUNK + t) * D_ + h * 64 + d;
    Es[r][d] = Eg[g];
    Ms[i >> 6][i & 63] = ldv(Mcg[((size_t)c * H_ + h) * 4096 + i]);
  }
  __syncthreads();
  const int r0 = (tid >> 4) * 4, d0 = (tid & 15) * 4;
  float a[4][4] = {};
  for (int k = 0; k < 64; ++k) {
    float ev[4], mv[4];
#pragma unroll
    for (int i = 0; i < 4; ++i) ev[i] = Es[r0 + i][k];
#pragma unroll
    for (int j = 0; j < 4; ++j) mv[j] = Ms[d0 + j][k];
#pragma unroll
    for (int i = 0; i < 4; ++i)
#pragma unroll
      for (int j = 0; j < 4; ++j) a[i][j] += ev[i] * mv[j];
  }
#pragma unroll
  for (int i = 0; i < 4; ++i)
#pragma unroll
    for (int j = 0; j < 4; ++j) {
      int r = r0 + i, d = d0 + j, t = r >> 2, b = r & 3;
      size_t g = ((size_t)b * S_ + (size_t)c * CHUNK + t) * D_ + h * 64 + d;
      attn[g] = f2bf(a[i][j] + bf2f(Fg[g]));
    }
}

// ---------------- launch ----------------
extern "C" void kernel_launch(void* const* d_in, const int* in_sizes, int n_in,
                              void* d_out, int out_size, void* d_ws, size_t ws_size,
                              hipStream_t stream) {
  (void)in_sizes; (void)n_in; (void)out_size;
  const float* x  = (const float*)d_in[0];
  const float* Wq = (const float*)d_in[1];
  const float* Wk = (const float*)d_in[2];
  const float* Wv = (const float*)d_in[3];
  const float* Wo = (const float*)d_in[4];
  float* out = (float*)d_out;

  char* w = (char*)d_ws;
  const size_t MB = 1024 * 1024;
  u16* Kbf = (u16*)w;                    // 32MB; -> smalls after phase1
  u16* Vbf = (u16*)(w + 32 * MB);        // 32MB; -> F
  void* Preg = (void*)(w + 64 * MB);     // 64MB fp32 | 32MB bf16; -> attn
  const bool big = ws_size >= 192 * MB;
  void* Rreg = big ? (void*)(w + 128 * MB) : (void*)(w + 96 * MB);
  float* Psup = (float*)w;
  float* Rsup = (float*)(w + 4 * MB);
  float* Msup = (float*)(w + 8 * MB);
  u16* attn = (u16*)Preg;

  dim3 gg(128, 8);
  gemm_k<1, float><<<gg, 256, 0, stream>>>(x, Wq, out, 16384, 1024, 1024);
  gemm_k<1, u16><<<gg, 256, 0, stream>>>(x, Wk, Kbf, 16384, 1024, 1024);
  gemm_k<1, u16><<<gg, 256, 0, stream>>>(x, Wv, Vbf, 16384, 1024, 1024);

  if (big) {
    float* P = (float*)Preg; float* R = (float*)Rreg;
    phase1_kernel<float><<<dim3(NCHUNK, H_), 256, 0, stream>>>(out, Kbf, Vbf, P, R);
    seq_levelA<float><<<dim3(NSUP, H_), 256, 0, stream>>>(P, R, Psup, Rsup);
    seq_levelB<<<dim3(H_), 256, 0, stream>>>(Psup, Rsup, Msup);
    seq_levelC<float><<<dim3(NSUP, H_), 256, 0, stream>>>(P, R, Msup);
    phase3_kernel<float><<<dim3(NCHUNK, H_), 256, 0, stream>>>(out, Vbf, R, attn);
  } else {
    u16* P = (u16*)Preg; u16* R = (u16*)Rreg;
    phase1_kernel<u16><<<dim3(NCHUNK, H_), 256, 0, stream>>>(out, Kbf, Vbf, P, R);
    seq_levelA<u16><<<dim3(NSUP, H_), 256, 0, stream>>>(P, R, Psup, Rsup);
    seq_levelB<<<dim3(H_), 256, 0, stream>>>(Psup, Rsup, Msup);
    seq_levelC<u16><<<dim3(NSUP, H_), 256, 0, stream>>>(P, R, Msup);
    phase3_kernel<u16><<<dim3(NCHUNK, H_), 256, 0, stream>>>(out, Vbf, R, attn);
  }
  gemm_k<0, float><<<gg, 256, 0, stream>>>(attn, Wo, out, 16384, 1024, 1024);
}

// Round 5
// 999.574 us; speedup vs baseline: 1.3854x; 1.0872x over previous
//
#include <hip/hip_runtime.h>

// L2RegressionAttention — chunked WY-transform. GEMMs read PRE-SPLIT bf16 hi/lo
// A (and B when ws allows) with explicit reg->LDS staging (round-3-proven
// mechanics; no global_load_lds this round — it raced under graph replay).
// B=4, S=4096, D=1024, H=16, hd=64, eta = 0.1/4 = 0.025.

typedef unsigned short u16;
typedef __attribute__((ext_vector_type(8))) short short8;
typedef __attribute__((ext_vector_type(4))) float f32x4;

#define B_ 4
#define S_ 4096
#define D_ 1024
#define H_ 16
#define CHUNK 16
#define NCHUNK 256
#define SUPW 16
#define NSUP 16
#define ETA 0.025f

__device__ __forceinline__ u16 f2bf(float f) {
  unsigned u = __builtin_bit_cast(unsigned, f);
  u += 0x7fffu + ((u >> 16) & 1u);
  return (u16)(u >> 16);
}
__device__ __forceinline__ float bf2f(u16 s) {
  unsigned u = ((unsigned)s) << 16;
  return __builtin_bit_cast(float, u);
}
__device__ __forceinline__ float ldv(float v) { return v; }
__device__ __forceinline__ float ldv(u16 v) { return bf2f(v); }
__device__ __forceinline__ void stv(float* p, float v) { *p = v; }
__device__ __forceinline__ void stv(u16* p, float v) { *p = f2bf(v); }

#define MFMA __builtin_amdgcn_mfma_f32_16x16x32_bf16

// ---------------- fp32 -> (hi, lo) bf16 split, float4-vectorized ----------------
__global__ void split4_kernel(const float* __restrict__ x, u16* __restrict__ hi,
                              u16* __restrict__ lo, int n4) {
  int i = blockIdx.x * blockDim.x + threadIdx.x;
  int stride = gridDim.x * blockDim.x;
  for (; i < n4; i += stride) {
    float4 v = ((const float4*)x)[i];
    ushort4 h, l;
    h.x = f2bf(v.x); l.x = f2bf(v.x - bf2f(h.x));
    h.y = f2bf(v.y); l.y = f2bf(v.y - bf2f(h.y));
    h.z = f2bf(v.z); l.z = f2bf(v.z - bf2f(h.z));
    h.w = f2bf(v.w); l.w = f2bf(v.w - bf2f(h.w));
    ((ushort4*)hi)[i] = h;
    ((ushort4*)lo)[i] = l;
  }
}

// ---------------- GEMM: C[M][N] = A * B^T ----------------
// A: pre-split bf16 (Ah, +Al if AP==2), explicit uint4 reg->LDS staging.
// B: BPRE=1 -> pre-split bf16 hi/lo; BPRE=0 -> fp32, split on the fly.
// Combos: ah*bh + ah*bl (+ al*bh if AP==2). 128x128 tile, BK=32, 4 waves.
template<int AP, int BPRE, typename OutT>
__global__ __launch_bounds__(256) void gemm_axw(
    const u16* __restrict__ Ahg, const u16* __restrict__ Alg,
    const void* __restrict__ Bhp, const u16* __restrict__ Blg,
    OutT* __restrict__ C, int M, int N, int K) {
  __shared__ __align__(16) u16 Ahs[128][32];
  __shared__ __align__(16) u16 Als[AP == 2 ? 128 : 1][32];
  __shared__ __align__(16) u16 Bhs[128][32];
  __shared__ __align__(16) u16 Bls[128][32];
  const int tid = threadIdx.x, w = tid >> 6, lane = tid & 63;
  const int bm = blockIdx.x * 128, bn = blockIdx.y * 128;
  const int wm = (w >> 1) * 64, wn = (w & 1) * 64;
  const int fr = lane & 15, kb = lane >> 4;

  f32x4 acc[4][4];
#pragma unroll
  for (int i = 0; i < 4; ++i)
#pragma unroll
    for (int j = 0; j < 4; ++j) acc[i][j] = (f32x4){0.f, 0.f, 0.f, 0.f};

  for (int k0 = 0; k0 < K; k0 += 32) {
    __syncthreads();  // prior frag reads complete before overwrite
    // stage A (bf16 pre-split): 128 rows x 32 u16 per buffer, uint4 chunks
#pragma unroll
    for (int i = 0; i < 2; ++i) {
      int e = tid + i * 256;             // 0..511
      int r = e >> 2, sg = (e & 3) * 8;  // 8 u16 = 16B
      *(uint4*)(&Ahs[r][sg]) = *(const uint4*)(&Ahg[(size_t)(bm + r) * K + k0 + sg]);
      if constexpr (AP == 2)
        *(uint4*)(&Als[r][sg]) = *(const uint4*)(&Alg[(size_t)(bm + r) * K + k0 + sg]);
    }
    if constexpr (BPRE) {
      const u16* Bhg = (const u16*)Bhp;
#pragma unroll
      for (int i = 0; i < 2; ++i) {
        int e = tid + i * 256;
        int r = e >> 2, sg = (e & 3) * 8;
        *(uint4*)(&Bhs[r][sg]) = *(const uint4*)(&Bhg[(size_t)(bn + r) * K + k0 + sg]);
        *(uint4*)(&Bls[r][sg]) = *(const uint4*)(&Blg[(size_t)(bn + r) * K + k0 + sg]);
      }
    } else {
      const float* Bm = (const float*)Bhp;
#pragma unroll
      for (int i = 0; i < 4; ++i) {
        int e = tid + i * 256, r = e >> 3, sg = (e & 7) * 4;
        float4 v = *(const float4*)(&Bm[(size_t)(bn + r) * K + k0 + sg]);
        ushort4 h, l;
        h.x = f2bf(v.x); l.x = f2bf(v.x - bf2f(h.x));
        h.y = f2bf(v.y); l.y = f2bf(v.y - bf2f(h.y));
        h.z = f2bf(v.z); l.z = f2bf(v.z - bf2f(h.z));
        h.w = f2bf(v.w); l.w = f2bf(v.w - bf2f(h.w));
        *(ushort4*)(&Bhs[r][sg]) = h;
        *(ushort4*)(&Bls[r][sg]) = l;
      }
    }
    __syncthreads();  // tiles ready
    short8 ah[4], al[4], bh[4], bl[4];
#pragma unroll
    for (int mi = 0; mi < 4; ++mi) {
      ah[mi] = *(const short8*)(&Ahs[wm + mi * 16 + fr][kb * 8]);
      if constexpr (AP == 2) al[mi] = *(const short8*)(&Als[wm + mi * 16 + fr][kb * 8]);
    }
#pragma unroll
    for (int ni = 0; ni < 4; ++ni) {
      bh[ni] = *(const short8*)(&Bhs[wn + ni * 16 + fr][kb * 8]);
      bl[ni] = *(const short8*)(&Bls[wn + ni * 16 + fr][kb * 8]);
    }
#pragma unroll
    for (int mi = 0; mi < 4; ++mi)
#pragma unroll
      for (int ni = 0; ni < 4; ++ni) {
        acc[mi][ni] = MFMA(ah[mi], bh[ni], acc[mi][ni], 0, 0, 0);
        acc[mi][ni] = MFMA(ah[mi], bl[ni], acc[mi][ni], 0, 0, 0);
        if constexpr (AP == 2)
          acc[mi][ni] = MFMA(al[mi], bh[ni], acc[mi][ni], 0, 0, 0);
      }
  }
  const int fc = lane & 15, fr4 = (lane >> 4) * 4;
#pragma unroll
  for (int mi = 0; mi < 4; ++mi)
#pragma unroll
    for (int ni = 0; ni < 4; ++ni) {
      int gm = bm + wm + mi * 16 + fr4;
      int gn = bn + wn + ni * 16 + fc;
#pragma unroll
      for (int rg = 0; rg < 4; ++rg)
        stv(&C[(size_t)(gm + rg) * N + gn], acc[mi][ni][rg]);
    }
}

// ---------------- phase 1 (MFMA): per (chunk, head) WY solve ----------------
template<typename PT>
__global__ __launch_bounds__(256) void phase1_kernel(
    float* __restrict__ Qg, const u16* __restrict__ Kg, u16* __restrict__ Vg,
    PT* __restrict__ Pg, PT* __restrict__ Rg) {
  __shared__ __align__(16) u16 Ks[64][72];
  __shared__ __align__(16) u16 Gh[64][72];
  __shared__ __align__(16) u16 Gl[64][72];
  __shared__ __align__(16) u16 Ab[64][72];
  __shared__ __align__(16) float Ut[64][68];
  __shared__ __align__(16) float Wt[64][68];

  const int c = blockIdx.x, h = blockIdx.y, tid = threadIdx.x;
  const int w = tid >> 6, lane = tid & 63;
  const int fr = lane & 15, kq = lane >> 4, orow = kq * 4;
  const int xr = 16 * w + fr;

  auto gidx = [&](int r, int d) -> size_t {
    return ((size_t)(r & 3) * S_ + (size_t)c * CHUNK + (r >> 2)) * D_ + h * 64 + d;
  };
  auto ldb = [&](const u16 (*M)[72], int row, int s) -> short8 {
    return *(const short8*)(&M[row][32 * s + 8 * kq]);
  };
  auto ldm = [&](const u16 (*M)[72], int row, int s, bool up) -> short8 {
    short8 r = *(const short8*)(&M[row][32 * s + 8 * kq]);
    int rb = row >> 2, k0 = 32 * s + 8 * kq;
#pragma unroll
    for (int j = 0; j < 8; ++j) {
      int kb2 = (k0 + j) >> 2;
      bool keep = up ? (kb2 > rb) : (rb > kb2);
      if (!keep) r[j] = 0;
    }
    return r;
  };
  auto ldt = [&](const u16 (*M)[72], int col, int s) -> short8 {
    short8 r;
    int k0 = 32 * s + 8 * kq;
#pragma unroll
    for (int j = 0; j < 8; ++j) r[j] = (short)M[k0 + j][col];
    return r;
  };
  auto ldf = [&](const float (*M)[68], int row, int s, short8& hh, short8& ll) {
    const float* p = &M[row][32 * s + 8 * kq];
#pragma unroll
    for (int j = 0; j < 8; ++j) {
      float v = p[j];
      u16 hb = f2bf(v);
      hh[j] = (short)hb;
      ll[j] = (short)f2bf(v - bf2f(hb));
    }
  };
  auto ldfh = [&](const float (*M)[68], int row, int s) -> short8 {
    const float* p = &M[row][32 * s + 8 * kq];
    short8 hh;
#pragma unroll
    for (int j = 0; j < 8; ++j) hh[j] = (short)f2bf(p[j]);
    return hh;
  };

  for (int i = tid; i < 4096; i += 256) {
    int r = i >> 6, d = i & 63;
    size_t g = gidx(r, d);
    u16 kraw = Kg[g];
    Ks[r][d] = kraw;
    Wt[d][r] = ETA * bf2f(kraw);
    Ut[d][r] = ETA * bf2f(Vg[g]);
  }
  __syncthreads();

  {
    f32x4 acc[4];
#pragma unroll
    for (int ni = 0; ni < 4; ++ni) acc[ni] = (f32x4){0.f, 0.f, 0.f, 0.f};
    short8 xf[2];
#pragma unroll
    for (int s = 0; s < 2; ++s) xf[s] = ldb(Ks, xr, s);
#pragma unroll
    for (int ni = 0; ni < 4; ++ni)
#pragma unroll
      for (int s = 0; s < 2; ++s)
        acc[ni] = MFMA(xf[s], ldb(Ks, 16 * ni + fr, s), acc[ni], 0, 0, 0);
#pragma unroll
    for (int ni = 0; ni < 4; ++ni)
#pragma unroll
      for (int rg = 0; rg < 4; ++rg) {
        float v = -ETA * acc[ni][rg];
        u16 hb = f2bf(v);
        int rr = 16 * w + orow + rg, cc = 16 * ni + fr;
        Gh[rr][cc] = hb;
        Gl[rr][cc] = f2bf(v - bf2f(hb));
      }
  }
  __syncthreads();

  auto app1 = [&](float (*St)[68]) {
    short8 xh[2], xl[2];
#pragma unroll
    for (int s = 0; s < 2; ++s) ldf(St, xr, s, xh[s], xl[s]);
    f32x4 acc[4];
#pragma unroll
    for (int ni = 0; ni < 4; ++ni) acc[ni] = (f32x4){0.f, 0.f, 0.f, 0.f};
#pragma unroll
    for (int ni = 0; ni < 4; ++ni)
#pragma unroll
      for (int s = 0; s < 2; ++s) {
        short8 yh = ldm(Gh, 16 * ni + fr, s, false);
        short8 yl = ldm(Gl, 16 * ni + fr, s, false);
        acc[ni] = MFMA(xh[s], yh, acc[ni], 0, 0, 0);
        acc[ni] = MFMA(xh[s], yl, acc[ni], 0, 0, 0);
        acc[ni] = MFMA(xl[s], yh, acc[ni], 0, 0, 0);
      }
#pragma unroll
    for (int ni = 0; ni < 4; ++ni)
#pragma unroll
      for (int rg = 0; rg < 4; ++rg)
        St[16 * w + orow + rg][16 * ni + fr] += acc[ni][rg];
  };
  auto appS = [&](float (*St)[68], const u16 (*Np)[72]) {
    short8 xh[2];
#pragma unroll
    for (int s = 0; s < 2; ++s) xh[s] = ldfh(St, xr, s);
    f32x4 acc[4];
#pragma unroll
    for (int ni = 0; ni < 4; ++ni) acc[ni] = (f32x4){0.f, 0.f, 0.f, 0.f};
#pragma unroll
    for (int ni = 0; ni < 4; ++ni)
#pragma unroll
      for (int s = 0; s < 2; ++s)
        acc[ni] = MFMA(xh[s], ldb(Np, 16 * ni + fr, s), acc[ni], 0, 0, 0);
#pragma unroll
    for (int ni = 0; ni < 4; ++ni)
#pragma unroll
      for (int rg = 0; rg < 4; ++rg)
        St[16 * w + orow + rg][16 * ni + fr] += acc[ni][rg];
  };

  app1(Ut);
  app1(Wt);
  {
    f32x4 acc[4];
#pragma unroll
    for (int ni = 0; ni < 4; ++ni) acc[ni] = (f32x4){0.f, 0.f, 0.f, 0.f};
    short8 xh[2], xl[2];
#pragma unroll
    for (int s = 0; s < 2; ++s) {
      xh[s] = ldm(Gh, xr, s, false);
      xl[s] = ldm(Gl, xr, s, false);
    }
#pragma unroll
    for (int ni = 0; ni < 4; ++ni)
#pragma unroll
      for (int s = 0; s < 2; ++s) {
        short8 yh = ldm(Gh, 16 * ni + fr, s, true);
        short8 yl = ldm(Gl, 16 * ni + fr, s, true);
        acc[ni] = MFMA(xh[s], yh, acc[ni], 0, 0, 0);
        acc[ni] = MFMA(xh[s], yl, acc[ni], 0, 0, 0);
        acc[ni] = MFMA(xl[s], yh, acc[ni], 0, 0, 0);
      }
#pragma unroll
    for (int ni = 0; ni < 4; ++ni)
#pragma unroll
      for (int rg = 0; rg < 4; ++rg)
        Ab[16 * w + orow + rg][16 * ni + fr] = f2bf(acc[ni][rg]);
  }
  __syncthreads();

  appS(Ut, Ab);
  appS(Wt, Ab);
  {
    f32x4 acc[4];
#pragma unroll
    for (int ni = 0; ni < 4; ++ni) acc[ni] = (f32x4){0.f, 0.f, 0.f, 0.f};
    short8 xf[2];
#pragma unroll
    for (int s = 0; s < 2; ++s) xf[s] = ldb(Ab, xr, s);
#pragma unroll
    for (int ni = 0; ni < 4; ++ni)
#pragma unroll
      for (int s = 0; s < 2; ++s)
        acc[ni] = MFMA(xf[s], ldt(Ab, 16 * ni + fr, s), acc[ni], 0, 0, 0);
#pragma unroll
    for (int ni = 0; ni < 4; ++ni)
#pragma unroll
      for (int rg = 0; rg < 4; ++rg)
        Gh[16 * w + orow + rg][16 * ni + fr] = f2bf(acc[ni][rg]);
  }
  __syncthreads();

  appS(Ut, Gh);
  appS(Wt, Gh);
  {
    f32x4 acc[4];
#pragma unroll
    for (int ni = 0; ni < 4; ++ni) acc[ni] = (f32x4){0.f, 0.f, 0.f, 0.f};
    short8 xf[2];
#pragma unroll
    for (int s = 0; s < 2; ++s) xf[s] = ldb(Gh, xr, s);
#pragma unroll
    for (int ni = 0; ni < 4; ++ni)
#pragma unroll
      for (int s = 0; s < 2; ++s)
        acc[ni] = MFMA(xf[s], ldt(Gh, 16 * ni + fr, s), acc[ni], 0, 0, 0);
#pragma unroll
    for (int ni = 0; ni < 4; ++ni)
#pragma unroll
      for (int rg = 0; rg < 4; ++rg)
        Gl[16 * w + orow + rg][16 * ni + fr] = f2bf(acc[ni][rg]);
  }
  __syncthreads();

  appS(Ut, Gl);
  appS(Wt, Gl);
  for (int i = tid; i < 4096; i += 256) {
    int r = i >> 6, d = i & 63;
    float qv = Qg[gidx(r, d)];
    u16 hb = f2bf(qv);
    Ab[r][d] = hb;
    Gh[r][d] = f2bf(qv - bf2f(hb));
  }
  __syncthreads();

  const size_t base = ((size_t)c * H_ + h) * 4096;
  {
    short8 xh[2], xl[2];
#pragma unroll
    for (int s = 0; s < 2; ++s) ldf(Wt, xr, s, xh[s], xl[s]);
    f32x4 acc[4];
#pragma unroll
    for (int ni = 0; ni < 4; ++ni) acc[ni] = (f32x4){0.f, 0.f, 0.f, 0.f};
#pragma unroll
    for (int ni = 0; ni < 4; ++ni)
#pragma unroll
      for (int s = 0; s < 2; ++s) {
        short8 yf = ldt(Ks, 16 * ni + fr, s);
        acc[ni] = MFMA(xh[s], yf, acc[ni], 0, 0, 0);
        acc[ni] = MFMA(xl[s], yf, acc[ni], 0, 0, 0);
      }
#pragma unroll
    for (int ni = 0; ni < 4; ++ni)
#pragma unroll
      for (int rg = 0; rg < 4; ++rg)
        stv(&Pg[base + (16 * w + orow + rg) * 64 + 16 * ni + fr], acc[ni][rg]);
  }
  {
    short8 xh[2], xl[2];
#pragma unroll
    for (int s = 0; s < 2; ++s) ldf(Ut, xr, s, xh[s], xl[s]);
    f32x4 acc[4];
#pragma unroll
    for (int ni = 0; ni < 4; ++ni) acc[ni] = (f32x4){0.f, 0.f, 0.f, 0.f};
#pragma unroll
    for (int ni = 0; ni < 4; ++ni)
#pragma unroll
      for (int s = 0; s < 2; ++s) {
        short8 yf = ldt(Ks, 16 * ni + fr, s);
        acc[ni] = MFMA(xh[s], yf, acc[ni], 0, 0, 0);
        acc[ni] = MFMA(xl[s], yf, acc[ni], 0, 0, 0);
      }
#pragma unroll
    for (int ni = 0; ni < 4; ++ni)
#pragma unroll
      for (int rg = 0; rg < 4; ++rg)
        stv(&Rg[base + (16 * w + orow + rg) * 64 + 16 * ni + fr], acc[ni][rg]);
  }
  float sreg[4][4];
  {
    short8 xh[2], xl[2];
#pragma unroll
    for (int s = 0; s < 2; ++s) {
      xh[s] = ldb(Ab, xr, s);
      xl[s] = ldb(Gh, xr, s);
    }
    f32x4 acc[4];
#pragma unroll
    for (int ni = 0; ni < 4; ++ni) acc[ni] = (f32x4){0.f, 0.f, 0.f, 0.f};
#pragma unroll
    for (int ni = 0; ni < 4; ++ni)
#pragma unroll
      for (int s = 0; s < 2; ++s) {
        short8 yf = ldb(Ks, 16 * ni + fr, s);
        acc[ni] = MFMA(xh[s], yf, acc[ni], 0, 0, 0);
        acc[ni] = MFMA(xl[s], yf, acc[ni], 0, 0, 0);
      }
#pragma unroll
    for (int ni = 0; ni < 4; ++ni)
#pragma unroll
      for (int rg = 0; rg < 4; ++rg) {
        int r = 16 * w + orow + rg, cc = 16 * ni + fr;
        sreg[ni][rg] = ((r >> 2) >= (cc >> 2)) ? acc[ni][rg] : 0.f;
      }
  }
  __syncthreads();

#pragma unroll
  for (int ni = 0; ni < 4; ++ni)
#pragma unroll
    for (int rg = 0; rg < 4; ++rg) {
      int r = 16 * w + orow + rg, cc = 16 * ni + fr;
      u16 hb = f2bf(sreg[ni][rg]);
      Gl[r][cc] = hb;
      Ks[r][cc] = f2bf(sreg[ni][rg] - bf2f(hb));
    }
  __syncthreads();

  {
    short8 xh[2], xl[2];
#pragma unroll
    for (int s = 0; s < 2; ++s) {
      xh[s] = ldb(Gl, xr, s);
      xl[s] = ldb(Ks, xr, s);
    }
    f32x4 accE[4], accF[4];
#pragma unroll
    for (int ni = 0; ni < 4; ++ni) {
      accE[ni] = (f32x4){0.f, 0.f, 0.f, 0.f};
      accF[ni] = (f32x4){0.f, 0.f, 0.f, 0.f};
    }
#pragma unroll
    for (int ni = 0; ni < 4; ++ni)
#pragma unroll
      for (int s = 0; s < 2; ++s) {
        short8 yh, yl;
        ldf(Wt, 16 * ni + fr, s, yh, yl);
        accE[ni] = MFMA(xh[s], yh, accE[ni], 0, 0, 0);
        accE[ni] = MFMA(xh[s], yl, accE[ni], 0, 0, 0);
        accE[ni] = MFMA(xl[s], yh, accE[ni], 0, 0, 0);
        ldf(Ut, 16 * ni + fr, s, yh, yl);
        accF[ni] = MFMA(xh[s], yh, accF[ni], 0, 0, 0);
        accF[ni] = MFMA(xh[s], yl, accF[ni], 0, 0, 0);
        accF[ni] = MFMA(xl[s], yh, accF[ni], 0, 0, 0);
      }
#pragma unroll
    for (int ni = 0; ni < 4; ++ni)
#pragma unroll
      for (int rg = 0; rg < 4; ++rg) {
        int r = 16 * w + orow + rg, d = 16 * ni + fr;
        size_t g = gidx(r, d);
        float qv = bf2f(Ab[r][d]) + bf2f(Gh[r][d]);
        Qg[g] = qv - accE[ni][rg];
        Vg[g] = f2bf(accF[ni][rg]);
      }
  }
}

// ---------------- 64x64 fp32 helpers (levels) ----------------
__device__ __forceinline__ void load64(float (*dst)[65], const float* src, int tid) {
  for (int i = tid; i < 4096; i += 256) dst[i >> 6][i & 63] = src[i];
}
__device__ __forceinline__ void store64(float* dst, const float (*src)[65], int tid) {
  for (int i = tid; i < 4096; i += 256) dst[i] = src[i >> 6][i & 63];
}
template<typename PT>
__device__ __forceinline__ void loadPfull(float (*dst)[65], const PT* src, int tid) {
  for (int i = tid; i < 4096; i += 256) {
    int r = i >> 6, cc = i & 63;
    dst[r][cc] = ((r == cc) ? 1.f : 0.f) - ldv(src[i]);
  }
}
template<typename PT>
__device__ __forceinline__ void loadR(float (*dst)[65], const PT* src, int tid) {
  for (int i = tid; i < 4096; i += 256) dst[i >> 6][i & 63] = ldv(src[i]);
}
__device__ __forceinline__ void mm64(const float (*X)[65], const float (*Y)[65],
                                     float (*Dst)[65], const float (*Add)[65], int tid) {
  const int r0 = (tid >> 4) * 4, c0 = (tid & 15) * 4;
  float a[4][4] = {};
  for (int d = 0; d < 64; ++d) {
    float xv[4], yv[4];
#pragma unroll
    for (int i = 0; i < 4; ++i) xv[i] = X[r0 + i][d];
#pragma unroll
    for (int j = 0; j < 4; ++j) yv[j] = Y[d][c0 + j];
#pragma unroll
    for (int i = 0; i < 4; ++i)
#pragma unroll
      for (int j = 0; j < 4; ++j) a[i][j] += xv[i] * yv[j];
  }
  __syncthreads();
#pragma unroll
  for (int i = 0; i < 4; ++i)
#pragma unroll
    for (int j = 0; j < 4; ++j) {
      float v = a[i][j];
      if (Add) v += Add[r0 + i][c0 + j];
      Dst[r0 + i][c0 + j] = v;
    }
  __syncthreads();
}

template<typename PT>
__global__ __launch_bounds__(256) void seq_levelA(const PT* __restrict__ Pg,
    const PT* __restrict__ Rg, float* __restrict__ Psup, float* __restrict__ Rsup) {
  __shared__ float Pa[64][65], Ra[64][65], Pi[64][65], Ri[64][65];
  const int sup = blockIdx.x, h = blockIdx.y, tid = threadIdx.x;
  const int cbase = sup * SUPW;
  loadPfull(Pa, Pg + ((size_t)cbase * H_ + h) * 4096, tid);
  loadR(Ra, Rg + ((size_t)cbase * H_ + h) * 4096, tid);
  __syncthreads();
  for (int s = 1; s < SUPW; ++s) {
    loadPfull(Pi, Pg + ((size_t)(cbase + s) * H_ + h) * 4096, tid);
    loadR(Ri, Rg + ((size_t)(cbase + s) * H_ + h) * 4096, tid);
    __syncthreads();
    mm64(Pa, Pi, Pa, nullptr, tid);
    mm64(Ra, Pi, Ra, Ri, tid);
  }
  store64(Psup + ((size_t)sup * H_ + h) * 4096, Pa, tid);
  store64(Rsup + ((size_t)sup * H_ + h) * 4096, Ra, tid);
}

__global__ __launch_bounds__(256) void seq_levelB(const float* __restrict__ Psup,
    const float* __restrict__ Rsup, float* __restrict__ Msup) {
  __shared__ float Ms[64][65], Pi[64][65], Ri[64][65];
  const int h = blockIdx.x, tid = threadIdx.x;
  for (int i = tid; i < 4096; i += 256) Ms[i >> 6][i & 63] = 0.f;
  __syncthreads();
  for (int s = 0; s < NSUP; ++s) {
    store64(Msup + ((size_t)s * H_ + h) * 4096, Ms, tid);
    load64(Pi, Psup + ((size_t)s * H_ + h) * 4096, tid);
    load64(Ri, Rsup + ((size_t)s * H_ + h) * 4096, tid);
    __syncthreads();
    mm64(Ms, Pi, Ms, Ri, tid);
  }
}

template<typename PT>
__global__ __launch_bounds__(256) void seq_levelC(const PT* __restrict__ Pg,
    PT* __restrict__ Rg, const float* __restrict__ Msup) {
  __shared__ float Ms[64][65], Pi[64][65], Ri[64][65];
  const int sup = blockIdx.x, h = blockIdx.y, tid = threadIdx.x;
  load64(Ms, Msup + ((size_t)sup * H_ + h) * 4096, tid);
  __syncthreads();
  for (int s = 0; s < SUPW; ++s) {
    const size_t slice = ((size_t)(sup * SUPW + s) * H_ + h) * 4096;
    loadPfull(Pi, Pg + slice, tid);
    loadR(Ri, Rg + slice, tid);
    __syncthreads();
    for (int i = tid; i < 4096; i += 256) stv(&Rg[slice + i], Ms[i >> 6][i & 63]);
    mm64(Ms, Pi, Ms, Ri, tid);
  }
}

// ---------------- phase 3: attn = E*M0^T + F (bf16 out) ----------------
template<typename PT>
__global__ __launch_bounds__(256) void phase3_kernel(
    const float* __restrict__ Eg, const u16* __restrict__ Fg,
    const PT* __restrict__ Mcg, u16* __restrict__ attn) {
  __shared__ float Es[64][65], Ms[64][65];
  const int c = blockIdx.x, h = blockIdx.y, tid = threadIdx.x;
  for (int i = tid; i < 4096; i += 256) {
    int r = i >> 6, d = i & 63, t = r >> 2, b = r & 3;
    size_t g = ((size_t)b * S_ + (size_t)c * CHUNK + t) * D_ + h * 64 + d;
    Es[r][d] = Eg[g];
    Ms[i >> 6][i & 63] = ldv(Mcg[((size_t)c * H_ + h) * 4096 + i]);
  }
  __syncthreads();
  const int r0 = (tid >> 4) * 4, d0 = (tid & 15) * 4;
  float a[4][4] = {};
  for (int k = 0; k < 64; ++k) {
    float ev[4], mv[4];
#pragma unroll
    for (int i = 0; i < 4; ++i) ev[i] = Es[r0 + i][k];
#pragma unroll
    for (int j = 0; j < 4; ++j) mv[j] = Ms[d0 + j][k];
#pragma unroll
    for (int i = 0; i < 4; ++i)
#pragma unroll
      for (int j = 0; j < 4; ++j) a[i][j] += ev[i] * mv[j];
  }
#pragma unroll
  for (int i = 0; i < 4; ++i)
#pragma unroll
    for (int j = 0; j < 4; ++j) {
      int r = r0 + i, d = d0 + j, t = r >> 2, b = r & 3;
      size_t g = ((size_t)b * S_ + (size_t)c * CHUNK + t) * D_ + h * 64 + d;
      attn[g] = f2bf(a[i][j] + bf2f(Fg[g]));
    }
}

// ---------------- launch ----------------
extern "C" void kernel_launch(void* const* d_in, const int* in_sizes, int n_in,
                              void* d_out, int out_size, void* d_ws, size_t ws_size,
                              hipStream_t stream) {
  (void)in_sizes; (void)n_in; (void)out_size;
  const float* x  = (const float*)d_in[0];
  const float* Wq = (const float*)d_in[1];
  const float* Wk = (const float*)d_in[2];
  const float* Wv = (const float*)d_in[3];
  const float* Wo = (const float*)d_in[4];
  float* out = (float*)d_out;

  char* w = (char*)d_ws;
  const size_t MB = 1024 * 1024;
  // layout: [0,32) Kbf -> smalls ; [32,64) Vbf -> F ; [64,96) xh -> P/attn ;
  // [96,128) xl -> R/Mc ; big: P fp32 [64,128), R fp32 [128,192) ;
  // wpre: W splits [192,208)
  u16* Kbf = (u16*)w;
  u16* Vbf = (u16*)(w + 32 * MB);
  u16* xh  = (u16*)(w + 64 * MB);
  u16* xl  = (u16*)(w + 96 * MB);
  const bool big  = ws_size >= 192 * MB;
  const bool wpre = ws_size >= 208 * MB;
  void* Preg = (void*)(w + 64 * MB);
  void* Rreg = big ? (void*)(w + 128 * MB) : (void*)(w + 96 * MB);
  float* Psup = (float*)w;
  float* Rsup = (float*)(w + 4 * MB);
  float* Msup = (float*)(w + 8 * MB);
  u16* attn = (u16*)Preg;
  u16* Wsp = (u16*)(w + 192 * MB);  // hi/lo pairs: q +0/+1M, k +2/+3M, v +4/+5M, o +6/+7M

  const size_t DSZ = (size_t)B_ * S_ * D_;  // 16777216
  split4_kernel<<<2048, 256, 0, stream>>>(x, xh, xl, (int)(DSZ / 4));
  if (wpre) {
    split4_kernel<<<512, 256, 0, stream>>>(Wq, Wsp + 0 * 1048576u, Wsp + 1 * 1048576u, 262144);
    split4_kernel<<<512, 256, 0, stream>>>(Wk, Wsp + 2 * 1048576u, Wsp + 3 * 1048576u, 262144);
    split4_kernel<<<512, 256, 0, stream>>>(Wv, Wsp + 4 * 1048576u, Wsp + 5 * 1048576u, 262144);
    split4_kernel<<<512, 256, 0, stream>>>(Wo, Wsp + 6 * 1048576u, Wsp + 7 * 1048576u, 262144);
  }

  dim3 gg(128, 8);
  if (wpre) {
    gemm_axw<2, 1, float><<<gg, 256, 0, stream>>>(xh, xl, Wsp + 0 * 1048576u, Wsp + 1 * 1048576u, out, 16384, 1024, 1024);
    gemm_axw<2, 1, u16><<<gg, 256, 0, stream>>>(xh, xl, Wsp + 2 * 1048576u, Wsp + 3 * 1048576u, Kbf, 16384, 1024, 1024);
    gemm_axw<2, 1, u16><<<gg, 256, 0, stream>>>(xh, xl, Wsp + 4 * 1048576u, Wsp + 5 * 1048576u, Vbf, 16384, 1024, 1024);
  } else {
    gemm_axw<2, 0, float><<<gg, 256, 0, stream>>>(xh, xl, Wq, nullptr, out, 16384, 1024, 1024);
    gemm_axw<2, 0, u16><<<gg, 256, 0, stream>>>(xh, xl, Wk, nullptr, Kbf, 16384, 1024, 1024);
    gemm_axw<2, 0, u16><<<gg, 256, 0, stream>>>(xh, xl, Wv, nullptr, Vbf, 16384, 1024, 1024);
  }

  if (big) {
    float* P = (float*)Preg; float* R = (float*)Rreg;
    phase1_kernel<float><<<dim3(NCHUNK, H_), 256, 0, stream>>>(out, Kbf, Vbf, P, R);
    seq_levelA<float><<<dim3(NSUP, H_), 256, 0, stream>>>(P, R, Psup, Rsup);
    seq_levelB<<<dim3(H_), 256, 0, stream>>>(Psup, Rsup, Msup);
    seq_levelC<float><<<dim3(NSUP, H_), 256, 0, stream>>>(P, R, Msup);
    phase3_kernel<float><<<dim3(NCHUNK, H_), 256, 0, stream>>>(out, Vbf, R, attn);
  } else {
    u16* P = (u16*)Preg; u16* R = (u16*)Rreg;
    phase1_kernel<u16><<<dim3(NCHUNK, H_), 256, 0, stream>>>(out, Kbf, Vbf, P, R);
    seq_levelA<u16><<<dim3(NSUP, H_), 256, 0, stream>>>(P, R, Psup, Rsup);
    seq_levelB<<<dim3(H_), 256, 0, stream>>>(Psup, Rsup, Msup);
    seq_levelC<u16><<<dim3(NSUP, H_), 256, 0, stream>>>(P, R, Msup);
    phase3_kernel<u16><<<dim3(NCHUNK, H_), 256, 0, stream>>>(out, Vbf, R, attn);
  }
  if (wpre) {
    gemm_axw<1, 1, float><<<gg, 256, 0, stream>>>(attn, nullptr, Wsp + 6 * 1048576u, Wsp + 7 * 1048576u, out, 16384, 1024, 1024);
  } else {
    gemm_axw<1, 0, float><<<gg, 256, 0, stream>>>(attn, nullptr, Wo, nullptr, out, 16384, 1024, 1024);
  }
}

// Round 6
// 959.893 us; speedup vs baseline: 1.4426x; 1.0413x over previous
//
#include <hip/hip_runtime.h>

// L2RegressionAttention — chunked WY-transform.
// r6: all GEMM operands pre-split bf16 hi/lo (Wsp time-multiplexed into the R
// region at 192MB); phase1 restructured to eliminate all strided ldt reads
// (KsT at load + transpose dual-writes in the Neumann squaring chain + early S).
// B=4, S=4096, D=1024, H=16, hd=64, eta = 0.1/4 = 0.025.

typedef unsigned short u16;
typedef __attribute__((ext_vector_type(8))) short short8;
typedef __attribute__((ext_vector_type(4))) float f32x4;

#define B_ 4
#define S_ 4096
#define D_ 1024
#define H_ 16
#define CHUNK 16
#define NCHUNK 256
#define SUPW 16
#define NSUP 16
#define ETA 0.025f

__device__ __forceinline__ u16 f2bf(float f) {
  unsigned u = __builtin_bit_cast(unsigned, f);
  u += 0x7fffu + ((u >> 16) & 1u);
  return (u16)(u >> 16);
}
__device__ __forceinline__ float bf2f(u16 s) {
  unsigned u = ((unsigned)s) << 16;
  return __builtin_bit_cast(float, u);
}
__device__ __forceinline__ float ldv(float v) { return v; }
__device__ __forceinline__ float ldv(u16 v) { return bf2f(v); }
__device__ __forceinline__ void stv(float* p, float v) { *p = v; }
__device__ __forceinline__ void stv(u16* p, float v) { *p = f2bf(v); }

#define MFMA __builtin_amdgcn_mfma_f32_16x16x32_bf16

// ---------------- fp32 -> (hi, lo) bf16 split, float4-vectorized ----------------
__global__ void split4_kernel(const float* __restrict__ x, u16* __restrict__ hi,
                              u16* __restrict__ lo, int n4) {
  int i = blockIdx.x * blockDim.x + threadIdx.x;
  int stride = gridDim.x * blockDim.x;
  for (; i < n4; i += stride) {
    float4 v = ((const float4*)x)[i];
    ushort4 h, l;
    h.x = f2bf(v.x); l.x = f2bf(v.x - bf2f(h.x));
    h.y = f2bf(v.y); l.y = f2bf(v.y - bf2f(h.y));
    h.z = f2bf(v.z); l.z = f2bf(v.z - bf2f(h.z));
    h.w = f2bf(v.w); l.w = f2bf(v.w - bf2f(h.w));
    ((ushort4*)hi)[i] = h;
    ((ushort4*)lo)[i] = l;
  }
}

// ---------------- GEMM: C[M][N] = A * B^T ----------------
// A: pre-split bf16 (Ah, +Al if AP==2). B: BPRE=1 pre-split; BPRE=0 fp32 split
// on the fly. Combos: ah*bh + ah*bl (+ al*bh if AP==2). 128x128 tile, BK=32.
template<int AP, int BPRE, typename OutT>
__global__ __launch_bounds__(256) void gemm_axw(
    const u16* __restrict__ Ahg, const u16* __restrict__ Alg,
    const void* __restrict__ Bhp, const u16* __restrict__ Blg,
    OutT* __restrict__ C, int M, int N, int K) {
  __shared__ __align__(16) u16 Ahs[128][32];
  __shared__ __align__(16) u16 Als[AP == 2 ? 128 : 1][32];
  __shared__ __align__(16) u16 Bhs[128][32];
  __shared__ __align__(16) u16 Bls[128][32];
  const int tid = threadIdx.x, w = tid >> 6, lane = tid & 63;
  const int bm = blockIdx.x * 128, bn = blockIdx.y * 128;
  const int wm = (w >> 1) * 64, wn = (w & 1) * 64;
  const int fr = lane & 15, kb = lane >> 4;

  f32x4 acc[4][4];
#pragma unroll
  for (int i = 0; i < 4; ++i)
#pragma unroll
    for (int j = 0; j < 4; ++j) acc[i][j] = (f32x4){0.f, 0.f, 0.f, 0.f};

  for (int k0 = 0; k0 < K; k0 += 32) {
    __syncthreads();  // prior frag reads complete before overwrite
#pragma unroll
    for (int i = 0; i < 2; ++i) {
      int e = tid + i * 256;             // 0..511
      int r = e >> 2, sg = (e & 3) * 8;  // 8 u16 = 16B
      *(uint4*)(&Ahs[r][sg]) = *(const uint4*)(&Ahg[(size_t)(bm + r) * K + k0 + sg]);
      if constexpr (AP == 2)
        *(uint4*)(&Als[r][sg]) = *(const uint4*)(&Alg[(size_t)(bm + r) * K + k0 + sg]);
    }
    if constexpr (BPRE) {
      const u16* Bhg = (const u16*)Bhp;
#pragma unroll
      for (int i = 0; i < 2; ++i) {
        int e = tid + i * 256;
        int r = e >> 2, sg = (e & 3) * 8;
        *(uint4*)(&Bhs[r][sg]) = *(const uint4*)(&Bhg[(size_t)(bn + r) * K + k0 + sg]);
        *(uint4*)(&Bls[r][sg]) = *(const uint4*)(&Blg[(size_t)(bn + r) * K + k0 + sg]);
      }
    } else {
      const float* Bm = (const float*)Bhp;
#pragma unroll
      for (int i = 0; i < 4; ++i) {
        int e = tid + i * 256, r = e >> 3, sg = (e & 7) * 4;
        float4 v = *(const float4*)(&Bm[(size_t)(bn + r) * K + k0 + sg]);
        ushort4 h, l;
        h.x = f2bf(v.x); l.x = f2bf(v.x - bf2f(h.x));
        h.y = f2bf(v.y); l.y = f2bf(v.y - bf2f(h.y));
        h.z = f2bf(v.z); l.z = f2bf(v.z - bf2f(h.z));
        h.w = f2bf(v.w); l.w = f2bf(v.w - bf2f(h.w));
        *(ushort4*)(&Bhs[r][sg]) = h;
        *(ushort4*)(&Bls[r][sg]) = l;
      }
    }
    __syncthreads();  // tiles ready
    short8 ah[4], al[4], bh[4], bl[4];
#pragma unroll
    for (int mi = 0; mi < 4; ++mi) {
      ah[mi] = *(const short8*)(&Ahs[wm + mi * 16 + fr][kb * 8]);
      if constexpr (AP == 2) al[mi] = *(const short8*)(&Als[wm + mi * 16 + fr][kb * 8]);
    }
#pragma unroll
    for (int ni = 0; ni < 4; ++ni) {
      bh[ni] = *(const short8*)(&Bhs[wn + ni * 16 + fr][kb * 8]);
      bl[ni] = *(const short8*)(&Bls[wn + ni * 16 + fr][kb * 8]);
    }
#pragma unroll
    for (int mi = 0; mi < 4; ++mi)
#pragma unroll
      for (int ni = 0; ni < 4; ++ni) {
        acc[mi][ni] = MFMA(ah[mi], bh[ni], acc[mi][ni], 0, 0, 0);
        acc[mi][ni] = MFMA(ah[mi], bl[ni], acc[mi][ni], 0, 0, 0);
        if constexpr (AP == 2)
          acc[mi][ni] = MFMA(al[mi], bh[ni], acc[mi][ni], 0, 0, 0);
      }
  }
  const int fc = lane & 15, fr4 = (lane >> 4) * 4;
#pragma unroll
  for (int mi = 0; mi < 4; ++mi)
#pragma unroll
    for (int ni = 0; ni < 4; ++ni) {
      int gm = bm + wm + mi * 16 + fr4;
      int gn = bn + wn + ni * 16 + fc;
#pragma unroll
      for (int rg = 0; rg < 4; ++rg)
        stv(&C[(size_t)(gm + rg) * N + gn], acc[mi][ni][rg]);
    }
}

// ---------------- phase 1 (MFMA, no strided LDS reads) ----------------
// Buffers (all reads ds_read_b128):
//   Ks : raw K -> N^2 -> N^4T -> Sm_hi
//   KsT: K^T (alive until P/R)
//   Gh : G_hi -> N^2T -> N^8
//   Gl : G_lo -> N^4  -> Sm_lo
//   Ut/Wt: fp32 states (eta V^T, eta K^T; updated in place per-wave-row-range)
// S = Q K^T computed EARLY from global-Q fragments into registers.
template<typename PT>
__global__ __launch_bounds__(256) void phase1_kernel(
    float* __restrict__ Qg, const u16* __restrict__ Kg, u16* __restrict__ Vg,
    PT* __restrict__ Pg, PT* __restrict__ Rg) {
  __shared__ __align__(16) u16 Ks[64][72];
  __shared__ __align__(16) u16 KsT[64][72];
  __shared__ __align__(16) u16 Gh[64][72];
  __shared__ __align__(16) u16 Gl[64][72];
  __shared__ __align__(16) float Ut[64][68];
  __shared__ __align__(16) float Wt[64][68];

  const int c = blockIdx.x, h = blockIdx.y, tid = threadIdx.x;
  const int w = tid >> 6, lane = tid & 63;
  const int fr = lane & 15, kq = lane >> 4, orow = kq * 4;
  const int xr = 16 * w + fr;

  auto gidx = [&](int r, int d) -> size_t {
    return ((size_t)(r & 3) * S_ + (size_t)c * CHUNK + (r >> 2)) * D_ + h * 64 + d;
  };
  auto ldb = [&](const u16 (*M)[72], int row, int s) -> short8 {
    return *(const short8*)(&M[row][32 * s + 8 * kq]);
  };
  // masked read of N = strict block-triangular part: up=false -> lower
  auto ldm = [&](const u16 (*M)[72], int row, int s, bool up) -> short8 {
    short8 r = *(const short8*)(&M[row][32 * s + 8 * kq]);
    int rb = row >> 2, k0 = 32 * s + 8 * kq;
#pragma unroll
    for (int j = 0; j < 8; ++j) {
      int kb2 = (k0 + j) >> 2;
      bool keep = up ? (kb2 > rb) : (rb > kb2);
      if (!keep) r[j] = 0;
    }
    return r;
  };
  auto ldf = [&](const float (*M)[68], int row, int s, short8& hh, short8& ll) {
    const float* p = &M[row][32 * s + 8 * kq];
#pragma unroll
    for (int j = 0; j < 8; ++j) {
      float v = p[j];
      u16 hb = f2bf(v);
      hh[j] = (short)hb;
      ll[j] = (short)f2bf(v - bf2f(hb));
    }
  };
  auto ldfh = [&](const float (*M)[68], int row, int s) -> short8 {
    const float* p = &M[row][32 * s + 8 * kq];
    short8 hh;
#pragma unroll
    for (int j = 0; j < 8; ++j) hh[j] = (short)f2bf(p[j]);
    return hh;
  };

  // ---- ph0: load K (+K^T), V; states ----
  for (int i = tid; i < 4096; i += 256) {
    int r = i >> 6, d = i & 63;
    size_t g = gidx(r, d);
    u16 kraw = Kg[g];
    Ks[r][d] = kraw;
    KsT[d][r] = kraw;
    Wt[d][r] = ETA * bf2f(kraw);
    Ut[d][r] = ETA * bf2f(Vg[g]);
  }
  __syncthreads();  // (1)

  // ---- G = -eta * K K^T -> Gh/Gl ----
  {
    f32x4 acc[4];
#pragma unroll
    for (int ni = 0; ni < 4; ++ni) acc[ni] = (f32x4){0.f, 0.f, 0.f, 0.f};
    short8 xf[2];
#pragma unroll
    for (int s = 0; s < 2; ++s) xf[s] = ldb(Ks, xr, s);
#pragma unroll
    for (int ni = 0; ni < 4; ++ni)
#pragma unroll
      for (int s = 0; s < 2; ++s)
        acc[ni] = MFMA(xf[s], ldb(Ks, 16 * ni + fr, s), acc[ni], 0, 0, 0);
#pragma unroll
    for (int ni = 0; ni < 4; ++ni)
#pragma unroll
      for (int rg = 0; rg < 4; ++rg) {
        float v = -ETA * acc[ni][rg];
        u16 hb = f2bf(v);
        int rr = 16 * w + orow + rg, cc = 16 * ni + fr;
        Gh[rr][cc] = hb;
        Gl[rr][cc] = f2bf(v - bf2f(hb));
      }
  }

  // ---- S = Q K^T -> sreg (early; Q fragments straight from global) ----
  float sreg[4][4];
  {
    short8 xh[2], xl[2];
#pragma unroll
    for (int s = 0; s < 2; ++s) {
      const float* qp = &Qg[gidx(xr, 32 * s + 8 * kq)];
#pragma unroll
      for (int j = 0; j < 8; ++j) {
        float v = qp[j];
        u16 hb = f2bf(v);
        xh[s][j] = (short)hb;
        xl[s][j] = (short)f2bf(v - bf2f(hb));
      }
    }
    f32x4 acc[4];
#pragma unroll
    for (int ni = 0; ni < 4; ++ni) acc[ni] = (f32x4){0.f, 0.f, 0.f, 0.f};
#pragma unroll
    for (int ni = 0; ni < 4; ++ni)
#pragma unroll
      for (int s = 0; s < 2; ++s) {
        short8 yf = ldb(Ks, 16 * ni + fr, s);
        acc[ni] = MFMA(xh[s], yf, acc[ni], 0, 0, 0);
        acc[ni] = MFMA(xl[s], yf, acc[ni], 0, 0, 0);
      }
#pragma unroll
    for (int ni = 0; ni < 4; ++ni)
#pragma unroll
      for (int rg = 0; rg < 4; ++rg) {
        int r = 16 * w + orow + rg, cc = 16 * ni + fr;
        sreg[ni][rg] = ((r >> 2) >= (cc >> 2)) ? acc[ni][rg] : 0.f;
      }
  }
  __syncthreads();  // (2) G ready

  // in-place state update: St += St * Y^T
  auto app1 = [&](float (*St)[68]) {  // Y = N from masked Gh/Gl (3-pass)
    short8 xh[2], xl[2];
#pragma unroll
    for (int s = 0; s < 2; ++s) ldf(St, xr, s, xh[s], xl[s]);
    f32x4 acc[4];
#pragma unroll
    for (int ni = 0; ni < 4; ++ni) acc[ni] = (f32x4){0.f, 0.f, 0.f, 0.f};
#pragma unroll
    for (int ni = 0; ni < 4; ++ni)
#pragma unroll
      for (int s = 0; s < 2; ++s) {
        short8 yh = ldm(Gh, 16 * ni + fr, s, false);
        short8 yl = ldm(Gl, 16 * ni + fr, s, false);
        acc[ni] = MFMA(xh[s], yh, acc[ni], 0, 0, 0);
        acc[ni] = MFMA(xh[s], yl, acc[ni], 0, 0, 0);
        acc[ni] = MFMA(xl[s], yh, acc[ni], 0, 0, 0);
      }
#pragma unroll
    for (int ni = 0; ni < 4; ++ni)
#pragma unroll
      for (int rg = 0; rg < 4; ++rg)
        St[16 * w + orow + rg][16 * ni + fr] += acc[ni][rg];
  };
  auto appS = [&](float (*St)[68], const u16 (*Np)[72]) {  // single-bf16 power
    short8 xh[2];
#pragma unroll
    for (int s = 0; s < 2; ++s) xh[s] = ldfh(St, xr, s);
    f32x4 acc[4];
#pragma unroll
    for (int ni = 0; ni < 4; ++ni) acc[ni] = (f32x4){0.f, 0.f, 0.f, 0.f};
#pragma unroll
    for (int ni = 0; ni < 4; ++ni)
#pragma unroll
      for (int s = 0; s < 2; ++s)
        acc[ni] = MFMA(xh[s], ldb(Np, 16 * ni + fr, s), acc[ni], 0, 0, 0);
#pragma unroll
    for (int ni = 0; ni < 4; ++ni)
#pragma unroll
      for (int rg = 0; rg < 4; ++rg)
        St[16 * w + orow + rg][16 * ni + fr] += acc[ni][rg];
  };

  // ---- ph2: app1(U,W); sq1: N^2 (3-pass masked) -> Ks, N^2T -> Gh ----
  app1(Ut);
  app1(Wt);
  {
    f32x4 sq[4];
#pragma unroll
    for (int ni = 0; ni < 4; ++ni) sq[ni] = (f32x4){0.f, 0.f, 0.f, 0.f};
    short8 xh[2], xl[2];
#pragma unroll
    for (int s = 0; s < 2; ++s) {
      xh[s] = ldm(Gh, xr, s, false);
      xl[s] = ldm(Gl, xr, s, false);
    }
#pragma unroll
    for (int ni = 0; ni < 4; ++ni)
#pragma unroll
      for (int s = 0; s < 2; ++s) {
        short8 yh = ldm(Gh, 16 * ni + fr, s, true);  // N^T via symmetry of G
        short8 yl = ldm(Gl, 16 * ni + fr, s, true);
        sq[ni] = MFMA(xh[s], yh, sq[ni], 0, 0, 0);
        sq[ni] = MFMA(xh[s], yl, sq[ni], 0, 0, 0);
        sq[ni] = MFMA(xl[s], yh, sq[ni], 0, 0, 0);
      }
    __syncthreads();  // (3) Gh/Gl & Ks reads done
#pragma unroll
    for (int ni = 0; ni < 4; ++ni)
#pragma unroll
      for (int rg = 0; rg < 4; ++rg) {
        u16 b = f2bf(sq[ni][rg]);
        int rr = 16 * w + orow + rg, cc = 16 * ni + fr;
        Ks[rr][cc] = b;   // N^2
        Gh[cc][rr] = b;   // N^2T
      }
  }
  __syncthreads();  // (4)

  // ---- ph3: app2 (Y=N^2=Ks); sq2: N^4 = N^2 * (N^2T)^T -> Gl, N^4T -> Ks ----
  appS(Ut, Ks);
  appS(Wt, Ks);
  {
    f32x4 sq[4];
#pragma unroll
    for (int ni = 0; ni < 4; ++ni) sq[ni] = (f32x4){0.f, 0.f, 0.f, 0.f};
    short8 xf[2];
#pragma unroll
    for (int s = 0; s < 2; ++s) xf[s] = ldb(Ks, xr, s);
#pragma unroll
    for (int ni = 0; ni < 4; ++ni)
#pragma unroll
      for (int s = 0; s < 2; ++s)
        sq[ni] = MFMA(xf[s], ldb(Gh, 16 * ni + fr, s), sq[ni], 0, 0, 0);
    __syncthreads();  // (5) Ks/Gh reads done
#pragma unroll
    for (int ni = 0; ni < 4; ++ni)
#pragma unroll
      for (int rg = 0; rg < 4; ++rg) {
        u16 b = f2bf(sq[ni][rg]);
        int rr = 16 * w + orow + rg, cc = 16 * ni + fr;
        Gl[rr][cc] = b;   // N^4
        Ks[cc][rr] = b;   // N^4T
      }
  }
  __syncthreads();  // (6)

  // ---- ph4: app3 (Y=N^4=Gl); sq3: N^8 = N^4 * (N^4T)^T -> Gh ----
  appS(Ut, Gl);
  appS(Wt, Gl);
  {
    f32x4 sq[4];
#pragma unroll
    for (int ni = 0; ni < 4; ++ni) sq[ni] = (f32x4){0.f, 0.f, 0.f, 0.f};
    short8 xf[2];
#pragma unroll
    for (int s = 0; s < 2; ++s) xf[s] = ldb(Gl, xr, s);
#pragma unroll
    for (int ni = 0; ni < 4; ++ni)
#pragma unroll
      for (int s = 0; s < 2; ++s)
        sq[ni] = MFMA(xf[s], ldb(Ks, 16 * ni + fr, s), sq[ni], 0, 0, 0);
    // Gh (N^2T) dead since ph3 -> direct write, no pre-sync needed
#pragma unroll
    for (int ni = 0; ni < 4; ++ni)
#pragma unroll
      for (int rg = 0; rg < 4; ++rg)
        Gh[16 * w + orow + rg][16 * ni + fr] = f2bf(sq[ni][rg]);
  }
  __syncthreads();  // (7)

  // ---- ph5: app4 (Y=N^8=Gh) ----
  appS(Ut, Gh);
  appS(Wt, Gh);

  // ---- ph6: P = W^T K, R = Ubar^T K (Y = ldb(KsT)); stash Sm h/l ----
  const size_t base = ((size_t)c * H_ + h) * 4096;
  {
    short8 xh[2], xl[2];
#pragma unroll
    for (int s = 0; s < 2; ++s) ldf(Wt, xr, s, xh[s], xl[s]);
    f32x4 acc[4];
#pragma unroll
    for (int ni = 0; ni < 4; ++ni) acc[ni] = (f32x4){0.f, 0.f, 0.f, 0.f};
#pragma unroll
    for (int ni = 0; ni < 4; ++ni)
#pragma unroll
      for (int s = 0; s < 2; ++s) {
        short8 yf = ldb(KsT, 16 * ni + fr, s);
        acc[ni] = MFMA(xh[s], yf, acc[ni], 0, 0, 0);
        acc[ni] = MFMA(xl[s], yf, acc[ni], 0, 0, 0);
      }
#pragma unroll
    for (int ni = 0; ni < 4; ++ni)
#pragma unroll
      for (int rg = 0; rg < 4; ++rg)
        stv(&Pg[base + (16 * w + orow + rg) * 64 + 16 * ni + fr], acc[ni][rg]);
  }
  {
    short8 xh[2], xl[2];
#pragma unroll
    for (int s = 0; s < 2; ++s) ldf(Ut, xr, s, xh[s], xl[s]);
    f32x4 acc[4];
#pragma unroll
    for (int ni = 0; ni < 4; ++ni) acc[ni] = (f32x4){0.f, 0.f, 0.f, 0.f};
#pragma unroll
    for (int ni = 0; ni < 4; ++ni)
#pragma unroll
      for (int s = 0; s < 2; ++s) {
        short8 yf = ldb(KsT, 16 * ni + fr, s);
        acc[ni] = MFMA(xh[s], yf, acc[ni], 0, 0, 0);
        acc[ni] = MFMA(xl[s], yf, acc[ni], 0, 0, 0);
      }
#pragma unroll
    for (int ni = 0; ni < 4; ++ni)
#pragma unroll
      for (int rg = 0; rg < 4; ++rg)
        stv(&Rg[base + (16 * w + orow + rg) * 64 + 16 * ni + fr], acc[ni][rg]);
  }
  // Sm h -> Ks (N^4T dead), l -> Gl (N^4 dead); own-wave row range
#pragma unroll
  for (int ni = 0; ni < 4; ++ni)
#pragma unroll
    for (int rg = 0; rg < 4; ++rg) {
      int r = 16 * w + orow + rg, cc = 16 * ni + fr;
      u16 hb = f2bf(sreg[ni][rg]);
      Ks[r][cc] = hb;
      Gl[r][cc] = f2bf(sreg[ni][rg] - bf2f(hb));
    }
  __syncthreads();  // (8) states + Sm ready for all-row reads

  // ---- ph7: E = Q - Sm*W -> Qg ; F = Sm*Ubar -> Vg ----
  {
    short8 xh[2], xl[2];
#pragma unroll
    for (int s = 0; s < 2; ++s) {
      xh[s] = ldb(Ks, xr, s);
      xl[s] = ldb(Gl, xr, s);
    }
    f32x4 accE[4], accF[4];
#pragma unroll
    for (int ni = 0; ni < 4; ++ni) {
      accE[ni] = (f32x4){0.f, 0.f, 0.f, 0.f};
      accF[ni] = (f32x4){0.f, 0.f, 0.f, 0.f};
    }
#pragma unroll
    for (int ni = 0; ni < 4; ++ni)
#pragma unroll
      for (int s = 0; s < 2; ++s) {
        short8 yh, yl;
        ldf(Wt, 16 * ni + fr, s, yh, yl);
        accE[ni] = MFMA(xh[s], yh, accE[ni], 0, 0, 0);
        accE[ni] = MFMA(xh[s], yl, accE[ni], 0, 0, 0);
        accE[ni] = MFMA(xl[s], yh, accE[ni], 0, 0, 0);
        ldf(Ut, 16 * ni + fr, s, yh, yl);
        accF[ni] = MFMA(xh[s], yh, accF[ni], 0, 0, 0);
        accF[ni] = MFMA(xh[s], yl, accF[ni], 0, 0, 0);
        accF[ni] = MFMA(xl[s], yh, accF[ni], 0, 0, 0);
      }
#pragma unroll
    for (int ni = 0; ni < 4; ++ni)
#pragma unroll
      for (int rg = 0; rg < 4; ++rg) {
        int r = 16 * w + orow + rg, d = 16 * ni + fr;
        size_t g = gidx(r, d);
        float qv = Qg[g];  // exact fp32 Q (read-then-overwrite, same thread)
        Qg[g] = qv - accE[ni][rg];
        Vg[g] = f2bf(accF[ni][rg]);
      }
  }
}

// ---------------- 64x64 fp32 helpers (levels) ----------------
__device__ __forceinline__ void load64(float (*dst)[65], const float* src, int tid) {
  for (int i = tid; i < 4096; i += 256) dst[i >> 6][i & 63] = src[i];
}
__device__ __forceinline__ void store64(float* dst, const float (*src)[65], int tid) {
  for (int i = tid; i < 4096; i += 256) dst[i] = src[i >> 6][i & 63];
}
template<typename PT>
__device__ __forceinline__ void loadPfull(float (*dst)[65], const PT* src, int tid) {
  for (int i = tid; i < 4096; i += 256) {
    int r = i >> 6, cc = i & 63;
    dst[r][cc] = ((r == cc) ? 1.f : 0.f) - ldv(src[i]);
  }
}
template<typename PT>
__device__ __forceinline__ void loadR(float (*dst)[65], const PT* src, int tid) {
  for (int i = tid; i < 4096; i += 256) dst[i >> 6][i & 63] = ldv(src[i]);
}
__device__ __forceinline__ void mm64(const float (*X)[65], const float (*Y)[65],
                                     float (*Dst)[65], const float (*Add)[65], int tid) {
  const int r0 = (tid >> 4) * 4, c0 = (tid & 15) * 4;
  float a[4][4] = {};
  for (int d = 0; d < 64; ++d) {
    float xv[4], yv[4];
#pragma unroll
    for (int i = 0; i < 4; ++i) xv[i] = X[r0 + i][d];
#pragma unroll
    for (int j = 0; j < 4; ++j) yv[j] = Y[d][c0 + j];
#pragma unroll
    for (int i = 0; i < 4; ++i)
#pragma unroll
      for (int j = 0; j < 4; ++j) a[i][j] += xv[i] * yv[j];
  }
  __syncthreads();
#pragma unroll
  for (int i = 0; i < 4; ++i)
#pragma unroll
    for (int j = 0; j < 4; ++j) {
      float v = a[i][j];
      if (Add) v += Add[r0 + i][c0 + j];
      Dst[r0 + i][c0 + j] = v;
    }
  __syncthreads();
}

template<typename PT>
__global__ __launch_bounds__(256) void seq_levelA(const PT* __restrict__ Pg,
    const PT* __restrict__ Rg, float* __restrict__ Psup, float* __restrict__ Rsup) {
  __shared__ float Pa[64][65], Ra[64][65], Pi[64][65], Ri[64][65];
  const int sup = blockIdx.x, h = blockIdx.y, tid = threadIdx.x;
  const int cbase = sup * SUPW;
  loadPfull(Pa, Pg + ((size_t)cbase * H_ + h) * 4096, tid);
  loadR(Ra, Rg + ((size_t)cbase * H_ + h) * 4096, tid);
  __syncthreads();
  for (int s = 1; s < SUPW; ++s) {
    loadPfull(Pi, Pg + ((size_t)(cbase + s) * H_ + h) * 4096, tid);
    loadR(Ri, Rg + ((size_t)(cbase + s) * H_ + h) * 4096, tid);
    __syncthreads();
    mm64(Pa, Pi, Pa, nullptr, tid);
    mm64(Ra, Pi, Ra, Ri, tid);
  }
  store64(Psup + ((size_t)sup * H_ + h) * 4096, Pa, tid);
  store64(Rsup + ((size_t)sup * H_ + h) * 4096, Ra, tid);
}

__global__ __launch_bounds__(256) void seq_levelB(const float* __restrict__ Psup,
    const float* __restrict__ Rsup, float* __restrict__ Msup) {
  __shared__ float Ms[64][65], Pi[64][65], Ri[64][65];
  const int h = blockIdx.x, tid = threadIdx.x;
  for (int i = tid; i < 4096; i += 256) Ms[i >> 6][i & 63] = 0.f;
  __syncthreads();
  for (int s = 0; s < NSUP; ++s) {
    store64(Msup + ((size_t)s * H_ + h) * 4096, Ms, tid);
    load64(Pi, Psup + ((size_t)s * H_ + h) * 4096, tid);
    load64(Ri, Rsup + ((size_t)s * H_ + h) * 4096, tid);
    __syncthreads();
    mm64(Ms, Pi, Ms, Ri, tid);
  }
}

template<typename PT>
__global__ __launch_bounds__(256) void seq_levelC(const PT* __restrict__ Pg,
    PT* __restrict__ Rg, const float* __restrict__ Msup) {
  __shared__ float Ms[64][65], Pi[64][65], Ri[64][65];
  const int sup = blockIdx.x, h = blockIdx.y, tid = threadIdx.x;
  load64(Ms, Msup + ((size_t)sup * H_ + h) * 4096, tid);
  __syncthreads();
  for (int s = 0; s < SUPW; ++s) {
    const size_t slice = ((size_t)(sup * SUPW + s) * H_ + h) * 4096;
    loadPfull(Pi, Pg + slice, tid);
    loadR(Ri, Rg + slice, tid);
    __syncthreads();
    for (int i = tid; i < 4096; i += 256) stv(&Rg[slice + i], Ms[i >> 6][i & 63]);
    mm64(Ms, Pi, Ms, Ri, tid);
  }
}

// ---------------- phase 3: attn = E*M0^T + F (bf16 out) ----------------
template<typename PT>
__global__ __launch_bounds__(256) void phase3_kernel(
    const float* __restrict__ Eg, const u16* __restrict__ Fg,
    const PT* __restrict__ Mcg, u16* __restrict__ attn) {
  __shared__ float Es[64][65], Ms[64][65];
  const int c = blockIdx.x, h = blockIdx.y, tid = threadIdx.x;
  for (int i = tid; i < 4096; i += 256) {
    int r = i >> 6, d = i & 63, t = r >> 2, b = r & 3;
    size_t g = ((size_t)b * S_ + (size_t)c * CHUNK + t) * D_ + h * 64 + d;
    Es[r][d] = Eg[g];
    Ms[i >> 6][i & 63] = ldv(Mcg[((size_t)c * H_ + h) * 4096 + i]);
  }
  __syncthreads();
  const int r0 = (tid >> 4) * 4, d0 = (tid & 15) * 4;
  float a[4][4] = {};
  for (int k = 0; k < 64; ++k) {
    float ev[4], mv[4];
#pragma unroll
    for (int i = 0; i < 4; ++i) ev[i] = Es[r0 + i][k];
#pragma unroll
    for (int j = 0; j < 4; ++j) mv[j] = Ms[d0 + j][k];
#pragma unroll
    for (int i = 0; i < 4; ++i)
#pragma unroll
      for (int j = 0; j < 4; ++j) a[i][j] += ev[i] * mv[j];
  }
#pragma unroll
  for (int i = 0; i < 4; ++i)
#pragma unroll
    for (int j = 0; j < 4; ++j) {
      int r = r0 + i, d = d0 + j, t = r >> 2, b = r & 3;
      size_t g = ((size_t)b * S_ + (size_t)c * CHUNK + t) * D_ + h * 64 + d;
      attn[g] = f2bf(a[i][j] + bf2f(Fg[g]));
    }
}

// ---------------- launch ----------------
extern "C" void kernel_launch(void* const* d_in, const int* in_sizes, int n_in,
                              void* d_out, int out_size, void* d_ws, size_t ws_size,
                              hipStream_t stream) {
  (void)in_sizes; (void)n_in; (void)out_size;
  const float* x  = (const float*)d_in[0];
  const float* Wq = (const float*)d_in[1];
  const float* Wk = (const float*)d_in[2];
  const float* Wv = (const float*)d_in[3];
  const float* Wo = (const float*)d_in[4];
  float* out = (float*)d_out;

  char* w = (char*)d_ws;
  const size_t MB = 1024 * 1024;
  // big (>=192MB): [0,32) Kbf->smalls ; [32,64) Vbf->F ; [64,96) xh ; [96,128) xl ;
  //   P fp32 [64,128) over xh/xl ; R fp32 [128,192) ; Wsp [128,144) time-muxed
  //   (Wq/k/v splits live pre-phase1; Wo re-split there post-phase3) ; attn over P.
  // small: bf16 P [64,96), R [96,128), B split on the fly.
  u16* Kbf = (u16*)w;
  u16* Vbf = (u16*)(w + 32 * MB);
  u16* xh  = (u16*)(w + 64 * MB);
  u16* xl  = (u16*)(w + 96 * MB);
  const bool big = ws_size >= 192 * MB;
  void* Preg = (void*)(w + 64 * MB);
  void* Rreg = big ? (void*)(w + 128 * MB) : (void*)(w + 96 * MB);
  float* Psup = (float*)w;
  float* Rsup = (float*)(w + 4 * MB);
  float* Msup = (float*)(w + 8 * MB);
  u16* attn = (u16*)Preg;
  u16* Wsp = (u16*)(w + 128 * MB);  // hi/lo u16 pairs at +0/+1M, +2/+3M, +4/+5M

  const size_t DSZ = (size_t)B_ * S_ * D_;  // 16777216
  split4_kernel<<<2048, 256, 0, stream>>>(x, xh, xl, (int)(DSZ / 4));

  dim3 gg(128, 8);
  if (big) {
    split4_kernel<<<512, 256, 0, stream>>>(Wq, Wsp + 0 * 1048576u, Wsp + 1 * 1048576u, 262144);
    split4_kernel<<<512, 256, 0, stream>>>(Wk, Wsp + 2 * 1048576u, Wsp + 3 * 1048576u, 262144);
    split4_kernel<<<512, 256, 0, stream>>>(Wv, Wsp + 4 * 1048576u, Wsp + 5 * 1048576u, 262144);
    gemm_axw<2, 1, float><<<gg, 256, 0, stream>>>(xh, xl, Wsp + 0 * 1048576u, Wsp + 1 * 1048576u, out, 16384, 1024, 1024);
    gemm_axw<2, 1, u16><<<gg, 256, 0, stream>>>(xh, xl, Wsp + 2 * 1048576u, Wsp + 3 * 1048576u, Kbf, 16384, 1024, 1024);
    gemm_axw<2, 1, u16><<<gg, 256, 0, stream>>>(xh, xl, Wsp + 4 * 1048576u, Wsp + 5 * 1048576u, Vbf, 16384, 1024, 1024);
    float* P = (float*)Preg; float* R = (float*)Rreg;
    phase1_kernel<float><<<dim3(NCHUNK, H_), 256, 0, stream>>>(out, Kbf, Vbf, P, R);
    seq_levelA<float><<<dim3(NSUP, H_), 256, 0, stream>>>(P, R, Psup, Rsup);
    seq_levelB<<<dim3(H_), 256, 0, stream>>>(Psup, Rsup, Msup);
    seq_levelC<float><<<dim3(NSUP, H_), 256, 0, stream>>>(P, R, Msup);
    phase3_kernel<float><<<dim3(NCHUNK, H_), 256, 0, stream>>>(out, Vbf, R, attn);
    split4_kernel<<<512, 256, 0, stream>>>(Wo, Wsp + 0 * 1048576u, Wsp + 1 * 1048576u, 262144);
    gemm_axw<1, 1, float><<<gg, 256, 0, stream>>>(attn, nullptr, Wsp + 0 * 1048576u, Wsp + 1 * 1048576u, out, 16384, 1024, 1024);
  } else {
    gemm_axw<2, 0, float><<<gg, 256, 0, stream>>>(xh, xl, Wq, nullptr, out, 16384, 1024, 1024);
    gemm_axw<2, 0, u16><<<gg, 256, 0, stream>>>(xh, xl, Wk, nullptr, Kbf, 16384, 1024, 1024);
    gemm_axw<2, 0, u16><<<gg, 256, 0, stream>>>(xh, xl, Wv, nullptr, Vbf, 16384, 1024, 1024);
    u16* P = (u16*)Preg; u16* R = (u16*)Rreg;
    phase1_kernel<u16><<<dim3(NCHUNK, H_), 256, 0, stream>>>(out, Kbf, Vbf, P, R);
    seq_levelA<u16><<<dim3(NSUP, H_), 256, 0, stream>>>(P, R, Psup, Rsup);
    seq_levelB<<<dim3(H_), 256, 0, stream>>>(Psup, Rsup, Msup);
    seq_levelC<u16><<<dim3(NSUP, H_), 256, 0, stream>>>(P, R, Msup);
    phase3_kernel<u16><<<dim3(NCHUNK, H_), 256, 0, stream>>>(out, Vbf, R, attn);
    gemm_axw<1, 0, float><<<gg, 256, 0, stream>>>(attn, nullptr, Wo, nullptr, out, 16384, 1024, 1024);
  }
}

// Round 7
// 873.070 us; speedup vs baseline: 1.5861x; 1.0994x over previous
//
#include <hip/hip_runtime.h>

// L2RegressionAttention — chunked WY-transform.
// r7: precision-budgeted MFMA passes. Projection GEMMs 2-pass (ah*bh + al*bh,
// no B_lo anywhere: K/V are bf16-stored so pass 3 was below storage rounding).
// phase1 E/F single-pass via one-time bf16 conversion of W/U/Sm into dead LDS
// buffers. Levels/phase3 unchanged (passing since r2).
// B=4, S=4096, D=1024, H=16, hd=64, eta = 0.1/4 = 0.025.

typedef unsigned short u16;
typedef __attribute__((ext_vector_type(8))) short short8;
typedef __attribute__((ext_vector_type(4))) float f32x4;

#define B_ 4
#define S_ 4096
#define D_ 1024
#define H_ 16
#define CHUNK 16
#define NCHUNK 256
#define SUPW 16
#define NSUP 16
#define ETA 0.025f

__device__ __forceinline__ u16 f2bf(float f) {
  unsigned u = __builtin_bit_cast(unsigned, f);
  u += 0x7fffu + ((u >> 16) & 1u);
  return (u16)(u >> 16);
}
__device__ __forceinline__ float bf2f(u16 s) {
  unsigned u = ((unsigned)s) << 16;
  return __builtin_bit_cast(float, u);
}
__device__ __forceinline__ float ldv(float v) { return v; }
__device__ __forceinline__ float ldv(u16 v) { return bf2f(v); }
__device__ __forceinline__ void stv(float* p, float v) { *p = v; }
__device__ __forceinline__ void stv(u16* p, float v) { *p = f2bf(v); }

#define MFMA __builtin_amdgcn_mfma_f32_16x16x32_bf16

// ---------------- fp32 -> (hi, lo) bf16 split, float4-vectorized ----------------
__global__ void split4_kernel(const float* __restrict__ x, u16* __restrict__ hi,
                              u16* __restrict__ lo, int n4) {
  int i = blockIdx.x * blockDim.x + threadIdx.x;
  int stride = gridDim.x * blockDim.x;
  for (; i < n4; i += stride) {
    float4 v = ((const float4*)x)[i];
    ushort4 h, l;
    h.x = f2bf(v.x); l.x = f2bf(v.x - bf2f(h.x));
    h.y = f2bf(v.y); l.y = f2bf(v.y - bf2f(h.y));
    h.z = f2bf(v.z); l.z = f2bf(v.z - bf2f(h.z));
    h.w = f2bf(v.w); l.w = f2bf(v.w - bf2f(h.w));
    ((ushort4*)hi)[i] = h;
    ((ushort4*)lo)[i] = l;
  }
}

// ---------------- GEMM: C[M][N] = A * B^T ----------------
// A: pre-split bf16 (Ah, +Al if AP==2). B: BPRE=1 pre-split bf16; BPRE=0 fp32
// split on the fly. Combos: ah*bh (+ ah*bl if BP==2) (+ al*bh if AP==2).
// 128x128 tile, BK=32, 4 waves each 64x64.
template<int AP, int BP, int BPRE, typename OutT>
__global__ __launch_bounds__(256) void gemm_axw(
    const u16* __restrict__ Ahg, const u16* __restrict__ Alg,
    const void* __restrict__ Bhp, const u16* __restrict__ Blg,
    OutT* __restrict__ C, int M, int N, int K) {
  __shared__ __align__(16) u16 Ahs[128][32];
  __shared__ __align__(16) u16 Als[AP == 2 ? 128 : 1][32];
  __shared__ __align__(16) u16 Bhs[128][32];
  __shared__ __align__(16) u16 Bls[BP == 2 ? 128 : 1][32];
  const int tid = threadIdx.x, w = tid >> 6, lane = tid & 63;
  const int bm = blockIdx.x * 128, bn = blockIdx.y * 128;
  const int wm = (w >> 1) * 64, wn = (w & 1) * 64;
  const int fr = lane & 15, kb = lane >> 4;

  f32x4 acc[4][4];
#pragma unroll
  for (int i = 0; i < 4; ++i)
#pragma unroll
    for (int j = 0; j < 4; ++j) acc[i][j] = (f32x4){0.f, 0.f, 0.f, 0.f};

  for (int k0 = 0; k0 < K; k0 += 32) {
    __syncthreads();  // prior frag reads complete before overwrite
#pragma unroll
    for (int i = 0; i < 2; ++i) {
      int e = tid + i * 256;             // 0..511
      int r = e >> 2, sg = (e & 3) * 8;  // 8 u16 = 16B
      *(uint4*)(&Ahs[r][sg]) = *(const uint4*)(&Ahg[(size_t)(bm + r) * K + k0 + sg]);
      if constexpr (AP == 2)
        *(uint4*)(&Als[r][sg]) = *(const uint4*)(&Alg[(size_t)(bm + r) * K + k0 + sg]);
    }
    if constexpr (BPRE) {
      const u16* Bhg = (const u16*)Bhp;
#pragma unroll
      for (int i = 0; i < 2; ++i) {
        int e = tid + i * 256;
        int r = e >> 2, sg = (e & 3) * 8;
        *(uint4*)(&Bhs[r][sg]) = *(const uint4*)(&Bhg[(size_t)(bn + r) * K + k0 + sg]);
        if constexpr (BP == 2)
          *(uint4*)(&Bls[r][sg]) = *(const uint4*)(&Blg[(size_t)(bn + r) * K + k0 + sg]);
      }
    } else {
      const float* Bm = (const float*)Bhp;
#pragma unroll
      for (int i = 0; i < 4; ++i) {
        int e = tid + i * 256, r = e >> 3, sg = (e & 7) * 4;
        float4 v = *(const float4*)(&Bm[(size_t)(bn + r) * K + k0 + sg]);
        ushort4 h;
        h.x = f2bf(v.x); h.y = f2bf(v.y); h.z = f2bf(v.z); h.w = f2bf(v.w);
        *(ushort4*)(&Bhs[r][sg]) = h;
        if constexpr (BP == 2) {
          ushort4 l;
          l.x = f2bf(v.x - bf2f(h.x));
          l.y = f2bf(v.y - bf2f(h.y));
          l.z = f2bf(v.z - bf2f(h.z));
          l.w = f2bf(v.w - bf2f(h.w));
          *(ushort4*)(&Bls[r][sg]) = l;
        }
      }
    }
    __syncthreads();  // tiles ready
    short8 ah[4], al[4], bh[4], bl[4];
#pragma unroll
    for (int mi = 0; mi < 4; ++mi) {
      ah[mi] = *(const short8*)(&Ahs[wm + mi * 16 + fr][kb * 8]);
      if constexpr (AP == 2) al[mi] = *(const short8*)(&Als[wm + mi * 16 + fr][kb * 8]);
    }
#pragma unroll
    for (int ni = 0; ni < 4; ++ni) {
      bh[ni] = *(const short8*)(&Bhs[wn + ni * 16 + fr][kb * 8]);
      if constexpr (BP == 2) bl[ni] = *(const short8*)(&Bls[wn + ni * 16 + fr][kb * 8]);
    }
#pragma unroll
    for (int mi = 0; mi < 4; ++mi)
#pragma unroll
      for (int ni = 0; ni < 4; ++ni) {
        acc[mi][ni] = MFMA(ah[mi], bh[ni], acc[mi][ni], 0, 0, 0);
        if constexpr (BP == 2)
          acc[mi][ni] = MFMA(ah[mi], bl[ni], acc[mi][ni], 0, 0, 0);
        if constexpr (AP == 2)
          acc[mi][ni] = MFMA(al[mi], bh[ni], acc[mi][ni], 0, 0, 0);
      }
  }
  const int fc = lane & 15, fr4 = (lane >> 4) * 4;
#pragma unroll
  for (int mi = 0; mi < 4; ++mi)
#pragma unroll
    for (int ni = 0; ni < 4; ++ni) {
      int gm = bm + wm + mi * 16 + fr4;
      int gn = bn + wn + ni * 16 + fc;
#pragma unroll
      for (int rg = 0; rg < 4; ++rg)
        stv(&C[(size_t)(gm + rg) * N + gn], acc[mi][ni][rg]);
    }
}

// ---------------- phase 1 (MFMA, no strided LDS reads) ----------------
// Buffers:
//   Ks : raw K -> N^2 -> N^4T -> Sm (single bf16)
//   KsT: K^T (alive until P/R)
//   Gh : G_hi -> N^2T -> N^8 -> Wb (single bf16)
//   Gl : G_lo -> N^4  -> Ub (single bf16)
//   Ut/Wt: fp32 states. E/F are single-pass MFMA on Smb x Wb/Ub.
template<typename PT>
__global__ __launch_bounds__(256) void phase1_kernel(
    float* __restrict__ Qg, const u16* __restrict__ Kg, u16* __restrict__ Vg,
    PT* __restrict__ Pg, PT* __restrict__ Rg) {
  __shared__ __align__(16) u16 Ks[64][72];
  __shared__ __align__(16) u16 KsT[64][72];
  __shared__ __align__(16) u16 Gh[64][72];
  __shared__ __align__(16) u16 Gl[64][72];
  __shared__ __align__(16) float Ut[64][68];
  __shared__ __align__(16) float Wt[64][68];

  const int c = blockIdx.x, h = blockIdx.y, tid = threadIdx.x;
  const int w = tid >> 6, lane = tid & 63;
  const int fr = lane & 15, kq = lane >> 4, orow = kq * 4;
  const int xr = 16 * w + fr;

  auto gidx = [&](int r, int d) -> size_t {
    return ((size_t)(r & 3) * S_ + (size_t)c * CHUNK + (r >> 2)) * D_ + h * 64 + d;
  };
  auto ldb = [&](const u16 (*M)[72], int row, int s) -> short8 {
    return *(const short8*)(&M[row][32 * s + 8 * kq]);
  };
  auto ldm = [&](const u16 (*M)[72], int row, int s, bool up) -> short8 {
    short8 r = *(const short8*)(&M[row][32 * s + 8 * kq]);
    int rb = row >> 2, k0 = 32 * s + 8 * kq;
#pragma unroll
    for (int j = 0; j < 8; ++j) {
      int kb2 = (k0 + j) >> 2;
      bool keep = up ? (kb2 > rb) : (rb > kb2);
      if (!keep) r[j] = 0;
    }
    return r;
  };
  auto ldf = [&](const float (*M)[68], int row, int s, short8& hh, short8& ll) {
    const float* p = &M[row][32 * s + 8 * kq];
#pragma unroll
    for (int j = 0; j < 8; ++j) {
      float v = p[j];
      u16 hb = f2bf(v);
      hh[j] = (short)hb;
      ll[j] = (short)f2bf(v - bf2f(hb));
    }
  };
  auto ldfh = [&](const float (*M)[68], int row, int s) -> short8 {
    const float* p = &M[row][32 * s + 8 * kq];
    short8 hh;
#pragma unroll
    for (int j = 0; j < 8; ++j) hh[j] = (short)f2bf(p[j]);
    return hh;
  };

  // ---- ph0: load K (+K^T), V; states ----
  for (int i = tid; i < 4096; i += 256) {
    int r = i >> 6, d = i & 63;
    size_t g = gidx(r, d);
    u16 kraw = Kg[g];
    Ks[r][d] = kraw;
    KsT[d][r] = kraw;
    Wt[d][r] = ETA * bf2f(kraw);
    Ut[d][r] = ETA * bf2f(Vg[g]);
  }
  __syncthreads();  // (1)

  // ---- G = -eta * K K^T -> Gh/Gl ----
  {
    f32x4 acc[4];
#pragma unroll
    for (int ni = 0; ni < 4; ++ni) acc[ni] = (f32x4){0.f, 0.f, 0.f, 0.f};
    short8 xf[2];
#pragma unroll
    for (int s = 0; s < 2; ++s) xf[s] = ldb(Ks, xr, s);
#pragma unroll
    for (int ni = 0; ni < 4; ++ni)
#pragma unroll
      for (int s = 0; s < 2; ++s)
        acc[ni] = MFMA(xf[s], ldb(Ks, 16 * ni + fr, s), acc[ni], 0, 0, 0);
#pragma unroll
    for (int ni = 0; ni < 4; ++ni)
#pragma unroll
      for (int rg = 0; rg < 4; ++rg) {
        float v = -ETA * acc[ni][rg];
        u16 hb = f2bf(v);
        int rr = 16 * w + orow + rg, cc = 16 * ni + fr;
        Gh[rr][cc] = hb;
        Gl[rr][cc] = f2bf(v - bf2f(hb));
      }
  }

  // ---- S = Q K^T -> sreg (early; Q fragments straight from global) ----
  float sreg[4][4];
  {
    short8 xh[2], xl[2];
#pragma unroll
    for (int s = 0; s < 2; ++s) {
      const float* qp = &Qg[gidx(xr, 32 * s + 8 * kq)];
#pragma unroll
      for (int j = 0; j < 8; ++j) {
        float v = qp[j];
        u16 hb = f2bf(v);
        xh[s][j] = (short)hb;
        xl[s][j] = (short)f2bf(v - bf2f(hb));
      }
    }
    f32x4 acc[4];
#pragma unroll
    for (int ni = 0; ni < 4; ++ni) acc[ni] = (f32x4){0.f, 0.f, 0.f, 0.f};
#pragma unroll
    for (int ni = 0; ni < 4; ++ni)
#pragma unroll
      for (int s = 0; s < 2; ++s) {
        short8 yf = ldb(Ks, 16 * ni + fr, s);
        acc[ni] = MFMA(xh[s], yf, acc[ni], 0, 0, 0);
        acc[ni] = MFMA(xl[s], yf, acc[ni], 0, 0, 0);
      }
#pragma unroll
    for (int ni = 0; ni < 4; ++ni)
#pragma unroll
      for (int rg = 0; rg < 4; ++rg) {
        int r = 16 * w + orow + rg, cc = 16 * ni + fr;
        sreg[ni][rg] = ((r >> 2) >= (cc >> 2)) ? acc[ni][rg] : 0.f;
      }
  }
  __syncthreads();  // (2) G ready

  // in-place state update: St += St * Y^T
  auto app1 = [&](float (*St)[68]) {  // Y = N from masked Gh/Gl (3-pass)
    short8 xh[2], xl[2];
#pragma unroll
    for (int s = 0; s < 2; ++s) ldf(St, xr, s, xh[s], xl[s]);
    f32x4 acc[4];
#pragma unroll
    for (int ni = 0; ni < 4; ++ni) acc[ni] = (f32x4){0.f, 0.f, 0.f, 0.f};
#pragma unroll
    for (int ni = 0; ni < 4; ++ni)
#pragma unroll
      for (int s = 0; s < 2; ++s) {
        short8 yh = ldm(Gh, 16 * ni + fr, s, false);
        short8 yl = ldm(Gl, 16 * ni + fr, s, false);
        acc[ni] = MFMA(xh[s], yh, acc[ni], 0, 0, 0);
        acc[ni] = MFMA(xh[s], yl, acc[ni], 0, 0, 0);
        acc[ni] = MFMA(xl[s], yh, acc[ni], 0, 0, 0);
      }
#pragma unroll
    for (int ni = 0; ni < 4; ++ni)
#pragma unroll
      for (int rg = 0; rg < 4; ++rg)
        St[16 * w + orow + rg][16 * ni + fr] += acc[ni][rg];
  };
  auto appS = [&](float (*St)[68], const u16 (*Np)[72]) {  // single-bf16 power
    short8 xh[2];
#pragma unroll
    for (int s = 0; s < 2; ++s) xh[s] = ldfh(St, xr, s);
    f32x4 acc[4];
#pragma unroll
    for (int ni = 0; ni < 4; ++ni) acc[ni] = (f32x4){0.f, 0.f, 0.f, 0.f};
#pragma unroll
    for (int ni = 0; ni < 4; ++ni)
#pragma unroll
      for (int s = 0; s < 2; ++s)
        acc[ni] = MFMA(xh[s], ldb(Np, 16 * ni + fr, s), acc[ni], 0, 0, 0);
#pragma unroll
    for (int ni = 0; ni < 4; ++ni)
#pragma unroll
      for (int rg = 0; rg < 4; ++rg)
        St[16 * w + orow + rg][16 * ni + fr] += acc[ni][rg];
  };

  // ---- ph2: app1(U,W); sq1: N^2 (3-pass masked) -> Ks, N^2T -> Gh ----
  app1(Ut);
  app1(Wt);
  {
    f32x4 sq[4];
#pragma unroll
    for (int ni = 0; ni < 4; ++ni) sq[ni] = (f32x4){0.f, 0.f, 0.f, 0.f};
    short8 xh[2], xl[2];
#pragma unroll
    for (int s = 0; s < 2; ++s) {
      xh[s] = ldm(Gh, xr, s, false);
      xl[s] = ldm(Gl, xr, s, false);
    }
#pragma unroll
    for (int ni = 0; ni < 4; ++ni)
#pragma unroll
      for (int s = 0; s < 2; ++s) {
        short8 yh = ldm(Gh, 16 * ni + fr, s, true);  // N^T via symmetry of G
        short8 yl = ldm(Gl, 16 * ni + fr, s, true);
        sq[ni] = MFMA(xh[s], yh, sq[ni], 0, 0, 0);
        sq[ni] = MFMA(xh[s], yl, sq[ni], 0, 0, 0);
        sq[ni] = MFMA(xl[s], yh, sq[ni], 0, 0, 0);
      }
    __syncthreads();  // (3) Gh/Gl & Ks reads done
#pragma unroll
    for (int ni = 0; ni < 4; ++ni)
#pragma unroll
      for (int rg = 0; rg < 4; ++rg) {
        u16 b = f2bf(sq[ni][rg]);
        int rr = 16 * w + orow + rg, cc = 16 * ni + fr;
        Ks[rr][cc] = b;   // N^2
        Gh[cc][rr] = b;   // N^2T
      }
  }
  __syncthreads();  // (4)

  // ---- ph3: app2 (Y=N^2=Ks); sq2: N^4 -> Gl, N^4T -> Ks ----
  appS(Ut, Ks);
  appS(Wt, Ks);
  {
    f32x4 sq[4];
#pragma unroll
    for (int ni = 0; ni < 4; ++ni) sq[ni] = (f32x4){0.f, 0.f, 0.f, 0.f};
    short8 xf[2];
#pragma unroll
    for (int s = 0; s < 2; ++s) xf[s] = ldb(Ks, xr, s);
#pragma unroll
    for (int ni = 0; ni < 4; ++ni)
#pragma unroll
      for (int s = 0; s < 2; ++s)
        sq[ni] = MFMA(xf[s], ldb(Gh, 16 * ni + fr, s), sq[ni], 0, 0, 0);
    __syncthreads();  // (5) Ks/Gh reads done
#pragma unroll
    for (int ni = 0; ni < 4; ++ni)
#pragma unroll
      for (int rg = 0; rg < 4; ++rg) {
        u16 b = f2bf(sq[ni][rg]);
        int rr = 16 * w + orow + rg, cc = 16 * ni + fr;
        Gl[rr][cc] = b;   // N^4
        Ks[cc][rr] = b;   // N^4T
      }
  }
  __syncthreads();  // (6)

  // ---- ph4: app3 (Y=N^4=Gl); sq3: N^8 -> Gh ----
  appS(Ut, Gl);
  appS(Wt, Gl);
  {
    f32x4 sq[4];
#pragma unroll
    for (int ni = 0; ni < 4; ++ni) sq[ni] = (f32x4){0.f, 0.f, 0.f, 0.f};
    short8 xf[2];
#pragma unroll
    for (int s = 0; s < 2; ++s) xf[s] = ldb(Gl, xr, s);
#pragma unroll
    for (int ni = 0; ni < 4; ++ni)
#pragma unroll
      for (int s = 0; s < 2; ++s)
        sq[ni] = MFMA(xf[s], ldb(Ks, 16 * ni + fr, s), sq[ni], 0, 0, 0);
    // Gh (N^2T) dead since ph3 -> direct write
#pragma unroll
    for (int ni = 0; ni < 4; ++ni)
#pragma unroll
      for (int rg = 0; rg < 4; ++rg)
        Gh[16 * w + orow + rg][16 * ni + fr] = f2bf(sq[ni][rg]);
  }
  __syncthreads();  // (7)

  // ---- ph5: app4 (Y=N^8=Gh) ----
  appS(Ut, Gh);
  appS(Wt, Gh);
  __syncthreads();  // (7b) all app4 reads of Gh + state writes settled

  // ---- ph6: P = W^T K, R = Ubar^T K (hi/lo x-side, Y = ldb(KsT));
  //           conversions Wb->Gh, Ub->Gl (all rows), Smb->Ks (own rows) ----
  const size_t base = ((size_t)c * H_ + h) * 4096;
  {
    short8 xh[2], xl[2];
#pragma unroll
    for (int s = 0; s < 2; ++s) ldf(Wt, xr, s, xh[s], xl[s]);
    f32x4 acc[4];
#pragma unroll
    for (int ni = 0; ni < 4; ++ni) acc[ni] = (f32x4){0.f, 0.f, 0.f, 0.f};
#pragma unroll
    for (int ni = 0; ni < 4; ++ni)
#pragma unroll
      for (int s = 0; s < 2; ++s) {
        short8 yf = ldb(KsT, 16 * ni + fr, s);
        acc[ni] = MFMA(xh[s], yf, acc[ni], 0, 0, 0);
        acc[ni] = MFMA(xl[s], yf, acc[ni], 0, 0, 0);
      }
#pragma unroll
    for (int ni = 0; ni < 4; ++ni)
#pragma unroll
      for (int rg = 0; rg < 4; ++rg)
        stv(&Pg[base + (16 * w + orow + rg) * 64 + 16 * ni + fr], acc[ni][rg]);
  }
  {
    short8 xh[2], xl[2];
#pragma unroll
    for (int s = 0; s < 2; ++s) ldf(Ut, xr, s, xh[s], xl[s]);
    f32x4 acc[4];
#pragma unroll
    for (int ni = 0; ni < 4; ++ni) acc[ni] = (f32x4){0.f, 0.f, 0.f, 0.f};
#pragma unroll
    for (int ni = 0; ni < 4; ++ni)
#pragma unroll
      for (int s = 0; s < 2; ++s) {
        short8 yf = ldb(KsT, 16 * ni + fr, s);
        acc[ni] = MFMA(xh[s], yf, acc[ni], 0, 0, 0);
        acc[ni] = MFMA(xl[s], yf, acc[ni], 0, 0, 0);
      }
#pragma unroll
    for (int ni = 0; ni < 4; ++ni)
#pragma unroll
      for (int rg = 0; rg < 4; ++rg)
        stv(&Rg[base + (16 * w + orow + rg) * 64 + 16 * ni + fr], acc[ni][rg]);
  }
  {
    // single-bf16 conversions (Gh/Gl/Ks dead: N^8 after app4, N^4, N^4T)
    const int r = tid >> 2, d0 = (tid & 3) * 16;
    short8 v0, v1;
#pragma unroll
    for (int j = 0; j < 8; ++j) v0[j] = (short)f2bf(Wt[r][d0 + j]);
#pragma unroll
    for (int j = 0; j < 8; ++j) v1[j] = (short)f2bf(Wt[r][d0 + 8 + j]);
    *(short8*)(&Gh[r][d0]) = v0;
    *(short8*)(&Gh[r][d0 + 8]) = v1;
#pragma unroll
    for (int j = 0; j < 8; ++j) v0[j] = (short)f2bf(Ut[r][d0 + j]);
#pragma unroll
    for (int j = 0; j < 8; ++j) v1[j] = (short)f2bf(Ut[r][d0 + 8 + j]);
    *(short8*)(&Gl[r][d0]) = v0;
    *(short8*)(&Gl[r][d0 + 8]) = v1;
  }
#pragma unroll
  for (int ni = 0; ni < 4; ++ni)
#pragma unroll
    for (int rg = 0; rg < 4; ++rg)
      Ks[16 * w + orow + rg][16 * ni + fr] = f2bf(sreg[ni][rg]);
  __syncthreads();  // (8)

  // ---- ph7: E = Q - Smb*Wb -> Qg ; F = Smb*Ub -> Vg (single-pass) ----
  {
    short8 xs[2];
#pragma unroll
    for (int s = 0; s < 2; ++s) xs[s] = ldb(Ks, xr, s);
    f32x4 accE[4], accF[4];
#pragma unroll
    for (int ni = 0; ni < 4; ++ni) {
      accE[ni] = (f32x4){0.f, 0.f, 0.f, 0.f};
      accF[ni] = (f32x4){0.f, 0.f, 0.f, 0.f};
    }
#pragma unroll
    for (int ni = 0; ni < 4; ++ni)
#pragma unroll
      for (int s = 0; s < 2; ++s) {
        accE[ni] = MFMA(xs[s], ldb(Gh, 16 * ni + fr, s), accE[ni], 0, 0, 0);
        accF[ni] = MFMA(xs[s], ldb(Gl, 16 * ni + fr, s), accF[ni], 0, 0, 0);
      }
#pragma unroll
    for (int ni = 0; ni < 4; ++ni)
#pragma unroll
      for (int rg = 0; rg < 4; ++rg) {
        int r = 16 * w + orow + rg, d = 16 * ni + fr;
        size_t g = gidx(r, d);
        float qv = Qg[g];  // exact fp32 Q (read-then-overwrite, same thread)
        Qg[g] = qv - accE[ni][rg];
        Vg[g] = f2bf(accF[ni][rg]);
      }
  }
}

// ---------------- 64x64 fp32 helpers (levels) ----------------
__device__ __forceinline__ void load64(float (*dst)[65], const float* src, int tid) {
  for (int i = tid; i < 4096; i += 256) dst[i >> 6][i & 63] = src[i];
}
__device__ __forceinline__ void store64(float* dst, const float (*src)[65], int tid) {
  for (int i = tid; i < 4096; i += 256) dst[i] = src[i >> 6][i & 63];
}
template<typename PT>
__device__ __forceinline__ void loadPfull(float (*dst)[65], const PT* src, int tid) {
  for (int i = tid; i < 4096; i += 256) {
    int r = i >> 6, cc = i & 63;
    dst[r][cc] = ((r == cc) ? 1.f : 0.f) - ldv(src[i]);
  }
}
template<typename PT>
__device__ __forceinline__ void loadR(float (*dst)[65], const PT* src, int tid) {
  for (int i = tid; i < 4096; i += 256) dst[i >> 6][i & 63] = ldv(src[i]);
}
__device__ __forceinline__ void mm64(const float (*X)[65], const float (*Y)[65],
                                     float (*Dst)[65], const float (*Add)[65], int tid) {
  const int r0 = (tid >> 4) * 4, c0 = (tid & 15) * 4;
  float a[4][4] = {};
  for (int d = 0; d < 64; ++d) {
    float xv[4], yv[4];
#pragma unroll
    for (int i = 0; i < 4; ++i) xv[i] = X[r0 + i][d];
#pragma unroll
    for (int j = 0; j < 4; ++j) yv[j] = Y[d][c0 + j];
#pragma unroll
    for (int i = 0; i < 4; ++i)
#pragma unroll
      for (int j = 0; j < 4; ++j) a[i][j] += xv[i] * yv[j];
  }
  __syncthreads();
#pragma unroll
  for (int i = 0; i < 4; ++i)
#pragma unroll
    for (int j = 0; j < 4; ++j) {
      float v = a[i][j];
      if (Add) v += Add[r0 + i][c0 + j];
      Dst[r0 + i][c0 + j] = v;
    }
  __syncthreads();
}

template<typename PT>
__global__ __launch_bounds__(256) void seq_levelA(const PT* __restrict__ Pg,
    const PT* __restrict__ Rg, float* __restrict__ Psup, float* __restrict__ Rsup) {
  __shared__ float Pa[64][65], Ra[64][65], Pi[64][65], Ri[64][65];
  const int sup = blockIdx.x, h = blockIdx.y, tid = threadIdx.x;
  const int cbase = sup * SUPW;
  loadPfull(Pa, Pg + ((size_t)cbase * H_ + h) * 4096, tid);
  loadR(Ra, Rg + ((size_t)cbase * H_ + h) * 4096, tid);
  __syncthreads();
  for (int s = 1; s < SUPW; ++s) {
    loadPfull(Pi, Pg + ((size_t)(cbase + s) * H_ + h) * 4096, tid);
    loadR(Ri, Rg + ((size_t)(cbase + s) * H_ + h) * 4096, tid);
    __syncthreads();
    mm64(Pa, Pi, Pa, nullptr, tid);
    mm64(Ra, Pi, Ra, Ri, tid);
  }
  store64(Psup + ((size_t)sup * H_ + h) * 4096, Pa, tid);
  store64(Rsup + ((size_t)sup * H_ + h) * 4096, Ra, tid);
}

__global__ __launch_bounds__(256) void seq_levelB(const float* __restrict__ Psup,
    const float* __restrict__ Rsup, float* __restrict__ Msup) {
  __shared__ float Ms[64][65], Pi[64][65], Ri[64][65];
  const int h = blockIdx.x, tid = threadIdx.x;
  for (int i = tid; i < 4096; i += 256) Ms[i >> 6][i & 63] = 0.f;
  __syncthreads();
  for (int s = 0; s < NSUP; ++s) {
    store64(Msup + ((size_t)s * H_ + h) * 4096, Ms, tid);
    load64(Pi, Psup + ((size_t)s * H_ + h) * 4096, tid);
    load64(Ri, Rsup + ((size_t)s * H_ + h) * 4096, tid);
    __syncthreads();
    mm64(Ms, Pi, Ms, Ri, tid);
  }
}

template<typename PT>
__global__ __launch_bounds__(256) void seq_levelC(const PT* __restrict__ Pg,
    PT* __restrict__ Rg, const float* __restrict__ Msup) {
  __shared__ float Ms[64][65], Pi[64][65], Ri[64][65];
  const int sup = blockIdx.x, h = blockIdx.y, tid = threadIdx.x;
  load64(Ms, Msup + ((size_t)sup * H_ + h) * 4096, tid);
  __syncthreads();
  for (int s = 0; s < SUPW; ++s) {
    const size_t slice = ((size_t)(sup * SUPW + s) * H_ + h) * 4096;
    loadPfull(Pi, Pg + slice, tid);
    loadR(Ri, Rg + slice, tid);
    __syncthreads();
    for (int i = tid; i < 4096; i += 256) stv(&Rg[slice + i], Ms[i >> 6][i & 63]);
    mm64(Ms, Pi, Ms, Ri, tid);
  }
}

// ---------------- phase 3: attn = E*M0^T + F (bf16 out) ----------------
template<typename PT>
__global__ __launch_bounds__(256) void phase3_kernel(
    const float* __restrict__ Eg, const u16* __restrict__ Fg,
    const PT* __restrict__ Mcg, u16* __restrict__ attn) {
  __shared__ float Es[64][65], Ms[64][65];
  const int c = blockIdx.x, h = blockIdx.y, tid = threadIdx.x;
  for (int i = tid; i < 4096; i += 256) {
    int r = i >> 6, d = i & 63, t = r >> 2, b = r & 3;
    size_t g = ((size_t)b * S_ + (size_t)c * CHUNK + t) * D_ + h * 64 + d;
    Es[r][d] = Eg[g];
    Ms[i >> 6][i & 63] = ldv(Mcg[((size_t)c * H_ + h) * 4096 + i]);
  }
  __syncthreads();
  const int r0 = (tid >> 4) * 4, d0 = (tid & 15) * 4;
  float a[4][4] = {};
  for (int k = 0; k < 64; ++k) {
    float ev[4], mv[4];
#pragma unroll
    for (int i = 0; i < 4; ++i) ev[i] = Es[r0 + i][k];
#pragma unroll
    for (int j = 0; j < 4; ++j) mv[j] = Ms[d0 + j][k];
#pragma unroll
    for (int i = 0; i < 4; ++i)
#pragma unroll
      for (int j = 0; j < 4; ++j) a[i][j] += ev[i] * mv[j];
  }
#pragma unroll
  for (int i = 0; i < 4; ++i)
#pragma unroll
    for (int j = 0; j < 4; ++j) {
      int r = r0 + i, d = d0 + j, t = r >> 2, b = r & 3;
      size_t g = ((size_t)b * S_ + (size_t)c * CHUNK + t) * D_ + h * 64 + d;
      attn[g] = f2bf(a[i][j] + bf2f(Fg[g]));
    }
}

// ---------------- launch ----------------
extern "C" void kernel_launch(void* const* d_in, const int* in_sizes, int n_in,
                              void* d_out, int out_size, void* d_ws, size_t ws_size,
                              hipStream_t stream) {
  (void)in_sizes; (void)n_in; (void)out_size;
  const float* x  = (const float*)d_in[0];
  const float* Wq = (const float*)d_in[1];
  const float* Wk = (const float*)d_in[2];
  const float* Wv = (const float*)d_in[3];
  const float* Wo = (const float*)d_in[4];
  float* out = (float*)d_out;

  char* w = (char*)d_ws;
  const size_t MB = 1024 * 1024;
  // big (>=192MB): [0,32) Kbf->smalls ; [32,64) Vbf->F ; [64,96) xh ; [96,128) xl ;
  //   P fp32 [64,128) over xh/xl ; R fp32 [128,192) ; Wsp [128,144) time-muxed ;
  //   attn over P.
  u16* Kbf = (u16*)w;
  u16* Vbf = (u16*)(w + 32 * MB);
  u16* xh  = (u16*)(w + 64 * MB);
  u16* xl  = (u16*)(w + 96 * MB);
  const bool big = ws_size >= 192 * MB;
  void* Preg = (void*)(w + 64 * MB);
  void* Rreg = big ? (void*)(w + 128 * MB) : (void*)(w + 96 * MB);
  float* Psup = (float*)w;
  float* Rsup = (float*)(w + 4 * MB);
  float* Msup = (float*)(w + 8 * MB);
  u16* attn = (u16*)Preg;
  u16* Wsp = (u16*)(w + 128 * MB);  // hi/lo u16 pairs at +0/+1M, +2/+3M, +4/+5M

  const size_t DSZ = (size_t)B_ * S_ * D_;  // 16777216
  split4_kernel<<<2048, 256, 0, stream>>>(x, xh, xl, (int)(DSZ / 4));

  dim3 gg(128, 8);
  if (big) {
    split4_kernel<<<512, 256, 0, stream>>>(Wq, Wsp + 0 * 1048576u, Wsp + 1 * 1048576u, 262144);
    split4_kernel<<<512, 256, 0, stream>>>(Wk, Wsp + 2 * 1048576u, Wsp + 3 * 1048576u, 262144);
    split4_kernel<<<512, 256, 0, stream>>>(Wv, Wsp + 4 * 1048576u, Wsp + 5 * 1048576u, 262144);
    gemm_axw<2, 1, 1, float><<<gg, 256, 0, stream>>>(xh, xl, Wsp + 0 * 1048576u, nullptr, out, 16384, 1024, 1024);
    gemm_axw<2, 1, 1, u16><<<gg, 256, 0, stream>>>(xh, xl, Wsp + 2 * 1048576u, nullptr, Kbf, 16384, 1024, 1024);
    gemm_axw<2, 1, 1, u16><<<gg, 256, 0, stream>>>(xh, xl, Wsp + 4 * 1048576u, nullptr, Vbf, 16384, 1024, 1024);
    float* P = (float*)Preg; float* R = (float*)Rreg;
    phase1_kernel<float><<<dim3(NCHUNK, H_), 256, 0, stream>>>(out, Kbf, Vbf, P, R);
    seq_levelA<float><<<dim3(NSUP, H_), 256, 0, stream>>>(P, R, Psup, Rsup);
    seq_levelB<<<dim3(H_), 256, 0, stream>>>(Psup, Rsup, Msup);
    seq_levelC<float><<<dim3(NSUP, H_), 256, 0, stream>>>(P, R, Msup);
    phase3_kernel<float><<<dim3(NCHUNK, H_), 256, 0, stream>>>(out, Vbf, R, attn);
    split4_kernel<<<512, 256, 0, stream>>>(Wo, Wsp + 0 * 1048576u, Wsp + 1 * 1048576u, 262144);
    gemm_axw<1, 2, 1, float><<<gg, 256, 0, stream>>>(attn, nullptr, Wsp + 0 * 1048576u, Wsp + 1 * 1048576u, out, 16384, 1024, 1024);
  } else {
    gemm_axw<2, 1, 0, float><<<gg, 256, 0, stream>>>(xh, xl, Wq, nullptr, out, 16384, 1024, 1024);
    gemm_axw<2, 1, 0, u16><<<gg, 256, 0, stream>>>(xh, xl, Wk, nullptr, Kbf, 16384, 1024, 1024);
    gemm_axw<2, 1, 0, u16><<<gg, 256, 0, stream>>>(xh, xl, Wv, nullptr, Vbf, 16384, 1024, 1024);
    u16* P = (u16*)Preg; u16* R = (u16*)Rreg;
    phase1_kernel<u16><<<dim3(NCHUNK, H_), 256, 0, stream>>>(out, Kbf, Vbf, P, R);
    seq_levelA<u16><<<dim3(NSUP, H_), 256, 0, stream>>>(P, R, Psup, Rsup);
    seq_levelB<<<dim3(H_), 256, 0, stream>>>(Psup, Rsup, Msup);
    seq_levelC<u16><<<dim3(NSUP, H_), 256, 0, stream>>>(P, R, Msup);
    phase3_kernel<u16><<<dim3(NCHUNK, H_), 256, 0, stream>>>(out, Vbf, R, attn);
    gemm_axw<1, 2, 0, float><<<gg, 256, 0, stream>>>(attn, nullptr, Wo, nullptr, out, 16384, 1024, 1024);
  }
}

// Round 8
// 869.809 us; speedup vs baseline: 1.5920x; 1.0037x over previous
//
#include <hip/hip_runtime.h>

// L2RegressionAttention — chunked WY-transform.
// r8: software-prefetch the serial level kernels (issue next P/R loads into
// registers under the mm64 compute; write to LDS next iteration) — exact fp32
// math unchanged. XCD-swizzle the GEMM block order (bijective, nwg%8==0).
// Everything else identical to passing r7.
// B=4, S=4096, D=1024, H=16, hd=64, eta = 0.1/4 = 0.025.

typedef unsigned short u16;
typedef __attribute__((ext_vector_type(8))) short short8;
typedef __attribute__((ext_vector_type(4))) float f32x4;

#define B_ 4
#define S_ 4096
#define D_ 1024
#define H_ 16
#define CHUNK 16
#define NCHUNK 256
#define SUPW 16
#define NSUP 16
#define ETA 0.025f

__device__ __forceinline__ u16 f2bf(float f) {
  unsigned u = __builtin_bit_cast(unsigned, f);
  u += 0x7fffu + ((u >> 16) & 1u);
  return (u16)(u >> 16);
}
__device__ __forceinline__ float bf2f(u16 s) {
  unsigned u = ((unsigned)s) << 16;
  return __builtin_bit_cast(float, u);
}
__device__ __forceinline__ float ldv(float v) { return v; }
__device__ __forceinline__ float ldv(u16 v) { return bf2f(v); }
__device__ __forceinline__ void stv(float* p, float v) { *p = v; }
__device__ __forceinline__ void stv(u16* p, float v) { *p = f2bf(v); }

#define MFMA __builtin_amdgcn_mfma_f32_16x16x32_bf16

// ---------------- fp32 -> (hi, lo) bf16 split, float4-vectorized ----------------
__global__ void split4_kernel(const float* __restrict__ x, u16* __restrict__ hi,
                              u16* __restrict__ lo, int n4) {
  int i = blockIdx.x * blockDim.x + threadIdx.x;
  int stride = gridDim.x * blockDim.x;
  for (; i < n4; i += stride) {
    float4 v = ((const float4*)x)[i];
    ushort4 h, l;
    h.x = f2bf(v.x); l.x = f2bf(v.x - bf2f(h.x));
    h.y = f2bf(v.y); l.y = f2bf(v.y - bf2f(h.y));
    h.z = f2bf(v.z); l.z = f2bf(v.z - bf2f(h.z));
    h.w = f2bf(v.w); l.w = f2bf(v.w - bf2f(h.w));
    ((ushort4*)hi)[i] = h;
    ((ushort4*)lo)[i] = l;
  }
}

// ---------------- GEMM: C[M][N] = A * B^T ----------------
// A: pre-split bf16 (Ah, +Al if AP==2). B: BPRE=1 pre-split bf16; BPRE=0 fp32
// split on the fly. Combos: ah*bh (+ ah*bl if BP==2) (+ al*bh if AP==2).
// 128x128 tile, BK=32, 4 waves. XCD-swizzled block order (T1).
template<int AP, int BP, int BPRE, typename OutT>
__global__ __launch_bounds__(256) void gemm_axw(
    const u16* __restrict__ Ahg, const u16* __restrict__ Alg,
    const void* __restrict__ Bhp, const u16* __restrict__ Blg,
    OutT* __restrict__ C, int M, int N, int K) {
  __shared__ __align__(16) u16 Ahs[128][32];
  __shared__ __align__(16) u16 Als[AP == 2 ? 128 : 1][32];
  __shared__ __align__(16) u16 Bhs[128][32];
  __shared__ __align__(16) u16 Bls[BP == 2 ? 128 : 1][32];
  const int tid = threadIdx.x, w = tid >> 6, lane = tid & 63;
  // XCD-aware swizzle: consecutive blocks on one XCD share the B panel
  const int nwg = gridDim.x * gridDim.y;
  const int orig = blockIdx.y * gridDim.x + blockIdx.x;
  const int id = ((nwg & 7) == 0) ? ((orig & 7) * (nwg >> 3) + (orig >> 3)) : orig;
  const int bm = (id % gridDim.x) * 128, bn = (id / gridDim.x) * 128;
  const int wm = (w >> 1) * 64, wn = (w & 1) * 64;
  const int fr = lane & 15, kb = lane >> 4;

  f32x4 acc[4][4];
#pragma unroll
  for (int i = 0; i < 4; ++i)
#pragma unroll
    for (int j = 0; j < 4; ++j) acc[i][j] = (f32x4){0.f, 0.f, 0.f, 0.f};

  for (int k0 = 0; k0 < K; k0 += 32) {
    __syncthreads();  // prior frag reads complete before overwrite
#pragma unroll
    for (int i = 0; i < 2; ++i) {
      int e = tid + i * 256;             // 0..511
      int r = e >> 2, sg = (e & 3) * 8;  // 8 u16 = 16B
      *(uint4*)(&Ahs[r][sg]) = *(const uint4*)(&Ahg[(size_t)(bm + r) * K + k0 + sg]);
      if constexpr (AP == 2)
        *(uint4*)(&Als[r][sg]) = *(const uint4*)(&Alg[(size_t)(bm + r) * K + k0 + sg]);
    }
    if constexpr (BPRE) {
      const u16* Bhg = (const u16*)Bhp;
#pragma unroll
      for (int i = 0; i < 2; ++i) {
        int e = tid + i * 256;
        int r = e >> 2, sg = (e & 3) * 8;
        *(uint4*)(&Bhs[r][sg]) = *(const uint4*)(&Bhg[(size_t)(bn + r) * K + k0 + sg]);
        if constexpr (BP == 2)
          *(uint4*)(&Bls[r][sg]) = *(const uint4*)(&Blg[(size_t)(bn + r) * K + k0 + sg]);
      }
    } else {
      const float* Bm = (const float*)Bhp;
#pragma unroll
      for (int i = 0; i < 4; ++i) {
        int e = tid + i * 256, r = e >> 3, sg = (e & 7) * 4;
        float4 v = *(const float4*)(&Bm[(size_t)(bn + r) * K + k0 + sg]);
        ushort4 h;
        h.x = f2bf(v.x); h.y = f2bf(v.y); h.z = f2bf(v.z); h.w = f2bf(v.w);
        *(ushort4*)(&Bhs[r][sg]) = h;
        if constexpr (BP == 2) {
          ushort4 l;
          l.x = f2bf(v.x - bf2f(h.x));
          l.y = f2bf(v.y - bf2f(h.y));
          l.z = f2bf(v.z - bf2f(h.z));
          l.w = f2bf(v.w - bf2f(h.w));
          *(ushort4*)(&Bls[r][sg]) = l;
        }
      }
    }
    __syncthreads();  // tiles ready
    short8 ah[4], al[4], bh[4], bl[4];
#pragma unroll
    for (int mi = 0; mi < 4; ++mi) {
      ah[mi] = *(const short8*)(&Ahs[wm + mi * 16 + fr][kb * 8]);
      if constexpr (AP == 2) al[mi] = *(const short8*)(&Als[wm + mi * 16 + fr][kb * 8]);
    }
#pragma unroll
    for (int ni = 0; ni < 4; ++ni) {
      bh[ni] = *(const short8*)(&Bhs[wn + ni * 16 + fr][kb * 8]);
      if constexpr (BP == 2) bl[ni] = *(const short8*)(&Bls[wn + ni * 16 + fr][kb * 8]);
    }
#pragma unroll
    for (int mi = 0; mi < 4; ++mi)
#pragma unroll
      for (int ni = 0; ni < 4; ++ni) {
        acc[mi][ni] = MFMA(ah[mi], bh[ni], acc[mi][ni], 0, 0, 0);
        if constexpr (BP == 2)
          acc[mi][ni] = MFMA(ah[mi], bl[ni], acc[mi][ni], 0, 0, 0);
        if constexpr (AP == 2)
          acc[mi][ni] = MFMA(al[mi], bh[ni], acc[mi][ni], 0, 0, 0);
      }
  }
  const int fc = lane & 15, fr4 = (lane >> 4) * 4;
#pragma unroll
  for (int mi = 0; mi < 4; ++mi)
#pragma unroll
    for (int ni = 0; ni < 4; ++ni) {
      int gm = bm + wm + mi * 16 + fr4;
      int gn = bn + wn + ni * 16 + fc;
#pragma unroll
      for (int rg = 0; rg < 4; ++rg)
        stv(&C[(size_t)(gm + rg) * N + gn], acc[mi][ni][rg]);
    }
}

// ---------------- phase 1 (MFMA, no strided LDS reads) — unchanged r7 ----------------
template<typename PT>
__global__ __launch_bounds__(256) void phase1_kernel(
    float* __restrict__ Qg, const u16* __restrict__ Kg, u16* __restrict__ Vg,
    PT* __restrict__ Pg, PT* __restrict__ Rg) {
  __shared__ __align__(16) u16 Ks[64][72];
  __shared__ __align__(16) u16 KsT[64][72];
  __shared__ __align__(16) u16 Gh[64][72];
  __shared__ __align__(16) u16 Gl[64][72];
  __shared__ __align__(16) float Ut[64][68];
  __shared__ __align__(16) float Wt[64][68];

  const int c = blockIdx.x, h = blockIdx.y, tid = threadIdx.x;
  const int w = tid >> 6, lane = tid & 63;
  const int fr = lane & 15, kq = lane >> 4, orow = kq * 4;
  const int xr = 16 * w + fr;

  auto gidx = [&](int r, int d) -> size_t {
    return ((size_t)(r & 3) * S_ + (size_t)c * CHUNK + (r >> 2)) * D_ + h * 64 + d;
  };
  auto ldb = [&](const u16 (*M)[72], int row, int s) -> short8 {
    return *(const short8*)(&M[row][32 * s + 8 * kq]);
  };
  auto ldm = [&](const u16 (*M)[72], int row, int s, bool up) -> short8 {
    short8 r = *(const short8*)(&M[row][32 * s + 8 * kq]);
    int rb = row >> 2, k0 = 32 * s + 8 * kq;
#pragma unroll
    for (int j = 0; j < 8; ++j) {
      int kb2 = (k0 + j) >> 2;
      bool keep = up ? (kb2 > rb) : (rb > kb2);
      if (!keep) r[j] = 0;
    }
    return r;
  };
  auto ldf = [&](const float (*M)[68], int row, int s, short8& hh, short8& ll) {
    const float* p = &M[row][32 * s + 8 * kq];
#pragma unroll
    for (int j = 0; j < 8; ++j) {
      float v = p[j];
      u16 hb = f2bf(v);
      hh[j] = (short)hb;
      ll[j] = (short)f2bf(v - bf2f(hb));
    }
  };
  auto ldfh = [&](const float (*M)[68], int row, int s) -> short8 {
    const float* p = &M[row][32 * s + 8 * kq];
    short8 hh;
#pragma unroll
    for (int j = 0; j < 8; ++j) hh[j] = (short)f2bf(p[j]);
    return hh;
  };

  for (int i = tid; i < 4096; i += 256) {
    int r = i >> 6, d = i & 63;
    size_t g = gidx(r, d);
    u16 kraw = Kg[g];
    Ks[r][d] = kraw;
    KsT[d][r] = kraw;
    Wt[d][r] = ETA * bf2f(kraw);
    Ut[d][r] = ETA * bf2f(Vg[g]);
  }
  __syncthreads();  // (1)

  {
    f32x4 acc[4];
#pragma unroll
    for (int ni = 0; ni < 4; ++ni) acc[ni] = (f32x4){0.f, 0.f, 0.f, 0.f};
    short8 xf[2];
#pragma unroll
    for (int s = 0; s < 2; ++s) xf[s] = ldb(Ks, xr, s);
#pragma unroll
    for (int ni = 0; ni < 4; ++ni)
#pragma unroll
      for (int s = 0; s < 2; ++s)
        acc[ni] = MFMA(xf[s], ldb(Ks, 16 * ni + fr, s), acc[ni], 0, 0, 0);
#pragma unroll
    for (int ni = 0; ni < 4; ++ni)
#pragma unroll
      for (int rg = 0; rg < 4; ++rg) {
        float v = -ETA * acc[ni][rg];
        u16 hb = f2bf(v);
        int rr = 16 * w + orow + rg, cc = 16 * ni + fr;
        Gh[rr][cc] = hb;
        Gl[rr][cc] = f2bf(v - bf2f(hb));
      }
  }

  float sreg[4][4];
  {
    short8 xh[2], xl[2];
#pragma unroll
    for (int s = 0; s < 2; ++s) {
      const float* qp = &Qg[gidx(xr, 32 * s + 8 * kq)];
#pragma unroll
      for (int j = 0; j < 8; ++j) {
        float v = qp[j];
        u16 hb = f2bf(v);
        xh[s][j] = (short)hb;
        xl[s][j] = (short)f2bf(v - bf2f(hb));
      }
    }
    f32x4 acc[4];
#pragma unroll
    for (int ni = 0; ni < 4; ++ni) acc[ni] = (f32x4){0.f, 0.f, 0.f, 0.f};
#pragma unroll
    for (int ni = 0; ni < 4; ++ni)
#pragma unroll
      for (int s = 0; s < 2; ++s) {
        short8 yf = ldb(Ks, 16 * ni + fr, s);
        acc[ni] = MFMA(xh[s], yf, acc[ni], 0, 0, 0);
        acc[ni] = MFMA(xl[s], yf, acc[ni], 0, 0, 0);
      }
#pragma unroll
    for (int ni = 0; ni < 4; ++ni)
#pragma unroll
      for (int rg = 0; rg < 4; ++rg) {
        int r = 16 * w + orow + rg, cc = 16 * ni + fr;
        sreg[ni][rg] = ((r >> 2) >= (cc >> 2)) ? acc[ni][rg] : 0.f;
      }
  }
  __syncthreads();  // (2) G ready

  auto app1 = [&](float (*St)[68]) {
    short8 xh[2], xl[2];
#pragma unroll
    for (int s = 0; s < 2; ++s) ldf(St, xr, s, xh[s], xl[s]);
    f32x4 acc[4];
#pragma unroll
    for (int ni = 0; ni < 4; ++ni) acc[ni] = (f32x4){0.f, 0.f, 0.f, 0.f};
#pragma unroll
    for (int ni = 0; ni < 4; ++ni)
#pragma unroll
      for (int s = 0; s < 2; ++s) {
        short8 yh = ldm(Gh, 16 * ni + fr, s, false);
        short8 yl = ldm(Gl, 16 * ni + fr, s, false);
        acc[ni] = MFMA(xh[s], yh, acc[ni], 0, 0, 0);
        acc[ni] = MFMA(xh[s], yl, acc[ni], 0, 0, 0);
        acc[ni] = MFMA(xl[s], yh, acc[ni], 0, 0, 0);
      }
#pragma unroll
    for (int ni = 0; ni < 4; ++ni)
#pragma unroll
      for (int rg = 0; rg < 4; ++rg)
        St[16 * w + orow + rg][16 * ni + fr] += acc[ni][rg];
  };
  auto appS = [&](float (*St)[68], const u16 (*Np)[72]) {
    short8 xh[2];
#pragma unroll
    for (int s = 0; s < 2; ++s) xh[s] = ldfh(St, xr, s);
    f32x4 acc[4];
#pragma unroll
    for (int ni = 0; ni < 4; ++ni) acc[ni] = (f32x4){0.f, 0.f, 0.f, 0.f};
#pragma unroll
    for (int ni = 0; ni < 4; ++ni)
#pragma unroll
      for (int s = 0; s < 2; ++s)
        acc[ni] = MFMA(xh[s], ldb(Np, 16 * ni + fr, s), acc[ni], 0, 0, 0);
#pragma unroll
    for (int ni = 0; ni < 4; ++ni)
#pragma unroll
      for (int rg = 0; rg < 4; ++rg)
        St[16 * w + orow + rg][16 * ni + fr] += acc[ni][rg];
  };

  app1(Ut);
  app1(Wt);
  {
    f32x4 sq[4];
#pragma unroll
    for (int ni = 0; ni < 4; ++ni) sq[ni] = (f32x4){0.f, 0.f, 0.f, 0.f};
    short8 xh[2], xl[2];
#pragma unroll
    for (int s = 0; s < 2; ++s) {
      xh[s] = ldm(Gh, xr, s, false);
      xl[s] = ldm(Gl, xr, s, false);
    }
#pragma unroll
    for (int ni = 0; ni < 4; ++ni)
#pragma unroll
      for (int s = 0; s < 2; ++s) {
        short8 yh = ldm(Gh, 16 * ni + fr, s, true);
        short8 yl = ldm(Gl, 16 * ni + fr, s, true);
        sq[ni] = MFMA(xh[s], yh, sq[ni], 0, 0, 0);
        sq[ni] = MFMA(xh[s], yl, sq[ni], 0, 0, 0);
        sq[ni] = MFMA(xl[s], yh, sq[ni], 0, 0, 0);
      }
    __syncthreads();  // (3)
#pragma unroll
    for (int ni = 0; ni < 4; ++ni)
#pragma unroll
      for (int rg = 0; rg < 4; ++rg) {
        u16 b = f2bf(sq[ni][rg]);
        int rr = 16 * w + orow + rg, cc = 16 * ni + fr;
        Ks[rr][cc] = b;   // N^2
        Gh[cc][rr] = b;   // N^2T
      }
  }
  __syncthreads();  // (4)

  appS(Ut, Ks);
  appS(Wt, Ks);
  {
    f32x4 sq[4];
#pragma unroll
    for (int ni = 0; ni < 4; ++ni) sq[ni] = (f32x4){0.f, 0.f, 0.f, 0.f};
    short8 xf[2];
#pragma unroll
    for (int s = 0; s < 2; ++s) xf[s] = ldb(Ks, xr, s);
#pragma unroll
    for (int ni = 0; ni < 4; ++ni)
#pragma unroll
      for (int s = 0; s < 2; ++s)
        sq[ni] = MFMA(xf[s], ldb(Gh, 16 * ni + fr, s), sq[ni], 0, 0, 0);
    __syncthreads();  // (5)
#pragma unroll
    for (int ni = 0; ni < 4; ++ni)
#pragma unroll
      for (int rg = 0; rg < 4; ++rg) {
        u16 b = f2bf(sq[ni][rg]);
        int rr = 16 * w + orow + rg, cc = 16 * ni + fr;
        Gl[rr][cc] = b;   // N^4
        Ks[cc][rr] = b;   // N^4T
      }
  }
  __syncthreads();  // (6)

  appS(Ut, Gl);
  appS(Wt, Gl);
  {
    f32x4 sq[4];
#pragma unroll
    for (int ni = 0; ni < 4; ++ni) sq[ni] = (f32x4){0.f, 0.f, 0.f, 0.f};
    short8 xf[2];
#pragma unroll
    for (int s = 0; s < 2; ++s) xf[s] = ldb(Gl, xr, s);
#pragma unroll
    for (int ni = 0; ni < 4; ++ni)
#pragma unroll
      for (int s = 0; s < 2; ++s)
        sq[ni] = MFMA(xf[s], ldb(Ks, 16 * ni + fr, s), sq[ni], 0, 0, 0);
#pragma unroll
    for (int ni = 0; ni < 4; ++ni)
#pragma unroll
      for (int rg = 0; rg < 4; ++rg)
        Gh[16 * w + orow + rg][16 * ni + fr] = f2bf(sq[ni][rg]);
  }
  __syncthreads();  // (7)

  appS(Ut, Gh);
  appS(Wt, Gh);
  __syncthreads();  // (7b)

  const size_t base = ((size_t)c * H_ + h) * 4096;
  {
    short8 xh[2], xl[2];
#pragma unroll
    for (int s = 0; s < 2; ++s) ldf(Wt, xr, s, xh[s], xl[s]);
    f32x4 acc[4];
#pragma unroll
    for (int ni = 0; ni < 4; ++ni) acc[ni] = (f32x4){0.f, 0.f, 0.f, 0.f};
#pragma unroll
    for (int ni = 0; ni < 4; ++ni)
#pragma unroll
      for (int s = 0; s < 2; ++s) {
        short8 yf = ldb(KsT, 16 * ni + fr, s);
        acc[ni] = MFMA(xh[s], yf, acc[ni], 0, 0, 0);
        acc[ni] = MFMA(xl[s], yf, acc[ni], 0, 0, 0);
      }
#pragma unroll
    for (int ni = 0; ni < 4; ++ni)
#pragma unroll
      for (int rg = 0; rg < 4; ++rg)
        stv(&Pg[base + (16 * w + orow + rg) * 64 + 16 * ni + fr], acc[ni][rg]);
  }
  {
    short8 xh[2], xl[2];
#pragma unroll
    for (int s = 0; s < 2; ++s) ldf(Ut, xr, s, xh[s], xl[s]);
    f32x4 acc[4];
#pragma unroll
    for (int ni = 0; ni < 4; ++ni) acc[ni] = (f32x4){0.f, 0.f, 0.f, 0.f};
#pragma unroll
    for (int ni = 0; ni < 4; ++ni)
#pragma unroll
      for (int s = 0; s < 2; ++s) {
        short8 yf = ldb(KsT, 16 * ni + fr, s);
        acc[ni] = MFMA(xh[s], yf, acc[ni], 0, 0, 0);
        acc[ni] = MFMA(xl[s], yf, acc[ni], 0, 0, 0);
      }
#pragma unroll
    for (int ni = 0; ni < 4; ++ni)
#pragma unroll
      for (int rg = 0; rg < 4; ++rg)
        stv(&Rg[base + (16 * w + orow + rg) * 64 + 16 * ni + fr], acc[ni][rg]);
  }
  {
    const int r = tid >> 2, d0 = (tid & 3) * 16;
    short8 v0, v1;
#pragma unroll
    for (int j = 0; j < 8; ++j) v0[j] = (short)f2bf(Wt[r][d0 + j]);
#pragma unroll
    for (int j = 0; j < 8; ++j) v1[j] = (short)f2bf(Wt[r][d0 + 8 + j]);
    *(short8*)(&Gh[r][d0]) = v0;
    *(short8*)(&Gh[r][d0 + 8]) = v1;
#pragma unroll
    for (int j = 0; j < 8; ++j) v0[j] = (short)f2bf(Ut[r][d0 + j]);
#pragma unroll
    for (int j = 0; j < 8; ++j) v1[j] = (short)f2bf(Ut[r][d0 + 8 + j]);
    *(short8*)(&Gl[r][d0]) = v0;
    *(short8*)(&Gl[r][d0 + 8]) = v1;
  }
#pragma unroll
  for (int ni = 0; ni < 4; ++ni)
#pragma unroll
    for (int rg = 0; rg < 4; ++rg)
      Ks[16 * w + orow + rg][16 * ni + fr] = f2bf(sreg[ni][rg]);
  __syncthreads();  // (8)

  {
    short8 xs[2];
#pragma unroll
    for (int s = 0; s < 2; ++s) xs[s] = ldb(Ks, xr, s);
    f32x4 accE[4], accF[4];
#pragma unroll
    for (int ni = 0; ni < 4; ++ni) {
      accE[ni] = (f32x4){0.f, 0.f, 0.f, 0.f};
      accF[ni] = (f32x4){0.f, 0.f, 0.f, 0.f};
    }
#pragma unroll
    for (int ni = 0; ni < 4; ++ni)
#pragma unroll
      for (int s = 0; s < 2; ++s) {
        accE[ni] = MFMA(xs[s], ldb(Gh, 16 * ni + fr, s), accE[ni], 0, 0, 0);
        accF[ni] = MFMA(xs[s], ldb(Gl, 16 * ni + fr, s), accF[ni], 0, 0, 0);
      }
#pragma unroll
    for (int ni = 0; ni < 4; ++ni)
#pragma unroll
      for (int rg = 0; rg < 4; ++rg) {
        int r = 16 * w + orow + rg, d = 16 * ni + fr;
        size_t g = gidx(r, d);
        float qv = Qg[g];
        Qg[g] = qv - accE[ni][rg];
        Vg[g] = f2bf(accF[ni][rg]);
      }
  }
}

// ---------------- 64x64 fp32 helpers (levels) ----------------
__device__ __forceinline__ void load64(float (*dst)[65], const float* src, int tid) {
  for (int i = tid; i < 4096; i += 256) dst[i >> 6][i & 63] = src[i];
}
__device__ __forceinline__ void store64(float* dst, const float (*src)[65], int tid) {
  for (int i = tid; i < 4096; i += 256) dst[i] = src[i >> 6][i & 63];
}
template<typename PT>
__device__ __forceinline__ void loadPfull(float (*dst)[65], const PT* src, int tid) {
  for (int i = tid; i < 4096; i += 256) {
    int r = i >> 6, cc = i & 63;
    dst[r][cc] = ((r == cc) ? 1.f : 0.f) - ldv(src[i]);
  }
}
template<typename PT>
__device__ __forceinline__ void loadR(float (*dst)[65], const PT* src, int tid) {
  for (int i = tid; i < 4096; i += 256) dst[i >> 6][i & 63] = ldv(src[i]);
}
__device__ __forceinline__ void mm64(const float (*X)[65], const float (*Y)[65],
                                     float (*Dst)[65], const float (*Add)[65], int tid) {
  const int r0 = (tid >> 4) * 4, c0 = (tid & 15) * 4;
  float a[4][4] = {};
  for (int d = 0; d < 64; ++d) {
    float xv[4], yv[4];
#pragma unroll
    for (int i = 0; i < 4; ++i) xv[i] = X[r0 + i][d];
#pragma unroll
    for (int j = 0; j < 4; ++j) yv[j] = Y[d][c0 + j];
#pragma unroll
    for (int i = 0; i < 4; ++i)
#pragma unroll
      for (int j = 0; j < 4; ++j) a[i][j] += xv[i] * yv[j];
  }
  __syncthreads();
#pragma unroll
  for (int i = 0; i < 4; ++i)
#pragma unroll
    for (int j = 0; j < 4; ++j) {
      float v = a[i][j];
      if (Add) v += Add[r0 + i][c0 + j];
      Dst[r0 + i][c0 + j] = v;
    }
  __syncthreads();
}

// level A with register prefetch: next-slice P/R loads hide under mm64 compute
template<typename PT>
__global__ __launch_bounds__(256) void seq_levelA(const PT* __restrict__ Pg,
    const PT* __restrict__ Rg, float* __restrict__ Psup, float* __restrict__ Rsup) {
  __shared__ float Pa[64][65], Ra[64][65], Pi[64][65], Ri[64][65];
  const int sup = blockIdx.x, h = blockIdx.y, tid = threadIdx.x;
  const int cbase = sup * SUPW;
  loadPfull(Pa, Pg + ((size_t)cbase * H_ + h) * 4096, tid);
  loadR(Ra, Rg + ((size_t)cbase * H_ + h) * 4096, tid);
  float pf[16], rf[16];
  {
    const PT* ps = Pg + ((size_t)(cbase + 1) * H_ + h) * 4096;
    const PT* rs = Rg + ((size_t)(cbase + 1) * H_ + h) * 4096;
#pragma unroll
    for (int k = 0; k < 16; ++k) { int i = tid + k * 256; pf[k] = ldv(ps[i]); rf[k] = ldv(rs[i]); }
  }
  for (int s = 1; s < SUPW; ++s) {
#pragma unroll
    for (int k = 0; k < 16; ++k) {
      int i = tid + k * 256, r = i >> 6, cc = i & 63;
      Pi[r][cc] = ((r == cc) ? 1.f : 0.f) - pf[k];
      Ri[r][cc] = rf[k];
    }
    __syncthreads();
    if (s + 1 < SUPW) {
      const PT* ps = Pg + ((size_t)(cbase + s + 1) * H_ + h) * 4096;
      const PT* rs = Rg + ((size_t)(cbase + s + 1) * H_ + h) * 4096;
#pragma unroll
      for (int k = 0; k < 16; ++k) { int i = tid + k * 256; pf[k] = ldv(ps[i]); rf[k] = ldv(rs[i]); }
    }
    mm64(Pa, Pi, Pa, nullptr, tid);
    mm64(Ra, Pi, Ra, Ri, tid);
  }
  store64(Psup + ((size_t)sup * H_ + h) * 4096, Pa, tid);
  store64(Rsup + ((size_t)sup * H_ + h) * 4096, Ra, tid);
}

// level B with register prefetch
__global__ __launch_bounds__(256) void seq_levelB(const float* __restrict__ Psup,
    const float* __restrict__ Rsup, float* __restrict__ Msup) {
  __shared__ float Ms[64][65], Pi[64][65], Ri[64][65];
  const int h = blockIdx.x, tid = threadIdx.x;
  for (int i = tid; i < 4096; i += 256) Ms[i >> 6][i & 63] = 0.f;
  float pf[16], rf[16];
  {
    const float* ps = Psup + ((size_t)0 * H_ + h) * 4096;
    const float* rs = Rsup + ((size_t)0 * H_ + h) * 4096;
#pragma unroll
    for (int k = 0; k < 16; ++k) { int i = tid + k * 256; pf[k] = ps[i]; rf[k] = rs[i]; }
  }
  for (int s = 0; s < NSUP; ++s) {
#pragma unroll
    for (int k = 0; k < 16; ++k) {
      int i = tid + k * 256, r = i >> 6, cc = i & 63;
      Pi[r][cc] = pf[k];
      Ri[r][cc] = rf[k];
    }
    store64(Msup + ((size_t)s * H_ + h) * 4096, Ms, tid);  // same-thread mapping
    __syncthreads();
    if (s + 1 < NSUP) {
      const float* ps = Psup + ((size_t)(s + 1) * H_ + h) * 4096;
      const float* rs = Rsup + ((size_t)(s + 1) * H_ + h) * 4096;
#pragma unroll
      for (int k = 0; k < 16; ++k) { int i = tid + k * 256; pf[k] = ps[i]; rf[k] = rs[i]; }
    }
    mm64(Ms, Pi, Ms, Ri, tid);
  }
}

// level C with register prefetch; Mc overlays Rg (same-thread i=tid+k*256
// mapping for prefetch-read and Mc-write -> program-order safe)
template<typename PT>
__global__ __launch_bounds__(256) void seq_levelC(const PT* __restrict__ Pg,
    PT* __restrict__ Rg, const float* __restrict__ Msup) {
  __shared__ float Ms[64][65], Pi[64][65], Ri[64][65];
  const int sup = blockIdx.x, h = blockIdx.y, tid = threadIdx.x;
  load64(Ms, Msup + ((size_t)sup * H_ + h) * 4096, tid);
  float pf[16], rf[16];
  {
    const size_t slice = ((size_t)(sup * SUPW) * H_ + h) * 4096;
#pragma unroll
    for (int k = 0; k < 16; ++k) { int i = tid + k * 256; pf[k] = ldv(Pg[slice + i]); rf[k] = ldv(Rg[slice + i]); }
  }
  for (int s = 0; s < SUPW; ++s) {
    const size_t slice = ((size_t)(sup * SUPW + s) * H_ + h) * 4096;
#pragma unroll
    for (int k = 0; k < 16; ++k) {
      int i = tid + k * 256, r = i >> 6, cc = i & 63;
      Pi[r][cc] = ((r == cc) ? 1.f : 0.f) - pf[k];
      Ri[r][cc] = rf[k];
    }
    // Mc write over R slot (Ms stable: prev mm64 ended with barrier / load64 same-thread)
    for (int i = tid; i < 4096; i += 256) stv(&Rg[slice + i], Ms[i >> 6][i & 63]);
    __syncthreads();
    if (s + 1 < SUPW) {
      const size_t sl2 = ((size_t)(sup * SUPW + s + 1) * H_ + h) * 4096;
#pragma unroll
      for (int k = 0; k < 16; ++k) { int i = tid + k * 256; pf[k] = ldv(Pg[sl2 + i]); rf[k] = ldv(Rg[sl2 + i]); }
    }
    mm64(Ms, Pi, Ms, Ri, tid);
  }
}

// ---------------- phase 3: attn = E*M0^T + F (bf16 out) ----------------
template<typename PT>
__global__ __launch_bounds__(256) void phase3_kernel(
    const float* __restrict__ Eg, const u16* __restrict__ Fg,
    const PT* __restrict__ Mcg, u16* __restrict__ attn) {
  __shared__ float Es[64][65], Ms[64][65];
  const int c = blockIdx.x, h = blockIdx.y, tid = threadIdx.x;
  for (int i = tid; i < 4096; i += 256) {
    int r = i >> 6, d = i & 63, t = r >> 2, b = r & 3;
    size_t g = ((size_t)b * S_ + (size_t)c * CHUNK + t) * D_ + h * 64 + d;
    Es[r][d] = Eg[g];
    Ms[i >> 6][i & 63] = ldv(Mcg[((size_t)c * H_ + h) * 4096 + i]);
  }
  __syncthreads();
  const int r0 = (tid >> 4) * 4, d0 = (tid & 15) * 4;
  float a[4][4] = {};
  for (int k = 0; k < 64; ++k) {
    float ev[4], mv[4];
#pragma unroll
    for (int i = 0; i < 4; ++i) ev[i] = Es[r0 + i][k];
#pragma unroll
    for (int j = 0; j < 4; ++j) mv[j] = Ms[d0 + j][k];
#pragma unroll
    for (int i = 0; i < 4; ++i)
#pragma unroll
      for (int j = 0; j < 4; ++j) a[i][j] += ev[i] * mv[j];
  }
#pragma unroll
  for (int i = 0; i < 4; ++i)
#pragma unroll
    for (int j = 0; j < 4; ++j) {
      int r = r0 + i, d = d0 + j, t = r >> 2, b = r & 3;
      size_t g = ((size_t)b * S_ + (size_t)c * CHUNK + t) * D_ + h * 64 + d;
      attn[g] = f2bf(a[i][j] + bf2f(Fg[g]));
    }
}

// ---------------- launch ----------------
extern "C" void kernel_launch(void* const* d_in, const int* in_sizes, int n_in,
                              void* d_out, int out_size, void* d_ws, size_t ws_size,
                              hipStream_t stream) {
  (void)in_sizes; (void)n_in; (void)out_size;
  const float* x  = (const float*)d_in[0];
  const float* Wq = (const float*)d_in[1];
  const float* Wk = (const float*)d_in[2];
  const float* Wv = (const float*)d_in[3];
  const float* Wo = (const float*)d_in[4];
  float* out = (float*)d_out;

  char* w = (char*)d_ws;
  const size_t MB = 1024 * 1024;
  u16* Kbf = (u16*)w;
  u16* Vbf = (u16*)(w + 32 * MB);
  u16* xh  = (u16*)(w + 64 * MB);
  u16* xl  = (u16*)(w + 96 * MB);
  const bool big = ws_size >= 192 * MB;
  void* Preg = (void*)(w + 64 * MB);
  void* Rreg = big ? (void*)(w + 128 * MB) : (void*)(w + 96 * MB);
  float* Psup = (float*)w;
  float* Rsup = (float*)(w + 4 * MB);
  float* Msup = (float*)(w + 8 * MB);
  u16* attn = (u16*)Preg;
  u16* Wsp = (u16*)(w + 128 * MB);  // hi/lo u16 pairs at +0/+1M, +2/+3M, +4/+5M

  const size_t DSZ = (size_t)B_ * S_ * D_;  // 16777216
  split4_kernel<<<2048, 256, 0, stream>>>(x, xh, xl, (int)(DSZ / 4));

  dim3 gg(128, 8);
  if (big) {
    split4_kernel<<<512, 256, 0, stream>>>(Wq, Wsp + 0 * 1048576u, Wsp + 1 * 1048576u, 262144);
    split4_kernel<<<512, 256, 0, stream>>>(Wk, Wsp + 2 * 1048576u, Wsp + 3 * 1048576u, 262144);
    split4_kernel<<<512, 256, 0, stream>>>(Wv, Wsp + 4 * 1048576u, Wsp + 5 * 1048576u, 262144);
    gemm_axw<2, 1, 1, float><<<gg, 256, 0, stream>>>(xh, xl, Wsp + 0 * 1048576u, nullptr, out, 16384, 1024, 1024);
    gemm_axw<2, 1, 1, u16><<<gg, 256, 0, stream>>>(xh, xl, Wsp + 2 * 1048576u, nullptr, Kbf, 16384, 1024, 1024);
    gemm_axw<2, 1, 1, u16><<<gg, 256, 0, stream>>>(xh, xl, Wsp + 4 * 1048576u, nullptr, Vbf, 16384, 1024, 1024);
    float* P = (float*)Preg; float* R = (float*)Rreg;
    phase1_kernel<float><<<dim3(NCHUNK, H_), 256, 0, stream>>>(out, Kbf, Vbf, P, R);
    seq_levelA<float><<<dim3(NSUP, H_), 256, 0, stream>>>(P, R, Psup, Rsup);
    seq_levelB<<<dim3(H_), 256, 0, stream>>>(Psup, Rsup, Msup);
    seq_levelC<float><<<dim3(NSUP, H_), 256, 0, stream>>>(P, R, Msup);
    phase3_kernel<float><<<dim3(NCHUNK, H_), 256, 0, stream>>>(out, Vbf, R, attn);
    split4_kernel<<<512, 256, 0, stream>>>(Wo, Wsp + 0 * 1048576u, Wsp + 1 * 1048576u, 262144);
    gemm_axw<1, 2, 1, float><<<gg, 256, 0, stream>>>(attn, nullptr, Wsp + 0 * 1048576u, Wsp + 1 * 1048576u, out, 16384, 1024, 1024);
  } else {
    gemm_axw<2, 1, 0, float><<<gg, 256, 0, stream>>>(xh, xl, Wq, nullptr, out, 16384, 1024, 1024);
    gemm_axw<2, 1, 0, u16><<<gg, 256, 0, stream>>>(xh, xl, Wk, nullptr, Kbf, 16384, 1024, 1024);
    gemm_axw<2, 1, 0, u16><<<gg, 256, 0, stream>>>(xh, xl, Wv, nullptr, Vbf, 16384, 1024, 1024);
    u16* P = (u16*)Preg; u16* R = (u16*)Rreg;
    phase1_kernel<u16><<<dim3(NCHUNK, H_), 256, 0, stream>>>(out, Kbf, Vbf, P, R);
    seq_levelA<u16><<<dim3(NSUP, H_), 256, 0, stream>>>(P, R, Psup, Rsup);
    seq_levelB<<<dim3(H_), 256, 0, stream>>>(Psup, Rsup, Msup);
    seq_levelC<u16><<<dim3(NSUP, H_), 256, 0, stream>>>(P, R, Msup);
    phase3_kernel<u16><<<dim3(NCHUNK, H_), 256, 0, stream>>>(out, Vbf, R, attn);
    gemm_axw<1, 2, 0, float><<<gg, 256, 0, stream>>>(attn, nullptr, Wo, nullptr, out, 16384, 1024, 1024);
  }
}

// Round 9
// 761.490 us; speedup vs baseline: 1.8185x; 1.1422x over previous
//
#include <hip/hip_runtime.h>

// L2RegressionAttention — chunked WY-transform.
// r9: (1) GEMMs use the verified 2-phase double-buffered global_load_lds
// template (explicit vmcnt(0) drain before each barrier); (2) seq_levelA/C
// matmuls MFMA-ized (bf16x3, fp32 state in LDS, transposed-staged Pi).
// phase1 / levelB / phase3 unchanged from passing r8.
// B=4, S=4096, D=1024, H=16, hd=64, eta = 0.1/4 = 0.025.

typedef unsigned short u16;
typedef __attribute__((ext_vector_type(8))) short short8;
typedef __attribute__((ext_vector_type(4))) float f32x4;

#define B_ 4
#define S_ 4096
#define D_ 1024
#define H_ 16
#define CHUNK 16
#define NCHUNK 256
#define SUPW 16
#define NSUP 16
#define ETA 0.025f

__device__ __forceinline__ u16 f2bf(float f) {
  unsigned u = __builtin_bit_cast(unsigned, f);
  u += 0x7fffu + ((u >> 16) & 1u);
  return (u16)(u >> 16);
}
__device__ __forceinline__ float bf2f(u16 s) {
  unsigned u = ((unsigned)s) << 16;
  return __builtin_bit_cast(float, u);
}
__device__ __forceinline__ float ldv(float v) { return v; }
__device__ __forceinline__ float ldv(u16 v) { return bf2f(v); }
__device__ __forceinline__ void stv(float* p, float v) { *p = v; }
__device__ __forceinline__ void stv(u16* p, float v) { *p = f2bf(v); }

#define MFMA __builtin_amdgcn_mfma_f32_16x16x32_bf16

// async global -> LDS, 16B/lane; dst base wave-uniform, +lane*16 implicit
__device__ __forceinline__ void gload16(const void* g, void* l) {
  __builtin_amdgcn_global_load_lds(
      (__attribute__((address_space(1))) void*)g,
      (__attribute__((address_space(3))) void*)l, 16, 0, 0);
}

// ---------------- fp32 -> (hi, lo) bf16 split, float4-vectorized ----------------
__global__ void split4_kernel(const float* __restrict__ x, u16* __restrict__ hi,
                              u16* __restrict__ lo, int n4) {
  int i = blockIdx.x * blockDim.x + threadIdx.x;
  int stride = gridDim.x * blockDim.x;
  for (; i < n4; i += stride) {
    float4 v = ((const float4*)x)[i];
    ushort4 h, l;
    h.x = f2bf(v.x); l.x = f2bf(v.x - bf2f(h.x));
    h.y = f2bf(v.y); l.y = f2bf(v.y - bf2f(h.y));
    h.z = f2bf(v.z); l.z = f2bf(v.z - bf2f(h.z));
    h.w = f2bf(v.w); l.w = f2bf(v.w - bf2f(h.w));
    ((ushort4*)hi)[i] = h;
    ((ushort4*)lo)[i] = l;
  }
}

// ---------------- GEMM: C[M][N] = A * B^T (2-phase dbuf gload_lds) ----------------
// A: pre-split bf16 (Ah, +Al if AP==2). B: BPRE=1 pre-split bf16 via gload_lds
// (+Bl if BP==2); BPRE=0 fp32 split on the fly (reg->LDS). 128x128, BK=32.
template<int AP, int BP, int BPRE, typename OutT>
__global__ __launch_bounds__(256) void gemm_axw(
    const u16* __restrict__ Ahg, const u16* __restrict__ Alg,
    const void* __restrict__ Bhp, const u16* __restrict__ Blg,
    OutT* __restrict__ C, int M, int N, int K) {
  __shared__ __align__(16) u16 Ahs[2][128][32];
  __shared__ __align__(16) u16 Als[AP == 2 ? 2 : 1][AP == 2 ? 128 : 1][32];
  __shared__ __align__(16) u16 Bhs[2][128][32];
  __shared__ __align__(16) u16 Bls[BP == 2 ? 2 : 1][BP == 2 ? 128 : 1][32];
  const int tid = threadIdx.x, w = tid >> 6, lane = tid & 63;
  const int nwg = gridDim.x * gridDim.y;
  const int orig = blockIdx.y * gridDim.x + blockIdx.x;
  const int id = ((nwg & 7) == 0) ? ((orig & 7) * (nwg >> 3) + (orig >> 3)) : orig;
  const int bm = (id % gridDim.x) * 128, bn = (id / gridDim.x) * 128;
  const int wm = (w >> 1) * 64, wn = (w & 1) * 64;
  const int fr = lane & 15, kb = lane >> 4;
  const int lrow = lane >> 2, lcol = (lane & 3) * 8;

  auto stage = [&](int buf, int k0) {
    {
      const size_t rb = (size_t)(bm + w * 32 + lrow) * K + k0 + lcol;
      gload16(Ahg + rb, &Ahs[buf][w * 32][0]);
      gload16(Ahg + rb + (size_t)16 * K, &Ahs[buf][w * 32 + 16][0]);
      if constexpr (AP == 2) {
        gload16(Alg + rb, &Als[buf][w * 32][0]);
        gload16(Alg + rb + (size_t)16 * K, &Als[buf][w * 32 + 16][0]);
      }
    }
    if constexpr (BPRE) {
      const u16* Bhg = (const u16*)Bhp;
      const size_t rb = (size_t)(bn + w * 32 + lrow) * K + k0 + lcol;
      gload16(Bhg + rb, &Bhs[buf][w * 32][0]);
      gload16(Bhg + rb + (size_t)16 * K, &Bhs[buf][w * 32 + 16][0]);
      if constexpr (BP == 2) {
        gload16(Blg + rb, &Bls[buf][w * 32][0]);
        gload16(Blg + rb + (size_t)16 * K, &Bls[buf][w * 32 + 16][0]);
      }
    } else {
      const float* Bm = (const float*)Bhp;
#pragma unroll
      for (int i2 = 0; i2 < 4; ++i2) {
        int e = tid + i2 * 256, r = e >> 3, sg = (e & 7) * 4;
        float4 v = *(const float4*)(&Bm[(size_t)(bn + r) * K + k0 + sg]);
        ushort4 hq;
        hq.x = f2bf(v.x); hq.y = f2bf(v.y); hq.z = f2bf(v.z); hq.w = f2bf(v.w);
        *(ushort4*)(&Bhs[buf][r][sg]) = hq;
        if constexpr (BP == 2) {
          ushort4 lq;
          lq.x = f2bf(v.x - bf2f(hq.x));
          lq.y = f2bf(v.y - bf2f(hq.y));
          lq.z = f2bf(v.z - bf2f(hq.z));
          lq.w = f2bf(v.w - bf2f(hq.w));
          *(ushort4*)(&Bls[buf][r][sg]) = lq;
        }
      }
    }
  };

  f32x4 acc[4][4];
#pragma unroll
  for (int i = 0; i < 4; ++i)
#pragma unroll
    for (int j = 0; j < 4; ++j) acc[i][j] = (f32x4){0.f, 0.f, 0.f, 0.f};

  stage(0, 0);
  asm volatile("s_waitcnt vmcnt(0)" ::: "memory");
  __syncthreads();
  const int nt = K >> 5;
  int cur = 0;
  for (int t = 0; t < nt; ++t) {
    if (t + 1 < nt) stage(cur ^ 1, (t + 1) * 32);  // issue-early into other buf
    short8 ah[4], al[4], bh[4], bl[4];
#pragma unroll
    for (int mi = 0; mi < 4; ++mi) {
      ah[mi] = *(const short8*)(&Ahs[cur][wm + mi * 16 + fr][kb * 8]);
      if constexpr (AP == 2) al[mi] = *(const short8*)(&Als[cur][wm + mi * 16 + fr][kb * 8]);
    }
#pragma unroll
    for (int ni = 0; ni < 4; ++ni) {
      bh[ni] = *(const short8*)(&Bhs[cur][wn + ni * 16 + fr][kb * 8]);
      if constexpr (BP == 2) bl[ni] = *(const short8*)(&Bls[cur][wn + ni * 16 + fr][kb * 8]);
    }
#pragma unroll
    for (int mi = 0; mi < 4; ++mi)
#pragma unroll
      for (int ni = 0; ni < 4; ++ni) {
        acc[mi][ni] = MFMA(ah[mi], bh[ni], acc[mi][ni], 0, 0, 0);
        if constexpr (BP == 2)
          acc[mi][ni] = MFMA(ah[mi], bl[ni], acc[mi][ni], 0, 0, 0);
        if constexpr (AP == 2)
          acc[mi][ni] = MFMA(al[mi], bh[ni], acc[mi][ni], 0, 0, 0);
      }
    asm volatile("s_waitcnt vmcnt(0)" ::: "memory");  // next buf staged
    __syncthreads();                                  // + all frag reads drained
    cur ^= 1;
  }
  const int fc = lane & 15, fr4 = (lane >> 4) * 4;
#pragma unroll
  for (int mi = 0; mi < 4; ++mi)
#pragma unroll
    for (int ni = 0; ni < 4; ++ni) {
      int gm = bm + wm + mi * 16 + fr4;
      int gn = bn + wn + ni * 16 + fc;
#pragma unroll
      for (int rg = 0; rg < 4; ++rg)
        stv(&C[(size_t)(gm + rg) * N + gn], acc[mi][ni][rg]);
    }
}

// ---------------- phase 1 (MFMA) — unchanged r7/r8 ----------------
template<typename PT>
__global__ __launch_bounds__(256) void phase1_kernel(
    float* __restrict__ Qg, const u16* __restrict__ Kg, u16* __restrict__ Vg,
    PT* __restrict__ Pg, PT* __restrict__ Rg) {
  __shared__ __align__(16) u16 Ks[64][72];
  __shared__ __align__(16) u16 KsT[64][72];
  __shared__ __align__(16) u16 Gh[64][72];
  __shared__ __align__(16) u16 Gl[64][72];
  __shared__ __align__(16) float Ut[64][68];
  __shared__ __align__(16) float Wt[64][68];

  const int c = blockIdx.x, h = blockIdx.y, tid = threadIdx.x;
  const int w = tid >> 6, lane = tid & 63;
  const int fr = lane & 15, kq = lane >> 4, orow = kq * 4;
  const int xr = 16 * w + fr;

  auto gidx = [&](int r, int d) -> size_t {
    return ((size_t)(r & 3) * S_ + (size_t)c * CHUNK + (r >> 2)) * D_ + h * 64 + d;
  };
  auto ldb = [&](const u16 (*M)[72], int row, int s) -> short8 {
    return *(const short8*)(&M[row][32 * s + 8 * kq]);
  };
  auto ldm = [&](const u16 (*M)[72], int row, int s, bool up) -> short8 {
    short8 r = *(const short8*)(&M[row][32 * s + 8 * kq]);
    int rb = row >> 2, k0 = 32 * s + 8 * kq;
#pragma unroll
    for (int j = 0; j < 8; ++j) {
      int kb2 = (k0 + j) >> 2;
      bool keep = up ? (kb2 > rb) : (rb > kb2);
      if (!keep) r[j] = 0;
    }
    return r;
  };
  auto ldf = [&](const float (*M)[68], int row, int s, short8& hh, short8& ll) {
    const float* p = &M[row][32 * s + 8 * kq];
#pragma unroll
    for (int j = 0; j < 8; ++j) {
      float v = p[j];
      u16 hb = f2bf(v);
      hh[j] = (short)hb;
      ll[j] = (short)f2bf(v - bf2f(hb));
    }
  };
  auto ldfh = [&](const float (*M)[68], int row, int s) -> short8 {
    const float* p = &M[row][32 * s + 8 * kq];
    short8 hh;
#pragma unroll
    for (int j = 0; j < 8; ++j) hh[j] = (short)f2bf(p[j]);
    return hh;
  };

  for (int i = tid; i < 4096; i += 256) {
    int r = i >> 6, d = i & 63;
    size_t g = gidx(r, d);
    u16 kraw = Kg[g];
    Ks[r][d] = kraw;
    KsT[d][r] = kraw;
    Wt[d][r] = ETA * bf2f(kraw);
    Ut[d][r] = ETA * bf2f(Vg[g]);
  }
  __syncthreads();  // (1)

  {
    f32x4 acc[4];
#pragma unroll
    for (int ni = 0; ni < 4; ++ni) acc[ni] = (f32x4){0.f, 0.f, 0.f, 0.f};
    short8 xf[2];
#pragma unroll
    for (int s = 0; s < 2; ++s) xf[s] = ldb(Ks, xr, s);
#pragma unroll
    for (int ni = 0; ni < 4; ++ni)
#pragma unroll
      for (int s = 0; s < 2; ++s)
        acc[ni] = MFMA(xf[s], ldb(Ks, 16 * ni + fr, s), acc[ni], 0, 0, 0);
#pragma unroll
    for (int ni = 0; ni < 4; ++ni)
#pragma unroll
      for (int rg = 0; rg < 4; ++rg) {
        float v = -ETA * acc[ni][rg];
        u16 hb = f2bf(v);
        int rr = 16 * w + orow + rg, cc = 16 * ni + fr;
        Gh[rr][cc] = hb;
        Gl[rr][cc] = f2bf(v - bf2f(hb));
      }
  }

  float sreg[4][4];
  {
    short8 xh[2], xl[2];
#pragma unroll
    for (int s = 0; s < 2; ++s) {
      const float* qp = &Qg[gidx(xr, 32 * s + 8 * kq)];
#pragma unroll
      for (int j = 0; j < 8; ++j) {
        float v = qp[j];
        u16 hb = f2bf(v);
        xh[s][j] = (short)hb;
        xl[s][j] = (short)f2bf(v - bf2f(hb));
      }
    }
    f32x4 acc[4];
#pragma unroll
    for (int ni = 0; ni < 4; ++ni) acc[ni] = (f32x4){0.f, 0.f, 0.f, 0.f};
#pragma unroll
    for (int ni = 0; ni < 4; ++ni)
#pragma unroll
      for (int s = 0; s < 2; ++s) {
        short8 yf = ldb(Ks, 16 * ni + fr, s);
        acc[ni] = MFMA(xh[s], yf, acc[ni], 0, 0, 0);
        acc[ni] = MFMA(xl[s], yf, acc[ni], 0, 0, 0);
      }
#pragma unroll
    for (int ni = 0; ni < 4; ++ni)
#pragma unroll
      for (int rg = 0; rg < 4; ++rg) {
        int r = 16 * w + orow + rg, cc = 16 * ni + fr;
        sreg[ni][rg] = ((r >> 2) >= (cc >> 2)) ? acc[ni][rg] : 0.f;
      }
  }
  __syncthreads();  // (2)

  auto app1 = [&](float (*St)[68]) {
    short8 xh[2], xl[2];
#pragma unroll
    for (int s = 0; s < 2; ++s) ldf(St, xr, s, xh[s], xl[s]);
    f32x4 acc[4];
#pragma unroll
    for (int ni = 0; ni < 4; ++ni) acc[ni] = (f32x4){0.f, 0.f, 0.f, 0.f};
#pragma unroll
    for (int ni = 0; ni < 4; ++ni)
#pragma unroll
      for (int s = 0; s < 2; ++s) {
        short8 yh = ldm(Gh, 16 * ni + fr, s, false);
        short8 yl = ldm(Gl, 16 * ni + fr, s, false);
        acc[ni] = MFMA(xh[s], yh, acc[ni], 0, 0, 0);
        acc[ni] = MFMA(xh[s], yl, acc[ni], 0, 0, 0);
        acc[ni] = MFMA(xl[s], yh, acc[ni], 0, 0, 0);
      }
#pragma unroll
    for (int ni = 0; ni < 4; ++ni)
#pragma unroll
      for (int rg = 0; rg < 4; ++rg)
        St[16 * w + orow + rg][16 * ni + fr] += acc[ni][rg];
  };
  auto appS = [&](float (*St)[68], const u16 (*Np)[72]) {
    short8 xh[2];
#pragma unroll
    for (int s = 0; s < 2; ++s) xh[s] = ldfh(St, xr, s);
    f32x4 acc[4];
#pragma unroll
    for (int ni = 0; ni < 4; ++ni) acc[ni] = (f32x4){0.f, 0.f, 0.f, 0.f};
#pragma unroll
    for (int ni = 0; ni < 4; ++ni)
#pragma unroll
      for (int s = 0; s < 2; ++s)
        acc[ni] = MFMA(xh[s], ldb(Np, 16 * ni + fr, s), acc[ni], 0, 0, 0);
#pragma unroll
    for (int ni = 0; ni < 4; ++ni)
#pragma unroll
      for (int rg = 0; rg < 4; ++rg)
        St[16 * w + orow + rg][16 * ni + fr] += acc[ni][rg];
  };

  app1(Ut);
  app1(Wt);
  {
    f32x4 sq[4];
#pragma unroll
    for (int ni = 0; ni < 4; ++ni) sq[ni] = (f32x4){0.f, 0.f, 0.f, 0.f};
    short8 xh[2], xl[2];
#pragma unroll
    for (int s = 0; s < 2; ++s) {
      xh[s] = ldm(Gh, xr, s, false);
      xl[s] = ldm(Gl, xr, s, false);
    }
#pragma unroll
    for (int ni = 0; ni < 4; ++ni)
#pragma unroll
      for (int s = 0; s < 2; ++s) {
        short8 yh = ldm(Gh, 16 * ni + fr, s, true);
        short8 yl = ldm(Gl, 16 * ni + fr, s, true);
        sq[ni] = MFMA(xh[s], yh, sq[ni], 0, 0, 0);
        sq[ni] = MFMA(xh[s], yl, sq[ni], 0, 0, 0);
        sq[ni] = MFMA(xl[s], yh, sq[ni], 0, 0, 0);
      }
    __syncthreads();  // (3)
#pragma unroll
    for (int ni = 0; ni < 4; ++ni)
#pragma unroll
      for (int rg = 0; rg < 4; ++rg) {
        u16 b = f2bf(sq[ni][rg]);
        int rr = 16 * w + orow + rg, cc = 16 * ni + fr;
        Ks[rr][cc] = b;
        Gh[cc][rr] = b;
      }
  }
  __syncthreads();  // (4)

  appS(Ut, Ks);
  appS(Wt, Ks);
  {
    f32x4 sq[4];
#pragma unroll
    for (int ni = 0; ni < 4; ++ni) sq[ni] = (f32x4){0.f, 0.f, 0.f, 0.f};
    short8 xf[2];
#pragma unroll
    for (int s = 0; s < 2; ++s) xf[s] = ldb(Ks, xr, s);
#pragma unroll
    for (int ni = 0; ni < 4; ++ni)
#pragma unroll
      for (int s = 0; s < 2; ++s)
        sq[ni] = MFMA(xf[s], ldb(Gh, 16 * ni + fr, s), sq[ni], 0, 0, 0);
    __syncthreads();  // (5)
#pragma unroll
    for (int ni = 0; ni < 4; ++ni)
#pragma unroll
      for (int rg = 0; rg < 4; ++rg) {
        u16 b = f2bf(sq[ni][rg]);
        int rr = 16 * w + orow + rg, cc = 16 * ni + fr;
        Gl[rr][cc] = b;
        Ks[cc][rr] = b;
      }
  }
  __syncthreads();  // (6)

  appS(Ut, Gl);
  appS(Wt, Gl);
  {
    f32x4 sq[4];
#pragma unroll
    for (int ni = 0; ni < 4; ++ni) sq[ni] = (f32x4){0.f, 0.f, 0.f, 0.f};
    short8 xf[2];
#pragma unroll
    for (int s = 0; s < 2; ++s) xf[s] = ldb(Gl, xr, s);
#pragma unroll
    for (int ni = 0; ni < 4; ++ni)
#pragma unroll
      for (int s = 0; s < 2; ++s)
        sq[ni] = MFMA(xf[s], ldb(Ks, 16 * ni + fr, s), sq[ni], 0, 0, 0);
#pragma unroll
    for (int ni = 0; ni < 4; ++ni)
#pragma unroll
      for (int rg = 0; rg < 4; ++rg)
        Gh[16 * w + orow + rg][16 * ni + fr] = f2bf(sq[ni][rg]);
  }
  __syncthreads();  // (7)

  appS(Ut, Gh);
  appS(Wt, Gh);
  __syncthreads();  // (7b)

  const size_t base = ((size_t)c * H_ + h) * 4096;
  {
    short8 xh[2], xl[2];
#pragma unroll
    for (int s = 0; s < 2; ++s) ldf(Wt, xr, s, xh[s], xl[s]);
    f32x4 acc[4];
#pragma unroll
    for (int ni = 0; ni < 4; ++ni) acc[ni] = (f32x4){0.f, 0.f, 0.f, 0.f};
#pragma unroll
    for (int ni = 0; ni < 4; ++ni)
#pragma unroll
      for (int s = 0; s < 2; ++s) {
        short8 yf = ldb(KsT, 16 * ni + fr, s);
        acc[ni] = MFMA(xh[s], yf, acc[ni], 0, 0, 0);
        acc[ni] = MFMA(xl[s], yf, acc[ni], 0, 0, 0);
      }
#pragma unroll
    for (int ni = 0; ni < 4; ++ni)
#pragma unroll
      for (int rg = 0; rg < 4; ++rg)
        stv(&Pg[base + (16 * w + orow + rg) * 64 + 16 * ni + fr], acc[ni][rg]);
  }
  {
    short8 xh[2], xl[2];
#pragma unroll
    for (int s = 0; s < 2; ++s) ldf(Ut, xr, s, xh[s], xl[s]);
    f32x4 acc[4];
#pragma unroll
    for (int ni = 0; ni < 4; ++ni) acc[ni] = (f32x4){0.f, 0.f, 0.f, 0.f};
#pragma unroll
    for (int ni = 0; ni < 4; ++ni)
#pragma unroll
      for (int s = 0; s < 2; ++s) {
        short8 yf = ldb(KsT, 16 * ni + fr, s);
        acc[ni] = MFMA(xh[s], yf, acc[ni], 0, 0, 0);
        acc[ni] = MFMA(xl[s], yf, acc[ni], 0, 0, 0);
      }
#pragma unroll
    for (int ni = 0; ni < 4; ++ni)
#pragma unroll
      for (int rg = 0; rg < 4; ++rg)
        stv(&Rg[base + (16 * w + orow + rg) * 64 + 16 * ni + fr], acc[ni][rg]);
  }
  {
    const int r = tid >> 2, d0 = (tid & 3) * 16;
    short8 v0, v1;
#pragma unroll
    for (int j = 0; j < 8; ++j) v0[j] = (short)f2bf(Wt[r][d0 + j]);
#pragma unroll
    for (int j = 0; j < 8; ++j) v1[j] = (short)f2bf(Wt[r][d0 + 8 + j]);
    *(short8*)(&Gh[r][d0]) = v0;
    *(short8*)(&Gh[r][d0 + 8]) = v1;
#pragma unroll
    for (int j = 0; j < 8; ++j) v0[j] = (short)f2bf(Ut[r][d0 + j]);
#pragma unroll
    for (int j = 0; j < 8; ++j) v1[j] = (short)f2bf(Ut[r][d0 + 8 + j]);
    *(short8*)(&Gl[r][d0]) = v0;
    *(short8*)(&Gl[r][d0 + 8]) = v1;
  }
#pragma unroll
  for (int ni = 0; ni < 4; ++ni)
#pragma unroll
    for (int rg = 0; rg < 4; ++rg)
      Ks[16 * w + orow + rg][16 * ni + fr] = f2bf(sreg[ni][rg]);
  __syncthreads();  // (8)

  {
    short8 xs[2];
#pragma unroll
    for (int s = 0; s < 2; ++s) xs[s] = ldb(Ks, xr, s);
    f32x4 accE[4], accF[4];
#pragma unroll
    for (int ni = 0; ni < 4; ++ni) {
      accE[ni] = (f32x4){0.f, 0.f, 0.f, 0.f};
      accF[ni] = (f32x4){0.f, 0.f, 0.f, 0.f};
    }
#pragma unroll
    for (int ni = 0; ni < 4; ++ni)
#pragma unroll
      for (int s = 0; s < 2; ++s) {
        accE[ni] = MFMA(xs[s], ldb(Gh, 16 * ni + fr, s), accE[ni], 0, 0, 0);
        accF[ni] = MFMA(xs[s], ldb(Gl, 16 * ni + fr, s), accF[ni], 0, 0, 0);
      }
#pragma unroll
    for (int ni = 0; ni < 4; ++ni)
#pragma unroll
      for (int rg = 0; rg < 4; ++rg) {
        int r = 16 * w + orow + rg, d = 16 * ni + fr;
        size_t g = gidx(r, d);
        float qv = Qg[g];
        Qg[g] = qv - accE[ni][rg];
        Vg[g] = f2bf(accF[ni][rg]);
      }
  }
}

// ---------------- scalar 64x64 helpers (levelB only) ----------------
__device__ __forceinline__ void load64(float (*dst)[65], const float* src, int tid) {
  for (int i = tid; i < 4096; i += 256) dst[i >> 6][i & 63] = src[i];
}
__device__ __forceinline__ void store64(float* dst, const float (*src)[65], int tid) {
  for (int i = tid; i < 4096; i += 256) dst[i] = src[i >> 6][i & 63];
}
__device__ __forceinline__ void mm64(const float (*X)[65], const float (*Y)[65],
                                     float (*Dst)[65], const float (*Add)[65], int tid) {
  const int r0 = (tid >> 4) * 4, c0 = (tid & 15) * 4;
  float a[4][4] = {};
  for (int d = 0; d < 64; ++d) {
    float xv[4], yv[4];
#pragma unroll
    for (int i = 0; i < 4; ++i) xv[i] = X[r0 + i][d];
#pragma unroll
    for (int j = 0; j < 4; ++j) yv[j] = Y[d][c0 + j];
#pragma unroll
    for (int i = 0; i < 4; ++i)
#pragma unroll
      for (int j = 0; j < 4; ++j) a[i][j] += xv[i] * yv[j];
  }
  __syncthreads();
#pragma unroll
  for (int i = 0; i < 4; ++i)
#pragma unroll
    for (int j = 0; j < 4; ++j) {
      float v = a[i][j];
      if (Add) v += Add[r0 + i][c0 + j];
      Dst[r0 + i][c0 + j] = v;
    }
  __syncthreads();
}

// ---------------- level A (MFMA, bf16x3): compose within superchunk ----------------
template<typename PT>
__global__ __launch_bounds__(256) void seq_levelA(const PT* __restrict__ Pg,
    const PT* __restrict__ Rg, float* __restrict__ Psup, float* __restrict__ Rsup) {
  __shared__ __align__(16) float Pa[64][68], Ra[64][68], Ri[64][68];
  __shared__ __align__(16) u16 Pih[64][72], Pil[64][72];
  const int sup = blockIdx.x, h = blockIdx.y, tid = threadIdx.x;
  const int w = tid >> 6, lane = tid & 63;
  const int fr = lane & 15, kq = lane >> 4, orow = kq * 4;
  const int xr = 16 * w + fr;
  const int cbase = sup * SUPW;

  // in-place Dst = Dst*Pi (+Add): X = own-band rows hi/lo, Y = PiT h/l (b128)
  auto upd = [&](float (*St)[68], const float (*Add)[68]) {
    short8 xh[2], xl[2];
#pragma unroll
    for (int s2 = 0; s2 < 2; ++s2) {
      const float* p = &St[xr][32 * s2 + 8 * kq];
#pragma unroll
      for (int j = 0; j < 8; ++j) {
        float v = p[j];
        u16 hb = f2bf(v);
        xh[s2][j] = (short)hb;
        xl[s2][j] = (short)f2bf(v - bf2f(hb));
      }
    }
    f32x4 acc[4];
#pragma unroll
    for (int ni = 0; ni < 4; ++ni) acc[ni] = (f32x4){0.f, 0.f, 0.f, 0.f};
#pragma unroll
    for (int ni = 0; ni < 4; ++ni)
#pragma unroll
      for (int s2 = 0; s2 < 2; ++s2) {
        short8 yh = *(const short8*)(&Pih[16 * ni + fr][32 * s2 + 8 * kq]);
        short8 yl = *(const short8*)(&Pil[16 * ni + fr][32 * s2 + 8 * kq]);
        acc[ni] = MFMA(xh[s2], yh, acc[ni], 0, 0, 0);
        acc[ni] = MFMA(xh[s2], yl, acc[ni], 0, 0, 0);
        acc[ni] = MFMA(xl[s2], yh, acc[ni], 0, 0, 0);
      }
#pragma unroll
    for (int ni = 0; ni < 4; ++ni)
#pragma unroll
      for (int rg = 0; rg < 4; ++rg) {
        float v = acc[ni][rg];
        if (Add) v += Add[16 * w + orow + rg][16 * ni + fr];
        St[16 * w + orow + rg][16 * ni + fr] = v;
      }
  };

  {
    const PT* ps = Pg + ((size_t)cbase * H_ + h) * 4096;
    const PT* rs = Rg + ((size_t)cbase * H_ + h) * 4096;
    for (int i = tid; i < 4096; i += 256) {
      int r = i >> 6, cc = i & 63;
      Pa[r][cc] = ((r == cc) ? 1.f : 0.f) - ldv(ps[i]);
      Ra[r][cc] = ldv(rs[i]);
    }
  }
  float pf[16], rf[16];
  {
    const PT* ps = Pg + ((size_t)(cbase + 1) * H_ + h) * 4096;
    const PT* rs = Rg + ((size_t)(cbase + 1) * H_ + h) * 4096;
#pragma unroll
    for (int k = 0; k < 16; ++k) { int i = tid + k * 256; pf[k] = ldv(ps[i]); rf[k] = ldv(rs[i]); }
  }
  for (int s = 1; s < SUPW; ++s) {
    // stage PiT h/l (transposed) + Ri from prefetch regs
#pragma unroll
    for (int k = 0; k < 16; ++k) {
      int i = tid + k * 256, d = i >> 6, cc = i & 63;
      float v = ((d == cc) ? 1.f : 0.f) - pf[k];
      u16 hb = f2bf(v);
      Pih[cc][d] = hb;
      Pil[cc][d] = f2bf(v - bf2f(hb));
      Ri[d][cc] = rf[k];
    }
    __syncthreads();
    if (s + 1 < SUPW) {
      const PT* ps = Pg + ((size_t)(cbase + s + 1) * H_ + h) * 4096;
      const PT* rs = Rg + ((size_t)(cbase + s + 1) * H_ + h) * 4096;
#pragma unroll
      for (int k = 0; k < 16; ++k) { int i = tid + k * 256; pf[k] = ldv(ps[i]); rf[k] = ldv(rs[i]); }
    }
    upd(Pa, nullptr);   // Pa = Pa*Pi
    upd(Ra, Ri);        // Ra = Ra*Pi + Ri
    __syncthreads();    // all Y-reads done before next stage
  }
  for (int i = tid; i < 4096; i += 256) {
    Psup[((size_t)sup * H_ + h) * 4096 + i] = Pa[i >> 6][i & 63];
    Rsup[((size_t)sup * H_ + h) * 4096 + i] = Ra[i >> 6][i & 63];
  }
}

// ---------------- level B: exact fp32 scalar (16 blocks, unchanged) ----------------
__global__ __launch_bounds__(256) void seq_levelB(const float* __restrict__ Psup,
    const float* __restrict__ Rsup, float* __restrict__ Msup) {
  __shared__ float Ms[64][65], Pi[64][65], Ri[64][65];
  const int h = blockIdx.x, tid = threadIdx.x;
  for (int i = tid; i < 4096; i += 256) Ms[i >> 6][i & 63] = 0.f;
  float pf[16], rf[16];
  {
    const float* ps = Psup + ((size_t)0 * H_ + h) * 4096;
    const float* rs = Rsup + ((size_t)0 * H_ + h) * 4096;
#pragma unroll
    for (int k = 0; k < 16; ++k) { int i = tid + k * 256; pf[k] = ps[i]; rf[k] = rs[i]; }
  }
  for (int s = 0; s < NSUP; ++s) {
#pragma unroll
    for (int k = 0; k < 16; ++k) {
      int i = tid + k * 256, r = i >> 6, cc = i & 63;
      Pi[r][cc] = pf[k];
      Ri[r][cc] = rf[k];
    }
    store64(Msup + ((size_t)s * H_ + h) * 4096, Ms, tid);
    __syncthreads();
    if (s + 1 < NSUP) {
      const float* ps = Psup + ((size_t)(s + 1) * H_ + h) * 4096;
      const float* rs = Rsup + ((size_t)(s + 1) * H_ + h) * 4096;
#pragma unroll
      for (int k = 0; k < 16; ++k) { int i = tid + k * 256; pf[k] = ps[i]; rf[k] = rs[i]; }
    }
    mm64(Ms, Pi, Ms, Ri, tid);
  }
}

// ---------------- level C (MFMA, bf16x3): expand; Mc overlays Rg ----------------
template<typename PT>
__global__ __launch_bounds__(256) void seq_levelC(const PT* __restrict__ Pg,
    PT* __restrict__ Rg, const float* __restrict__ Msup) {
  __shared__ __align__(16) float Ms[64][68], Ri[64][68];
  __shared__ __align__(16) u16 Pih[64][72], Pil[64][72];
  const int sup = blockIdx.x, h = blockIdx.y, tid = threadIdx.x;
  const int w = tid >> 6, lane = tid & 63;
  const int fr = lane & 15, kq = lane >> 4, orow = kq * 4;
  const int xr = 16 * w + fr;

  auto upd = [&](float (*St)[68], const float (*Add)[68]) {
    short8 xh[2], xl[2];
#pragma unroll
    for (int s2 = 0; s2 < 2; ++s2) {
      const float* p = &St[xr][32 * s2 + 8 * kq];
#pragma unroll
      for (int j = 0; j < 8; ++j) {
        float v = p[j];
        u16 hb = f2bf(v);
        xh[s2][j] = (short)hb;
        xl[s2][j] = (short)f2bf(v - bf2f(hb));
      }
    }
    f32x4 acc[4];
#pragma unroll
    for (int ni = 0; ni < 4; ++ni) acc[ni] = (f32x4){0.f, 0.f, 0.f, 0.f};
#pragma unroll
    for (int ni = 0; ni < 4; ++ni)
#pragma unroll
      for (int s2 = 0; s2 < 2; ++s2) {
        short8 yh = *(const short8*)(&Pih[16 * ni + fr][32 * s2 + 8 * kq]);
        short8 yl = *(const short8*)(&Pil[16 * ni + fr][32 * s2 + 8 * kq]);
        acc[ni] = MFMA(xh[s2], yh, acc[ni], 0, 0, 0);
        acc[ni] = MFMA(xh[s2], yl, acc[ni], 0, 0, 0);
        acc[ni] = MFMA(xl[s2], yh, acc[ni], 0, 0, 0);
      }
#pragma unroll
    for (int ni = 0; ni < 4; ++ni)
#pragma unroll
      for (int rg = 0; rg < 4; ++rg) {
        float v = acc[ni][rg];
        if (Add) v += Add[16 * w + orow + rg][16 * ni + fr];
        St[16 * w + orow + rg][16 * ni + fr] = v;
      }
  };

  for (int i = tid; i < 4096; i += 256)
    Ms[i >> 6][i & 63] = Msup[((size_t)sup * H_ + h) * 4096 + i];
  float pf[16], rf[16];
  {
    const size_t slice = ((size_t)(sup * SUPW) * H_ + h) * 4096;
#pragma unroll
    for (int k = 0; k < 16; ++k) { int i = tid + k * 256; pf[k] = ldv(Pg[slice + i]); rf[k] = ldv(Rg[slice + i]); }
  }
  for (int s = 0; s < SUPW; ++s) {
    const size_t slice = ((size_t)(sup * SUPW + s) * H_ + h) * 4096;
#pragma unroll
    for (int k = 0; k < 16; ++k) {
      int i = tid + k * 256, d = i >> 6, cc = i & 63;
      float v = ((d == cc) ? 1.f : 0.f) - pf[k];
      u16 hb = f2bf(v);
      Pih[cc][d] = hb;
      Pil[cc][d] = f2bf(v - bf2f(hb));
      Ri[d][cc] = rf[k];
    }
    // Mc = M at chunk start, over R slot (Ri already in regs/LDS; same-thread map)
    for (int i = tid; i < 4096; i += 256) stv(&Rg[slice + i], Ms[i >> 6][i & 63]);
    __syncthreads();
    if (s + 1 < SUPW) {
      const size_t sl2 = ((size_t)(sup * SUPW + s + 1) * H_ + h) * 4096;
#pragma unroll
      for (int k = 0; k < 16; ++k) { int i = tid + k * 256; pf[k] = ldv(Pg[sl2 + i]); rf[k] = ldv(Rg[sl2 + i]); }
    }
    upd(Ms, Ri);        // Ms = Ms*Pi + Ri
    __syncthreads();
  }
}

// ---------------- phase 3: attn = E*M0^T + F (bf16 out) — unchanged ----------------
template<typename PT>
__global__ __launch_bounds__(256) void phase3_kernel(
    const float* __restrict__ Eg, const u16* __restrict__ Fg,
    const PT* __restrict__ Mcg, u16* __restrict__ attn) {
  __shared__ float Es[64][65], Ms[64][65];
  const int c = blockIdx.x, h = blockIdx.y, tid = threadIdx.x;
  for (int i = tid; i < 4096; i += 256) {
    int r = i >> 6, d = i & 63, t = r >> 2, b = r & 3;
    size_t g = ((size_t)b * S_ + (size_t)c * CHUNK + t) * D_ + h * 64 + d;
    Es[r][d] = Eg[g];
    Ms[i >> 6][i & 63] = ldv(Mcg[((size_t)c * H_ + h) * 4096 + i]);
  }
  __syncthreads();
  const int r0 = (tid >> 4) * 4, d0 = (tid & 15) * 4;
  float a[4][4] = {};
  for (int k = 0; k < 64; ++k) {
    float ev[4], mv[4];
#pragma unroll
    for (int i = 0; i < 4; ++i) ev[i] = Es[r0 + i][k];
#pragma unroll
    for (int j = 0; j < 4; ++j) mv[j] = Ms[d0 + j][k];
#pragma unroll
    for (int i = 0; i < 4; ++i)
#pragma unroll
      for (int j = 0; j < 4; ++j) a[i][j] += ev[i] * mv[j];
  }
#pragma unroll
  for (int i = 0; i < 4; ++i)
#pragma unroll
    for (int j = 0; j < 4; ++j) {
      int r = r0 + i, d = d0 + j, t = r >> 2, b = r & 3;
      size_t g = ((size_t)b * S_ + (size_t)c * CHUNK + t) * D_ + h * 64 + d;
      attn[g] = f2bf(a[i][j] + bf2f(Fg[g]));
    }
}

// ---------------- launch ----------------
extern "C" void kernel_launch(void* const* d_in, const int* in_sizes, int n_in,
                              void* d_out, int out_size, void* d_ws, size_t ws_size,
                              hipStream_t stream) {
  (void)in_sizes; (void)n_in; (void)out_size;
  const float* x  = (const float*)d_in[0];
  const float* Wq = (const float*)d_in[1];
  const float* Wk = (const float*)d_in[2];
  const float* Wv = (const float*)d_in[3];
  const float* Wo = (const float*)d_in[4];
  float* out = (float*)d_out;

  char* w = (char*)d_ws;
  const size_t MB = 1024 * 1024;
  u16* Kbf = (u16*)w;
  u16* Vbf = (u16*)(w + 32 * MB);
  u16* xh  = (u16*)(w + 64 * MB);
  u16* xl  = (u16*)(w + 96 * MB);
  const bool big = ws_size >= 192 * MB;
  void* Preg = (void*)(w + 64 * MB);
  void* Rreg = big ? (void*)(w + 128 * MB) : (void*)(w + 96 * MB);
  float* Psup = (float*)w;
  float* Rsup = (float*)(w + 4 * MB);
  float* Msup = (float*)(w + 8 * MB);
  u16* attn = (u16*)Preg;
  u16* Wsp = (u16*)(w + 128 * MB);  // hi/lo u16 pairs at +0/+1M, +2/+3M, +4/+5M

  const size_t DSZ = (size_t)B_ * S_ * D_;  // 16777216
  split4_kernel<<<2048, 256, 0, stream>>>(x, xh, xl, (int)(DSZ / 4));

  dim3 gg(128, 8);
  if (big) {
    split4_kernel<<<512, 256, 0, stream>>>(Wq, Wsp + 0 * 1048576u, Wsp + 1 * 1048576u, 262144);
    split4_kernel<<<512, 256, 0, stream>>>(Wk, Wsp + 2 * 1048576u, Wsp + 3 * 1048576u, 262144);
    split4_kernel<<<512, 256, 0, stream>>>(Wv, Wsp + 4 * 1048576u, Wsp + 5 * 1048576u, 262144);
    gemm_axw<2, 1, 1, float><<<gg, 256, 0, stream>>>(xh, xl, Wsp + 0 * 1048576u, nullptr, out, 16384, 1024, 1024);
    gemm_axw<2, 1, 1, u16><<<gg, 256, 0, stream>>>(xh, xl, Wsp + 2 * 1048576u, nullptr, Kbf, 16384, 1024, 1024);
    gemm_axw<2, 1, 1, u16><<<gg, 256, 0, stream>>>(xh, xl, Wsp + 4 * 1048576u, nullptr, Vbf, 16384, 1024, 1024);
    float* P = (float*)Preg; float* R = (float*)Rreg;
    phase1_kernel<float><<<dim3(NCHUNK, H_), 256, 0, stream>>>(out, Kbf, Vbf, P, R);
    seq_levelA<float><<<dim3(NSUP, H_), 256, 0, stream>>>(P, R, Psup, Rsup);
    seq_levelB<<<dim3(H_), 256, 0, stream>>>(Psup, Rsup, Msup);
    seq_levelC<float><<<dim3(NSUP, H_), 256, 0, stream>>>(P, R, Msup);
    phase3_kernel<float><<<dim3(NCHUNK, H_), 256, 0, stream>>>(out, Vbf, R, attn);
    split4_kernel<<<512, 256, 0, stream>>>(Wo, Wsp + 0 * 1048576u, Wsp + 1 * 1048576u, 262144);
    gemm_axw<1, 2, 1, float><<<gg, 256, 0, stream>>>(attn, nullptr, Wsp + 0 * 1048576u, Wsp + 1 * 1048576u, out, 16384, 1024, 1024);
  } else {
    gemm_axw<2, 1, 0, float><<<gg, 256, 0, stream>>>(xh, xl, Wq, nullptr, out, 16384, 1024, 1024);
    gemm_axw<2, 1, 0, u16><<<gg, 256, 0, stream>>>(xh, xl, Wk, nullptr, Kbf, 16384, 1024, 1024);
    gemm_axw<2, 1, 0, u16><<<gg, 256, 0, stream>>>(xh, xl, Wv, nullptr, Vbf, 16384, 1024, 1024);
    u16* P = (u16*)Preg; u16* R = (u16*)Rreg;
    phase1_kernel<u16><<<dim3(NCHUNK, H_), 256, 0, stream>>>(out, Kbf, Vbf, P, R);
    seq_levelA<u16><<<dim3(NSUP, H_), 256, 0, stream>>>(P, R, Psup, Rsup);
    seq_levelB<<<dim3(H_), 256, 0, stream>>>(Psup, Rsup, Msup);
    seq_levelC<u16><<<dim3(NSUP, H_), 256, 0, stream>>>(P, R, Msup);
    phase3_kernel<u16><<<dim3(NCHUNK, H_), 256, 0, stream>>>(out, Vbf, R, attn);
    gemm_axw<1, 2, 0, float><<<gg, 256, 0, stream>>>(attn, nullptr, Wo, nullptr, out, 16384, 1024, 1024);
  }
}

// Round 10
// 581.180 us; speedup vs baseline: 2.3827x; 1.3102x over previous
//
#include <hip/hip_runtime.h>

// L2RegressionAttention — chunked WY-transform.
// r10: all four GEMMs single-pass bf16 (ah*bh) — K/V/attn are bf16-stored so
// the lo-correction passes were below the storage-rounding floor. Splits emit
// hi only. phase1 / levels / phase3 byte-identical to passing r9.
// B=4, S=4096, D=1024, H=16, hd=64, eta = 0.1/4 = 0.025.

typedef unsigned short u16;
typedef __attribute__((ext_vector_type(8))) short short8;
typedef __attribute__((ext_vector_type(4))) float f32x4;

#define B_ 4
#define S_ 4096
#define D_ 1024
#define H_ 16
#define CHUNK 16
#define NCHUNK 256
#define SUPW 16
#define NSUP 16
#define ETA 0.025f

__device__ __forceinline__ u16 f2bf(float f) {
  unsigned u = __builtin_bit_cast(unsigned, f);
  u += 0x7fffu + ((u >> 16) & 1u);
  return (u16)(u >> 16);
}
__device__ __forceinline__ float bf2f(u16 s) {
  unsigned u = ((unsigned)s) << 16;
  return __builtin_bit_cast(float, u);
}
__device__ __forceinline__ float ldv(float v) { return v; }
__device__ __forceinline__ float ldv(u16 v) { return bf2f(v); }
__device__ __forceinline__ void stv(float* p, float v) { *p = v; }
__device__ __forceinline__ void stv(u16* p, float v) { *p = f2bf(v); }

#define MFMA __builtin_amdgcn_mfma_f32_16x16x32_bf16

// async global -> LDS, 16B/lane; dst base wave-uniform, +lane*16 implicit
__device__ __forceinline__ void gload16(const void* g, void* l) {
  __builtin_amdgcn_global_load_lds(
      (__attribute__((address_space(1))) void*)g,
      (__attribute__((address_space(3))) void*)l, 16, 0, 0);
}

// ---------------- fp32 -> bf16 hi-only convert, float4-vectorized ----------------
__global__ void cvt_hi_kernel(const float* __restrict__ x, u16* __restrict__ hi, int n4) {
  int i = blockIdx.x * blockDim.x + threadIdx.x;
  int stride = gridDim.x * blockDim.x;
  for (; i < n4; i += stride) {
    float4 v = ((const float4*)x)[i];
    ushort4 h;
    h.x = f2bf(v.x); h.y = f2bf(v.y); h.z = f2bf(v.z); h.w = f2bf(v.w);
    ((ushort4*)hi)[i] = h;
  }
}

// ---------------- GEMM: C[M][N] = A * B^T (2-phase dbuf gload_lds) ----------------
// Single-pass bf16: A = Ah (pre-split hi), B = Bh (BPRE=1 pre-split hi via
// gload_lds; BPRE=0 fp32 converted on the fly). 128x128, BK=32, 4 waves.
template<int BPRE, typename OutT>
__global__ __launch_bounds__(256) void gemm_axw(
    const u16* __restrict__ Ahg, const void* __restrict__ Bhp,
    OutT* __restrict__ C, int M, int N, int K) {
  __shared__ __align__(16) u16 Ahs[2][128][32];
  __shared__ __align__(16) u16 Bhs[2][128][32];
  const int tid = threadIdx.x, w = tid >> 6, lane = tid & 63;
  const int nwg = gridDim.x * gridDim.y;
  const int orig = blockIdx.y * gridDim.x + blockIdx.x;
  const int id = ((nwg & 7) == 0) ? ((orig & 7) * (nwg >> 3) + (orig >> 3)) : orig;
  const int bm = (id % gridDim.x) * 128, bn = (id / gridDim.x) * 128;
  const int wm = (w >> 1) * 64, wn = (w & 1) * 64;
  const int fr = lane & 15, kb = lane >> 4;
  const int lrow = lane >> 2, lcol = (lane & 3) * 8;

  auto stage = [&](int buf, int k0) {
    {
      const size_t rb = (size_t)(bm + w * 32 + lrow) * K + k0 + lcol;
      gload16(Ahg + rb, &Ahs[buf][w * 32][0]);
      gload16(Ahg + rb + (size_t)16 * K, &Ahs[buf][w * 32 + 16][0]);
    }
    if constexpr (BPRE) {
      const u16* Bhg = (const u16*)Bhp;
      const size_t rb = (size_t)(bn + w * 32 + lrow) * K + k0 + lcol;
      gload16(Bhg + rb, &Bhs[buf][w * 32][0]);
      gload16(Bhg + rb + (size_t)16 * K, &Bhs[buf][w * 32 + 16][0]);
    } else {
      const float* Bm = (const float*)Bhp;
#pragma unroll
      for (int i2 = 0; i2 < 4; ++i2) {
        int e = tid + i2 * 256, r = e >> 3, sg = (e & 7) * 4;
        float4 v = *(const float4*)(&Bm[(size_t)(bn + r) * K + k0 + sg]);
        ushort4 hq;
        hq.x = f2bf(v.x); hq.y = f2bf(v.y); hq.z = f2bf(v.z); hq.w = f2bf(v.w);
        *(ushort4*)(&Bhs[buf][r][sg]) = hq;
      }
    }
  };

  f32x4 acc[4][4];
#pragma unroll
  for (int i = 0; i < 4; ++i)
#pragma unroll
    for (int j = 0; j < 4; ++j) acc[i][j] = (f32x4){0.f, 0.f, 0.f, 0.f};

  stage(0, 0);
  asm volatile("s_waitcnt vmcnt(0)" ::: "memory");
  __syncthreads();
  const int nt = K >> 5;
  int cur = 0;
  for (int t = 0; t < nt; ++t) {
    if (t + 1 < nt) stage(cur ^ 1, (t + 1) * 32);  // issue-early into other buf
    short8 ah[4], bh[4];
#pragma unroll
    for (int mi = 0; mi < 4; ++mi)
      ah[mi] = *(const short8*)(&Ahs[cur][wm + mi * 16 + fr][kb * 8]);
#pragma unroll
    for (int ni = 0; ni < 4; ++ni)
      bh[ni] = *(const short8*)(&Bhs[cur][wn + ni * 16 + fr][kb * 8]);
#pragma unroll
    for (int mi = 0; mi < 4; ++mi)
#pragma unroll
      for (int ni = 0; ni < 4; ++ni)
        acc[mi][ni] = MFMA(ah[mi], bh[ni], acc[mi][ni], 0, 0, 0);
    asm volatile("s_waitcnt vmcnt(0)" ::: "memory");  // next buf staged
    __syncthreads();                                  // + frag reads drained
    cur ^= 1;
  }
  const int fc = lane & 15, fr4 = (lane >> 4) * 4;
#pragma unroll
  for (int mi = 0; mi < 4; ++mi)
#pragma unroll
    for (int ni = 0; ni < 4; ++ni) {
      int gm = bm + wm + mi * 16 + fr4;
      int gn = bn + wn + ni * 16 + fc;
#pragma unroll
      for (int rg = 0; rg < 4; ++rg)
        stv(&C[(size_t)(gm + rg) * N + gn], acc[mi][ni][rg]);
    }
}

// ---------------- phase 1 (MFMA) — unchanged r9 ----------------
template<typename PT>
__global__ __launch_bounds__(256) void phase1_kernel(
    float* __restrict__ Qg, const u16* __restrict__ Kg, u16* __restrict__ Vg,
    PT* __restrict__ Pg, PT* __restrict__ Rg) {
  __shared__ __align__(16) u16 Ks[64][72];
  __shared__ __align__(16) u16 KsT[64][72];
  __shared__ __align__(16) u16 Gh[64][72];
  __shared__ __align__(16) u16 Gl[64][72];
  __shared__ __align__(16) float Ut[64][68];
  __shared__ __align__(16) float Wt[64][68];

  const int c = blockIdx.x, h = blockIdx.y, tid = threadIdx.x;
  const int w = tid >> 6, lane = tid & 63;
  const int fr = lane & 15, kq = lane >> 4, orow = kq * 4;
  const int xr = 16 * w + fr;

  auto gidx = [&](int r, int d) -> size_t {
    return ((size_t)(r & 3) * S_ + (size_t)c * CHUNK + (r >> 2)) * D_ + h * 64 + d;
  };
  auto ldb = [&](const u16 (*M)[72], int row, int s) -> short8 {
    return *(const short8*)(&M[row][32 * s + 8 * kq]);
  };
  auto ldm = [&](const u16 (*M)[72], int row, int s, bool up) -> short8 {
    short8 r = *(const short8*)(&M[row][32 * s + 8 * kq]);
    int rb = row >> 2, k0 = 32 * s + 8 * kq;
#pragma unroll
    for (int j = 0; j < 8; ++j) {
      int kb2 = (k0 + j) >> 2;
      bool keep = up ? (kb2 > rb) : (rb > kb2);
      if (!keep) r[j] = 0;
    }
    return r;
  };
  auto ldf = [&](const float (*M)[68], int row, int s, short8& hh, short8& ll) {
    const float* p = &M[row][32 * s + 8 * kq];
#pragma unroll
    for (int j = 0; j < 8; ++j) {
      float v = p[j];
      u16 hb = f2bf(v);
      hh[j] = (short)hb;
      ll[j] = (short)f2bf(v - bf2f(hb));
    }
  };
  auto ldfh = [&](const float (*M)[68], int row, int s) -> short8 {
    const float* p = &M[row][32 * s + 8 * kq];
    short8 hh;
#pragma unroll
    for (int j = 0; j < 8; ++j) hh[j] = (short)f2bf(p[j]);
    return hh;
  };

  for (int i = tid; i < 4096; i += 256) {
    int r = i >> 6, d = i & 63;
    size_t g = gidx(r, d);
    u16 kraw = Kg[g];
    Ks[r][d] = kraw;
    KsT[d][r] = kraw;
    Wt[d][r] = ETA * bf2f(kraw);
    Ut[d][r] = ETA * bf2f(Vg[g]);
  }
  __syncthreads();  // (1)

  {
    f32x4 acc[4];
#pragma unroll
    for (int ni = 0; ni < 4; ++ni) acc[ni] = (f32x4){0.f, 0.f, 0.f, 0.f};
    short8 xf[2];
#pragma unroll
    for (int s = 0; s < 2; ++s) xf[s] = ldb(Ks, xr, s);
#pragma unroll
    for (int ni = 0; ni < 4; ++ni)
#pragma unroll
      for (int s = 0; s < 2; ++s)
        acc[ni] = MFMA(xf[s], ldb(Ks, 16 * ni + fr, s), acc[ni], 0, 0, 0);
#pragma unroll
    for (int ni = 0; ni < 4; ++ni)
#pragma unroll
      for (int rg = 0; rg < 4; ++rg) {
        float v = -ETA * acc[ni][rg];
        u16 hb = f2bf(v);
        int rr = 16 * w + orow + rg, cc = 16 * ni + fr;
        Gh[rr][cc] = hb;
        Gl[rr][cc] = f2bf(v - bf2f(hb));
      }
  }

  float sreg[4][4];
  {
    short8 xh[2], xl[2];
#pragma unroll
    for (int s = 0; s < 2; ++s) {
      const float* qp = &Qg[gidx(xr, 32 * s + 8 * kq)];
#pragma unroll
      for (int j = 0; j < 8; ++j) {
        float v = qp[j];
        u16 hb = f2bf(v);
        xh[s][j] = (short)hb;
        xl[s][j] = (short)f2bf(v - bf2f(hb));
      }
    }
    f32x4 acc[4];
#pragma unroll
    for (int ni = 0; ni < 4; ++ni) acc[ni] = (f32x4){0.f, 0.f, 0.f, 0.f};
#pragma unroll
    for (int ni = 0; ni < 4; ++ni)
#pragma unroll
      for (int s = 0; s < 2; ++s) {
        short8 yf = ldb(Ks, 16 * ni + fr, s);
        acc[ni] = MFMA(xh[s], yf, acc[ni], 0, 0, 0);
        acc[ni] = MFMA(xl[s], yf, acc[ni], 0, 0, 0);
      }
#pragma unroll
    for (int ni = 0; ni < 4; ++ni)
#pragma unroll
      for (int rg = 0; rg < 4; ++rg) {
        int r = 16 * w + orow + rg, cc = 16 * ni + fr;
        sreg[ni][rg] = ((r >> 2) >= (cc >> 2)) ? acc[ni][rg] : 0.f;
      }
  }
  __syncthreads();  // (2)

  auto app1 = [&](float (*St)[68]) {
    short8 xh[2], xl[2];
#pragma unroll
    for (int s = 0; s < 2; ++s) ldf(St, xr, s, xh[s], xl[s]);
    f32x4 acc[4];
#pragma unroll
    for (int ni = 0; ni < 4; ++ni) acc[ni] = (f32x4){0.f, 0.f, 0.f, 0.f};
#pragma unroll
    for (int ni = 0; ni < 4; ++ni)
#pragma unroll
      for (int s = 0; s < 2; ++s) {
        short8 yh = ldm(Gh, 16 * ni + fr, s, false);
        short8 yl = ldm(Gl, 16 * ni + fr, s, false);
        acc[ni] = MFMA(xh[s], yh, acc[ni], 0, 0, 0);
        acc[ni] = MFMA(xh[s], yl, acc[ni], 0, 0, 0);
        acc[ni] = MFMA(xl[s], yh, acc[ni], 0, 0, 0);
      }
#pragma unroll
    for (int ni = 0; ni < 4; ++ni)
#pragma unroll
      for (int rg = 0; rg < 4; ++rg)
        St[16 * w + orow + rg][16 * ni + fr] += acc[ni][rg];
  };
  auto appS = [&](float (*St)[68], const u16 (*Np)[72]) {
    short8 xh[2];
#pragma unroll
    for (int s = 0; s < 2; ++s) xh[s] = ldfh(St, xr, s);
    f32x4 acc[4];
#pragma unroll
    for (int ni = 0; ni < 4; ++ni) acc[ni] = (f32x4){0.f, 0.f, 0.f, 0.f};
#pragma unroll
    for (int ni = 0; ni < 4; ++ni)
#pragma unroll
      for (int s = 0; s < 2; ++s)
        acc[ni] = MFMA(xh[s], ldb(Np, 16 * ni + fr, s), acc[ni], 0, 0, 0);
#pragma unroll
    for (int ni = 0; ni < 4; ++ni)
#pragma unroll
      for (int rg = 0; rg < 4; ++rg)
        St[16 * w + orow + rg][16 * ni + fr] += acc[ni][rg];
  };

  app1(Ut);
  app1(Wt);
  {
    f32x4 sq[4];
#pragma unroll
    for (int ni = 0; ni < 4; ++ni) sq[ni] = (f32x4){0.f, 0.f, 0.f, 0.f};
    short8 xh[2], xl[2];
#pragma unroll
    for (int s = 0; s < 2; ++s) {
      xh[s] = ldm(Gh, xr, s, false);
      xl[s] = ldm(Gl, xr, s, false);
    }
#pragma unroll
    for (int ni = 0; ni < 4; ++ni)
#pragma unroll
      for (int s = 0; s < 2; ++s) {
        short8 yh = ldm(Gh, 16 * ni + fr, s, true);
        short8 yl = ldm(Gl, 16 * ni + fr, s, true);
        sq[ni] = MFMA(xh[s], yh, sq[ni], 0, 0, 0);
        sq[ni] = MFMA(xh[s], yl, sq[ni], 0, 0, 0);
        sq[ni] = MFMA(xl[s], yh, sq[ni], 0, 0, 0);
      }
    __syncthreads();  // (3)
#pragma unroll
    for (int ni = 0; ni < 4; ++ni)
#pragma unroll
      for (int rg = 0; rg < 4; ++rg) {
        u16 b = f2bf(sq[ni][rg]);
        int rr = 16 * w + orow + rg, cc = 16 * ni + fr;
        Ks[rr][cc] = b;
        Gh[cc][rr] = b;
      }
  }
  __syncthreads();  // (4)

  appS(Ut, Ks);
  appS(Wt, Ks);
  {
    f32x4 sq[4];
#pragma unroll
    for (int ni = 0; ni < 4; ++ni) sq[ni] = (f32x4){0.f, 0.f, 0.f, 0.f};
    short8 xf[2];
#pragma unroll
    for (int s = 0; s < 2; ++s) xf[s] = ldb(Ks, xr, s);
#pragma unroll
    for (int ni = 0; ni < 4; ++ni)
#pragma unroll
      for (int s = 0; s < 2; ++s)
        sq[ni] = MFMA(xf[s], ldb(Gh, 16 * ni + fr, s), sq[ni], 0, 0, 0);
    __syncthreads();  // (5)
#pragma unroll
    for (int ni = 0; ni < 4; ++ni)
#pragma unroll
      for (int rg = 0; rg < 4; ++rg) {
        u16 b = f2bf(sq[ni][rg]);
        int rr = 16 * w + orow + rg, cc = 16 * ni + fr;
        Gl[rr][cc] = b;
        Ks[cc][rr] = b;
      }
  }
  __syncthreads();  // (6)

  appS(Ut, Gl);
  appS(Wt, Gl);
  {
    f32x4 sq[4];
#pragma unroll
    for (int ni = 0; ni < 4; ++ni) sq[ni] = (f32x4){0.f, 0.f, 0.f, 0.f};
    short8 xf[2];
#pragma unroll
    for (int s = 0; s < 2; ++s) xf[s] = ldb(Gl, xr, s);
#pragma unroll
    for (int ni = 0; ni < 4; ++ni)
#pragma unroll
      for (int s = 0; s < 2; ++s)
        sq[ni] = MFMA(xf[s], ldb(Ks, 16 * ni + fr, s), sq[ni], 0, 0, 0);
#pragma unroll
    for (int ni = 0; ni < 4; ++ni)
#pragma unroll
      for (int rg = 0; rg < 4; ++rg)
        Gh[16 * w + orow + rg][16 * ni + fr] = f2bf(sq[ni][rg]);
  }
  __syncthreads();  // (7)

  appS(Ut, Gh);
  appS(Wt, Gh);
  __syncthreads();  // (7b)

  const size_t base = ((size_t)c * H_ + h) * 4096;
  {
    short8 xh[2], xl[2];
#pragma unroll
    for (int s = 0; s < 2; ++s) ldf(Wt, xr, s, xh[s], xl[s]);
    f32x4 acc[4];
#pragma unroll
    for (int ni = 0; ni < 4; ++ni) acc[ni] = (f32x4){0.f, 0.f, 0.f, 0.f};
#pragma unroll
    for (int ni = 0; ni < 4; ++ni)
#pragma unroll
      for (int s = 0; s < 2; ++s) {
        short8 yf = ldb(KsT, 16 * ni + fr, s);
        acc[ni] = MFMA(xh[s], yf, acc[ni], 0, 0, 0);
        acc[ni] = MFMA(xl[s], yf, acc[ni], 0, 0, 0);
      }
#pragma unroll
    for (int ni = 0; ni < 4; ++ni)
#pragma unroll
      for (int rg = 0; rg < 4; ++rg)
        stv(&Pg[base + (16 * w + orow + rg) * 64 + 16 * ni + fr], acc[ni][rg]);
  }
  {
    short8 xh[2], xl[2];
#pragma unroll
    for (int s = 0; s < 2; ++s) ldf(Ut, xr, s, xh[s], xl[s]);
    f32x4 acc[4];
#pragma unroll
    for (int ni = 0; ni < 4; ++ni) acc[ni] = (f32x4){0.f, 0.f, 0.f, 0.f};
#pragma unroll
    for (int ni = 0; ni < 4; ++ni)
#pragma unroll
      for (int s = 0; s < 2; ++s) {
        short8 yf = ldb(KsT, 16 * ni + fr, s);
        acc[ni] = MFMA(xh[s], yf, acc[ni], 0, 0, 0);
        acc[ni] = MFMA(xl[s], yf, acc[ni], 0, 0, 0);
      }
#pragma unroll
    for (int ni = 0; ni < 4; ++ni)
#pragma unroll
      for (int rg = 0; rg < 4; ++rg)
        stv(&Rg[base + (16 * w + orow + rg) * 64 + 16 * ni + fr], acc[ni][rg]);
  }
  {
    const int r = tid >> 2, d0 = (tid & 3) * 16;
    short8 v0, v1;
#pragma unroll
    for (int j = 0; j < 8; ++j) v0[j] = (short)f2bf(Wt[r][d0 + j]);
#pragma unroll
    for (int j = 0; j < 8; ++j) v1[j] = (short)f2bf(Wt[r][d0 + 8 + j]);
    *(short8*)(&Gh[r][d0]) = v0;
    *(short8*)(&Gh[r][d0 + 8]) = v1;
#pragma unroll
    for (int j = 0; j < 8; ++j) v0[j] = (short)f2bf(Ut[r][d0 + j]);
#pragma unroll
    for (int j = 0; j < 8; ++j) v1[j] = (short)f2bf(Ut[r][d0 + 8 + j]);
    *(short8*)(&Gl[r][d0]) = v0;
    *(short8*)(&Gl[r][d0 + 8]) = v1;
  }
#pragma unroll
  for (int ni = 0; ni < 4; ++ni)
#pragma unroll
    for (int rg = 0; rg < 4; ++rg)
      Ks[16 * w + orow + rg][16 * ni + fr] = f2bf(sreg[ni][rg]);
  __syncthreads();  // (8)

  {
    short8 xs[2];
#pragma unroll
    for (int s = 0; s < 2; ++s) xs[s] = ldb(Ks, xr, s);
    f32x4 accE[4], accF[4];
#pragma unroll
    for (int ni = 0; ni < 4; ++ni) {
      accE[ni] = (f32x4){0.f, 0.f, 0.f, 0.f};
      accF[ni] = (f32x4){0.f, 0.f, 0.f, 0.f};
    }
#pragma unroll
    for (int ni = 0; ni < 4; ++ni)
#pragma unroll
      for (int s = 0; s < 2; ++s) {
        accE[ni] = MFMA(xs[s], ldb(Gh, 16 * ni + fr, s), accE[ni], 0, 0, 0);
        accF[ni] = MFMA(xs[s], ldb(Gl, 16 * ni + fr, s), accF[ni], 0, 0, 0);
      }
#pragma unroll
    for (int ni = 0; ni < 4; ++ni)
#pragma unroll
      for (int rg = 0; rg < 4; ++rg) {
        int r = 16 * w + orow + rg, d = 16 * ni + fr;
        size_t g = gidx(r, d);
        float qv = Qg[g];
        Qg[g] = qv - accE[ni][rg];
        Vg[g] = f2bf(accF[ni][rg]);
      }
  }
}

// ---------------- scalar 64x64 helpers (levelB only) ----------------
__device__ __forceinline__ void store64(float* dst, const float (*src)[65], int tid) {
  for (int i = tid; i < 4096; i += 256) dst[i] = src[i >> 6][i & 63];
}
__device__ __forceinline__ void mm64(const float (*X)[65], const float (*Y)[65],
                                     float (*Dst)[65], const float (*Add)[65], int tid) {
  const int r0 = (tid >> 4) * 4, c0 = (tid & 15) * 4;
  float a[4][4] = {};
  for (int d = 0; d < 64; ++d) {
    float xv[4], yv[4];
#pragma unroll
    for (int i = 0; i < 4; ++i) xv[i] = X[r0 + i][d];
#pragma unroll
    for (int j = 0; j < 4; ++j) yv[j] = Y[d][c0 + j];
#pragma unroll
    for (int i = 0; i < 4; ++i)
#pragma unroll
      for (int j = 0; j < 4; ++j) a[i][j] += xv[i] * yv[j];
  }
  __syncthreads();
#pragma unroll
  for (int i = 0; i < 4; ++i)
#pragma unroll
    for (int j = 0; j < 4; ++j) {
      float v = a[i][j];
      if (Add) v += Add[r0 + i][c0 + j];
      Dst[r0 + i][c0 + j] = v;
    }
  __syncthreads();
}

// ---------------- level A (MFMA, bf16x3) — unchanged r9 ----------------
template<typename PT>
__global__ __launch_bounds__(256) void seq_levelA(const PT* __restrict__ Pg,
    const PT* __restrict__ Rg, float* __restrict__ Psup, float* __restrict__ Rsup) {
  __shared__ __align__(16) float Pa[64][68], Ra[64][68], Ri[64][68];
  __shared__ __align__(16) u16 Pih[64][72], Pil[64][72];
  const int sup = blockIdx.x, h = blockIdx.y, tid = threadIdx.x;
  const int w = tid >> 6, lane = tid & 63;
  const int fr = lane & 15, kq = lane >> 4, orow = kq * 4;
  const int xr = 16 * w + fr;
  const int cbase = sup * SUPW;

  auto upd = [&](float (*St)[68], const float (*Add)[68]) {
    short8 xh[2], xl[2];
#pragma unroll
    for (int s2 = 0; s2 < 2; ++s2) {
      const float* p = &St[xr][32 * s2 + 8 * kq];
#pragma unroll
      for (int j = 0; j < 8; ++j) {
        float v = p[j];
        u16 hb = f2bf(v);
        xh[s2][j] = (short)hb;
        xl[s2][j] = (short)f2bf(v - bf2f(hb));
      }
    }
    f32x4 acc[4];
#pragma unroll
    for (int ni = 0; ni < 4; ++ni) acc[ni] = (f32x4){0.f, 0.f, 0.f, 0.f};
#pragma unroll
    for (int ni = 0; ni < 4; ++ni)
#pragma unroll
      for (int s2 = 0; s2 < 2; ++s2) {
        short8 yh = *(const short8*)(&Pih[16 * ni + fr][32 * s2 + 8 * kq]);
        short8 yl = *(const short8*)(&Pil[16 * ni + fr][32 * s2 + 8 * kq]);
        acc[ni] = MFMA(xh[s2], yh, acc[ni], 0, 0, 0);
        acc[ni] = MFMA(xh[s2], yl, acc[ni], 0, 0, 0);
        acc[ni] = MFMA(xl[s2], yh, acc[ni], 0, 0, 0);
      }
#pragma unroll
    for (int ni = 0; ni < 4; ++ni)
#pragma unroll
      for (int rg = 0; rg < 4; ++rg) {
        float v = acc[ni][rg];
        if (Add) v += Add[16 * w + orow + rg][16 * ni + fr];
        St[16 * w + orow + rg][16 * ni + fr] = v;
      }
  };

  {
    const PT* ps = Pg + ((size_t)cbase * H_ + h) * 4096;
    const PT* rs = Rg + ((size_t)cbase * H_ + h) * 4096;
    for (int i = tid; i < 4096; i += 256) {
      int r = i >> 6, cc = i & 63;
      Pa[r][cc] = ((r == cc) ? 1.f : 0.f) - ldv(ps[i]);
      Ra[r][cc] = ldv(rs[i]);
    }
  }
  float pf[16], rf[16];
  {
    const PT* ps = Pg + ((size_t)(cbase + 1) * H_ + h) * 4096;
    const PT* rs = Rg + ((size_t)(cbase + 1) * H_ + h) * 4096;
#pragma unroll
    for (int k = 0; k < 16; ++k) { int i = tid + k * 256; pf[k] = ldv(ps[i]); rf[k] = ldv(rs[i]); }
  }
  for (int s = 1; s < SUPW; ++s) {
#pragma unroll
    for (int k = 0; k < 16; ++k) {
      int i = tid + k * 256, d = i >> 6, cc = i & 63;
      float v = ((d == cc) ? 1.f : 0.f) - pf[k];
      u16 hb = f2bf(v);
      Pih[cc][d] = hb;
      Pil[cc][d] = f2bf(v - bf2f(hb));
      Ri[d][cc] = rf[k];
    }
    __syncthreads();
    if (s + 1 < SUPW) {
      const PT* ps = Pg + ((size_t)(cbase + s + 1) * H_ + h) * 4096;
      const PT* rs = Rg + ((size_t)(cbase + s + 1) * H_ + h) * 4096;
#pragma unroll
      for (int k = 0; k < 16; ++k) { int i = tid + k * 256; pf[k] = ldv(ps[i]); rf[k] = ldv(rs[i]); }
    }
    upd(Pa, nullptr);
    upd(Ra, Ri);
    __syncthreads();
  }
  for (int i = tid; i < 4096; i += 256) {
    Psup[((size_t)sup * H_ + h) * 4096 + i] = Pa[i >> 6][i & 63];
    Rsup[((size_t)sup * H_ + h) * 4096 + i] = Ra[i >> 6][i & 63];
  }
}

// ---------------- level B: exact fp32 scalar — unchanged ----------------
__global__ __launch_bounds__(256) void seq_levelB(const float* __restrict__ Psup,
    const float* __restrict__ Rsup, float* __restrict__ Msup) {
  __shared__ float Ms[64][65], Pi[64][65], Ri[64][65];
  const int h = blockIdx.x, tid = threadIdx.x;
  for (int i = tid; i < 4096; i += 256) Ms[i >> 6][i & 63] = 0.f;
  float pf[16], rf[16];
  {
    const float* ps = Psup + ((size_t)0 * H_ + h) * 4096;
    const float* rs = Rsup + ((size_t)0 * H_ + h) * 4096;
#pragma unroll
    for (int k = 0; k < 16; ++k) { int i = tid + k * 256; pf[k] = ps[i]; rf[k] = rs[i]; }
  }
  for (int s = 0; s < NSUP; ++s) {
#pragma unroll
    for (int k = 0; k < 16; ++k) {
      int i = tid + k * 256, r = i >> 6, cc = i & 63;
      Pi[r][cc] = pf[k];
      Ri[r][cc] = rf[k];
    }
    store64(Msup + ((size_t)s * H_ + h) * 4096, Ms, tid);
    __syncthreads();
    if (s + 1 < NSUP) {
      const float* ps = Psup + ((size_t)(s + 1) * H_ + h) * 4096;
      const float* rs = Rsup + ((size_t)(s + 1) * H_ + h) * 4096;
#pragma unroll
      for (int k = 0; k < 16; ++k) { int i = tid + k * 256; pf[k] = ps[i]; rf[k] = rs[i]; }
    }
    mm64(Ms, Pi, Ms, Ri, tid);
  }
}

// ---------------- level C (MFMA, bf16x3) — unchanged r9 ----------------
template<typename PT>
__global__ __launch_bounds__(256) void seq_levelC(const PT* __restrict__ Pg,
    PT* __restrict__ Rg, const float* __restrict__ Msup) {
  __shared__ __align__(16) float Ms[64][68], Ri[64][68];
  __shared__ __align__(16) u16 Pih[64][72], Pil[64][72];
  const int sup = blockIdx.x, h = blockIdx.y, tid = threadIdx.x;
  const int w = tid >> 6, lane = tid & 63;
  const int fr = lane & 15, kq = lane >> 4, orow = kq * 4;
  const int xr = 16 * w + fr;

  auto upd = [&](float (*St)[68], const float (*Add)[68]) {
    short8 xh[2], xl[2];
#pragma unroll
    for (int s2 = 0; s2 < 2; ++s2) {
      const float* p = &St[xr][32 * s2 + 8 * kq];
#pragma unroll
      for (int j = 0; j < 8; ++j) {
        float v = p[j];
        u16 hb = f2bf(v);
        xh[s2][j] = (short)hb;
        xl[s2][j] = (short)f2bf(v - bf2f(hb));
      }
    }
    f32x4 acc[4];
#pragma unroll
    for (int ni = 0; ni < 4; ++ni) acc[ni] = (f32x4){0.f, 0.f, 0.f, 0.f};
#pragma unroll
    for (int ni = 0; ni < 4; ++ni)
#pragma unroll
      for (int s2 = 0; s2 < 2; ++s2) {
        short8 yh = *(const short8*)(&Pih[16 * ni + fr][32 * s2 + 8 * kq]);
        short8 yl = *(const short8*)(&Pil[16 * ni + fr][32 * s2 + 8 * kq]);
        acc[ni] = MFMA(xh[s2], yh, acc[ni], 0, 0, 0);
        acc[ni] = MFMA(xh[s2], yl, acc[ni], 0, 0, 0);
        acc[ni] = MFMA(xl[s2], yh, acc[ni], 0, 0, 0);
      }
#pragma unroll
    for (int ni = 0; ni < 4; ++ni)
#pragma unroll
      for (int rg = 0; rg < 4; ++rg) {
        float v = acc[ni][rg];
        if (Add) v += Add[16 * w + orow + rg][16 * ni + fr];
        St[16 * w + orow + rg][16 * ni + fr] = v;
      }
  };

  for (int i = tid; i < 4096; i += 256)
    Ms[i >> 6][i & 63] = Msup[((size_t)sup * H_ + h) * 4096 + i];
  float pf[16], rf[16];
  {
    const size_t slice = ((size_t)(sup * SUPW) * H_ + h) * 4096;
#pragma unroll
    for (int k = 0; k < 16; ++k) { int i = tid + k * 256; pf[k] = ldv(Pg[slice + i]); rf[k] = ldv(Rg[slice + i]); }
  }
  for (int s = 0; s < SUPW; ++s) {
    const size_t slice = ((size_t)(sup * SUPW + s) * H_ + h) * 4096;
#pragma unroll
    for (int k = 0; k < 16; ++k) {
      int i = tid + k * 256, d = i >> 6, cc = i & 63;
      float v = ((d == cc) ? 1.f : 0.f) - pf[k];
      u16 hb = f2bf(v);
      Pih[cc][d] = hb;
      Pil[cc][d] = f2bf(v - bf2f(hb));
      Ri[d][cc] = rf[k];
    }
    for (int i = tid; i < 4096; i += 256) stv(&Rg[slice + i], Ms[i >> 6][i & 63]);
    __syncthreads();
    if (s + 1 < SUPW) {
      const size_t sl2 = ((size_t)(sup * SUPW + s + 1) * H_ + h) * 4096;
#pragma unroll
      for (int k = 0; k < 16; ++k) { int i = tid + k * 256; pf[k] = ldv(Pg[sl2 + i]); rf[k] = ldv(Rg[sl2 + i]); }
    }
    upd(Ms, Ri);
    __syncthreads();
  }
}

// ---------------- phase 3: attn = E*M0^T + F (bf16 out) — unchanged ----------------
template<typename PT>
__global__ __launch_bounds__(256) void phase3_kernel(
    const float* __restrict__ Eg, const u16* __restrict__ Fg,
    const PT* __restrict__ Mcg, u16* __restrict__ attn) {
  __shared__ float Es[64][65], Ms[64][65];
  const int c = blockIdx.x, h = blockIdx.y, tid = threadIdx.x;
  for (int i = tid; i < 4096; i += 256) {
    int r = i >> 6, d = i & 63, t = r >> 2, b = r & 3;
    size_t g = ((size_t)b * S_ + (size_t)c * CHUNK + t) * D_ + h * 64 + d;
    Es[r][d] = Eg[g];
    Ms[i >> 6][i & 63] = ldv(Mcg[((size_t)c * H_ + h) * 4096 + i]);
  }
  __syncthreads();
  const int r0 = (tid >> 4) * 4, d0 = (tid & 15) * 4;
  float a[4][4] = {};
  for (int k = 0; k < 64; ++k) {
    float ev[4], mv[4];
#pragma unroll
    for (int i = 0; i < 4; ++i) ev[i] = Es[r0 + i][k];
#pragma unroll
    for (int j = 0; j < 4; ++j) mv[j] = Ms[d0 + j][k];
#pragma unroll
    for (int i = 0; i < 4; ++i)
#pragma unroll
      for (int j = 0; j < 4; ++j) a[i][j] += ev[i] * mv[j];
  }
#pragma unroll
  for (int i = 0; i < 4; ++i)
#pragma unroll
    for (int j = 0; j < 4; ++j) {
      int r = r0 + i, d = d0 + j, t = r >> 2, b = r & 3;
      size_t g = ((size_t)b * S_ + (size_t)c * CHUNK + t) * D_ + h * 64 + d;
      attn[g] = f2bf(a[i][j] + bf2f(Fg[g]));
    }
}

// ---------------- launch ----------------
extern "C" void kernel_launch(void* const* d_in, const int* in_sizes, int n_in,
                              void* d_out, int out_size, void* d_ws, size_t ws_size,
                              hipStream_t stream) {
  (void)in_sizes; (void)n_in; (void)out_size;
  const float* x  = (const float*)d_in[0];
  const float* Wq = (const float*)d_in[1];
  const float* Wk = (const float*)d_in[2];
  const float* Wv = (const float*)d_in[3];
  const float* Wo = (const float*)d_in[4];
  float* out = (float*)d_out;

  char* w = (char*)d_ws;
  const size_t MB = 1024 * 1024;
  u16* Kbf = (u16*)w;
  u16* Vbf = (u16*)(w + 32 * MB);
  u16* xh  = (u16*)(w + 64 * MB);
  const bool big = ws_size >= 192 * MB;
  void* Preg = (void*)(w + 64 * MB);
  void* Rreg = big ? (void*)(w + 128 * MB) : (void*)(w + 96 * MB);
  float* Psup = (float*)w;
  float* Rsup = (float*)(w + 4 * MB);
  float* Msup = (float*)(w + 8 * MB);
  u16* attn = (u16*)Preg;
  u16* Wsp = (u16*)(w + 128 * MB);  // hi-only: q +0, k +1M, v +2M (u16 units); o reuses +0

  const size_t DSZ = (size_t)B_ * S_ * D_;  // 16777216
  cvt_hi_kernel<<<2048, 256, 0, stream>>>(x, xh, (int)(DSZ / 4));

  dim3 gg(128, 8);
  if (big) {
    cvt_hi_kernel<<<512, 256, 0, stream>>>(Wq, Wsp + 0 * 1048576u, 262144);
    cvt_hi_kernel<<<512, 256, 0, stream>>>(Wk, Wsp + 1 * 1048576u, 262144);
    cvt_hi_kernel<<<512, 256, 0, stream>>>(Wv, Wsp + 2 * 1048576u, 262144);
    gemm_axw<1, float><<<gg, 256, 0, stream>>>(xh, Wsp + 0 * 1048576u, out, 16384, 1024, 1024);
    gemm_axw<1, u16><<<gg, 256, 0, stream>>>(xh, Wsp + 1 * 1048576u, Kbf, 16384, 1024, 1024);
    gemm_axw<1, u16><<<gg, 256, 0, stream>>>(xh, Wsp + 2 * 1048576u, Vbf, 16384, 1024, 1024);
    float* P = (float*)Preg; float* R = (float*)Rreg;
    phase1_kernel<float><<<dim3(NCHUNK, H_), 256, 0, stream>>>(out, Kbf, Vbf, P, R);
    seq_levelA<float><<<dim3(NSUP, H_), 256, 0, stream>>>(P, R, Psup, Rsup);
    seq_levelB<<<dim3(H_), 256, 0, stream>>>(Psup, Rsup, Msup);
    seq_levelC<float><<<dim3(NSUP, H_), 256, 0, stream>>>(P, R, Msup);
    phase3_kernel<float><<<dim3(NCHUNK, H_), 256, 0, stream>>>(out, Vbf, R, attn);
    cvt_hi_kernel<<<512, 256, 0, stream>>>(Wo, Wsp + 0 * 1048576u, 262144);
    gemm_axw<1, float><<<gg, 256, 0, stream>>>(attn, Wsp + 0 * 1048576u, out, 16384, 1024, 1024);
  } else {
    gemm_axw<0, float><<<gg, 256, 0, stream>>>(xh, Wq, out, 16384, 1024, 1024);
    gemm_axw<0, u16><<<gg, 256, 0, stream>>>(xh, Wk, Kbf, 16384, 1024, 1024);
    gemm_axw<0, u16><<<gg, 256, 0, stream>>>(xh, Wv, Vbf, 16384, 1024, 1024);
    u16* P = (u16*)Preg; u16* R = (u16*)Rreg;
    phase1_kernel<u16><<<dim3(NCHUNK, H_), 256, 0, stream>>>(out, Kbf, Vbf, P, R);
    seq_levelA<u16><<<dim3(NSUP, H_), 256, 0, stream>>>(P, R, Psup, Rsup);
    seq_levelB<<<dim3(H_), 256, 0, stream>>>(Psup, Rsup, Msup);
    seq_levelC<u16><<<dim3(NSUP, H_), 256, 0, stream>>>(P, R, Msup);
    phase3_kernel<u16><<<dim3(NCHUNK, H_), 256, 0, stream>>>(out, Vbf, R, attn);
    gemm_axw<0, float><<<gg, 256, 0, stream>>>(attn, Wo, out, 16384, 1024, 1024);
  }
}